// Round 5
// baseline (4970.981 us; speedup 1.0000x reference)
//
#include <hip/hip_runtime.h>
#include <stdint.h>

// ---------------------------------------------------------------------------
// JAX threefry2x32 (20 rounds), bit-exact port of jax/_src/prng.py
// ---------------------------------------------------------------------------
static __host__ __device__ inline uint32_t rotl32(uint32_t x, int r) {
  return (x << r) | (x >> (32 - r));
}

static __host__ __device__ inline void tf2x32(uint32_t k0, uint32_t k1,
                                              uint32_t x0, uint32_t x1,
                                              uint32_t& o0, uint32_t& o1) {
  uint32_t k2 = k0 ^ k1 ^ 0x1BD11BDAu;
#define TFR(a) { x0 += x1; x1 = rotl32(x1, a); x1 ^= x0; }
  x0 += k0; x1 += k1;
  TFR(13) TFR(15) TFR(26) TFR(6)
  x0 += k1; x1 += k2 + 1u;
  TFR(17) TFR(29) TFR(16) TFR(24)
  x0 += k2; x1 += k0 + 2u;
  TFR(13) TFR(15) TFR(26) TFR(6)
  x0 += k0; x1 += k1 + 3u;
  TFR(17) TFR(29) TFR(16) TFR(24)
  x0 += k1; x1 += k2 + 4u;
  TFR(13) TFR(15) TFR(26) TFR(6)
  x0 += k2; x1 += k0 + 5u;
#undef TFR
  o0 = x0; o1 = x1;
}

static __device__ inline uint32_t fold_bits(uint32_t k0, uint32_t k1, uint32_t ctr) {
  uint32_t a, b;
  tf2x32(k0, k1, 0u, ctr, a, b);
  return a ^ b;
}

// Candidates: m = bits>>9 < CUT. Expected 4.19M >= R~3.36M (~440 sigma margin).
#define CUT       (1u << 20)
#define NBINS     256u
#define BINREG    17408u         // per-bin region (mean 16381, +8 sigma)
#define ELEMS_K1  32768
#define MASKI     0x07FFFFFFu    // idx mask in .y (bits 25,26 always 0)

// pair packing: .x = (m<<12) | (value>>5)   [m:20 | v_hi:12]
//               .y = ((value&31)<<27) | idx [v_lo:5 | 0:2 | idx:25]
// sort key within bin: fine bucket c=(.x>>12)&4095, tie by (.y & MASKI)

// ---------------------------------------------------------------------------
// K1: per 32768-elem block: bernoulli mask + rsums; classify to 256 bins
// (LDS lbin), reserve bin runs, emit packed pairs bin-grouped.
// No global fine histogram, no pools.
// ---------------------------------------------------------------------------
__global__ __launch_bounds__(256) void k_megalite(const float* __restrict__ x,
                                                  uint64_t* __restrict__ mask,
                                                  uint32_t* __restrict__ rsums,
                                                  uint32_t* __restrict__ binCursor,
                                                  uint2* __restrict__ pairs,
                                                  uint32_t bk0, uint32_t bk1,
                                                  uint32_t sk0, uint32_t sk1, int n) {
  __shared__ uint8_t  lbin[ELEMS_K1];                 // 32 KB
  __shared__ uint32_t lhist[256], lgbase[256], lcur[256];
  __shared__ uint32_t wcnt[4];
  int tid = threadIdx.x, lane = tid & 63, wid = tid >> 6;
  int base = blockIdx.x * ELEMS_K1;
  lhist[tid] = 0;
  __syncthreads();

  uint32_t cnt = 0;
  for (int k = 0; k < ELEMS_K1 / 256; k++) {
    int li = k * 256 + tid;
    int i = base + li;
    bool inb = (i < n);
    float xv = inb ? x[i] : 0.0f;
    bool nonpad = inb && (xv != 0.0f);
    // bernoulli stream
    bool r = false;
    if (inb) {
      uint32_t bb = fold_bits(bk0, bk1, (uint32_t)i);
      float u = __uint_as_float((bb >> 9) | 0x3f800000u) - 1.0f;
      r = (u < 0.1f) && nonpad;
    }
    unsigned long long ball = __ballot(r);
    int wbase = base + k * 256 + wid * 64;
    if (lane == 0 && wbase < n) mask[wbase / 64] = (uint64_t)ball;
    cnt += r ? 1u : 0u;
    // shuffle-key classify
    uint8_t b = 0xFF;
    if (nonpad) {
      uint32_t m = fold_bits(sk0, sk1, (uint32_t)i) >> 9;
      if (m < CUT) { b = (uint8_t)(m >> 12); atomicAdd(&lhist[b], 1u); }
    }
    lbin[li] = b;
  }
  // rsums
  for (int d = 32; d >= 1; d >>= 1) cnt += __shfl_down(cnt, d, 64);
  if (lane == 0) wcnt[wid] = cnt;
  __syncthreads();
  if (tid == 0) rsums[blockIdx.x] = wcnt[0] + wcnt[1] + wcnt[2] + wcnt[3];
  // reserve per-bin contiguous runs
  uint32_t h = lhist[tid];
  lgbase[tid] = h ? atomicAdd((unsigned int*)&binCursor[tid], h) : 0u;
  lcur[tid] = 0u;
  __syncthreads();
  // emission: recompute m for candidates only (~12.5%), x re-read is L2-hot
  for (int k = 0; k < ELEMS_K1 / 256; k++) {
    int li = k * 256 + tid;
    int i = base + li;
    if (i >= n) continue;
    uint8_t b = lbin[li];
    if (b == 0xFF) continue;
    uint32_t m = fold_bits(sk0, sk1, (uint32_t)i) >> 9;
    uint32_t v = (uint32_t)x[i];
    uint32_t off = atomicAdd(&lcur[b], 1u) + lgbase[b];
    if (off < BINREG) {
      pairs[(size_t)b * BINREG + off] =
          make_uint2((m << 12) | (v >> 5), ((v & 31u) << 27) | (uint32_t)i);
    }
  }
}

// ---------------------------------------------------------------------------
// exclusive scan in place; also writes data[n] = total (alloc n+1!)
// ---------------------------------------------------------------------------
__global__ void k_scan_single(uint32_t* __restrict__ data, int n) {
  __shared__ uint32_t wsum[4];
  int tid = threadIdx.x, lane = tid & 63, wid = tid >> 6;
  uint32_t running = 0;
  for (int base = 0; base < n; base += 256) {
    int i = base + tid;
    uint32_t v = (i < n) ? data[i] : 0u;
    uint32_t incl = v;
    for (int d = 1; d < 64; d <<= 1) {
      uint32_t t = __shfl_up(incl, (unsigned)d, 64);
      if (lane >= d) incl += t;
    }
    if (lane == 63) wsum[wid] = incl;
    __syncthreads();
    uint32_t woff = 0, tot = 0;
    for (int w = 0; w < 4; w++) { uint32_t s = wsum[w]; if (w < wid) woff += s; tot += s; }
    if (i < n) data[i] = running + woff + (incl - v);
    running += tot;
    __syncthreads();
  }
  if (tid == 0) data[n] = running;
}

__global__ void k_copy256(uint32_t* __restrict__ dst, const uint32_t* __restrict__ src) {
  dst[threadIdx.x] = src[threadIdx.x];
}

// ---------------------------------------------------------------------------
// K2: one 1024-thread block per bin. Local 4096-bucket histogram -> block scan
// -> scatter pairs to exact global positions (sole-owner ~130KB window, L2-
// friendly) -> in-place per-bucket tie stabilization by idx.
// ---------------------------------------------------------------------------
__global__ __launch_bounds__(1024) void k_binsort(const uint2* __restrict__ pairs,
                                                  const uint32_t* __restrict__ binPrefix,
                                                  uint2* __restrict__ wnd) {
  __shared__ uint32_t hist[4096];    // 16 KB: counts -> prefix -> running cursor
  __shared__ uint32_t hstart[4096];  // 16 KB: frozen prefix (bucket starts)
  __shared__ uint32_t wsums[16];
  int tid = threadIdx.x, lane = tid & 63, wid = tid >> 6;
  uint32_t bin = blockIdx.x;
  uint32_t gbase = binPrefix[bin];
  uint32_t cnt = binPrefix[bin + 1] - gbase;
  if (cnt > BINREG) cnt = BINREG;
  size_t s = (size_t)bin * BINREG;

  for (int c = tid; c < 4096; c += 1024) hist[c] = 0;
  __syncthreads();
  for (uint32_t j = tid; j < cnt; j += 1024)
    atomicAdd(&hist[(pairs[s + j].x >> 12) & 4095u], 1u);
  __syncthreads();
  // block exclusive scan of hist[4096]; thread t owns entries [4t, 4t+4)
  uint32_t h0 = hist[4 * tid], h1 = hist[4 * tid + 1],
           h2 = hist[4 * tid + 2], h3 = hist[4 * tid + 3];
  uint32_t tsum = h0 + h1 + h2 + h3;
  uint32_t incl = tsum;
  for (int d = 1; d < 64; d <<= 1) {
    uint32_t t = __shfl_up(incl, (unsigned)d, 64);
    if (lane >= d) incl += t;
  }
  if (lane == 63) wsums[wid] = incl;
  __syncthreads();
  if (wid == 0) {
    uint32_t v = (lane < 16) ? wsums[lane] : 0u;
    uint32_t in2 = v;
    for (int d = 1; d < 64; d <<= 1) {
      uint32_t t = __shfl_up(in2, (unsigned)d, 64);
      if (lane >= d) in2 += t;
    }
    if (lane < 16) wsums[lane] = in2 - v;   // exclusive wave base
  }
  __syncthreads();
  uint32_t texcl = wsums[wid] + (incl - tsum);
  uint32_t e0 = texcl, e1 = e0 + h0, e2 = e1 + h1, e3 = e2 + h2;
  __syncthreads();   // all reads of hist done before overwrite
  hist[4 * tid] = e0;   hstart[4 * tid] = e0;
  hist[4 * tid + 1] = e1; hstart[4 * tid + 1] = e1;
  hist[4 * tid + 2] = e2; hstart[4 * tid + 2] = e2;
  hist[4 * tid + 3] = e3; hstart[4 * tid + 3] = e3;
  __syncthreads();
  // scatter to exact global slots (unstable within bucket)
  for (uint32_t j = tid; j < cnt; j += 1024) {
    uint2 p = pairs[s + j];
    uint32_t c = (p.x >> 12) & 4095u;
    uint32_t lpos = atomicAdd(&hist[c], 1u);
    wnd[gbase + lpos] = p;
  }
  __threadfence();
  __syncthreads();
  // stabilize ties by idx (avg 4/bucket, window is L2-hot)
  for (int c = tid; c < 4096; c += 1024) {
    uint32_t lo = hstart[c], hi = hist[c];
    for (uint32_t u = lo + 1; u < hi; u++) {
      uint2 v = wnd[gbase + u];
      uint32_t w = u;
      while (w > lo && (wnd[gbase + w - 1].y & MASKI) > (v.y & MASKI)) {
        wnd[gbase + w] = wnd[gbase + w - 1];
        w--;
      }
      wnd[gbase + w] = v;
    }
  }
}

// ---------------------------------------------------------------------------
// K3: out[i] = repl ? value(wnd[rank]) : x[i].  rank reads are sequential.
// Blocking matches K1 (32768 elems) so rsums line up.
// ---------------------------------------------------------------------------
__global__ __launch_bounds__(256) void k_final(const float* __restrict__ x,
                                               const uint64_t* __restrict__ mask,
                                               const uint32_t* __restrict__ rsums,
                                               const uint2* __restrict__ wnd,
                                               float* __restrict__ out, int n) {
  __shared__ uint32_t wcnt[4];
  int tid = threadIdx.x, lane = tid & 63, wid = tid >> 6;
  int base = blockIdx.x * ELEMS_K1;
  uint32_t running = rsums[blockIdx.x];
  for (int k = 0; k < ELEMS_K1 / 256; k++) {
    int i = base + k * 256 + tid;
    int wbase = base + k * 256 + wid * 64;
    uint64_t word = (wbase < n) ? mask[wbase / 64] : 0ull;
    bool r = (word >> lane) & 1ull;
    uint32_t inword = (uint32_t)__popcll(word & ((1ull << lane) - 1ull));
    uint32_t wtot = (uint32_t)__popcll(word);
    if (lane == 0) wcnt[wid] = wtot;
    __syncthreads();
    uint32_t woff = 0, tot = 0;
    for (int w = 0; w < 4; w++) { uint32_t s = wcnt[w]; if (w < wid) woff += s; tot += s; }
    if (i < n) {
      float o = x[i];
      if (r) {
        uint32_t rank = running + woff + inword;
        uint2 p = wnd[rank];
        uint32_t v = ((p.x & 0xFFFu) << 5) | (p.y >> 27);
        o = (float)v;
      }
      out[i] = o;
    }
    running += tot;
    __syncthreads();
  }
}

// ---------------------------------------------------------------------------
extern "C" void kernel_launch(void* const* d_in, const int* in_sizes, int n_in,
                              void* d_out, int out_size, void* d_ws, size_t ws_size,
                              hipStream_t stream) {
  const float* x = (const float*)d_in[0];
  float* out = (float*)d_out;
  int n = in_sizes[0];
  (void)n_in; (void)out_size; (void)ws_size;

  uint32_t bk0, bk1, sk0, sk1;
  tf2x32(0u, 42u, 0u, 0u, bk0, bk1);
  tf2x32(0u, 42u, 0u, 1u, sk0, sk1);

  int nBlkK = (n + ELEMS_K1 - 1) / ELEMS_K1;   // 1024

  size_t off = 0;
  auto alloc = [&](size_t bytes) -> void* {
    void* p = (uint8_t*)d_ws + off;
    off += (bytes + 255) & ~(size_t)255;
    return p;
  };
  uint32_t* binCursor = (uint32_t*)alloc((size_t)NBINS * 4);
  uint32_t* binPrefix = (uint32_t*)alloc((size_t)(NBINS + 1) * 4);
  uint32_t* rsums     = (uint32_t*)alloc((size_t)(nBlkK + 1) * 4);
  uint64_t* mask      = (uint64_t*)alloc((size_t)((n + 63) / 64) * 8);   // 4 MB
  uint2*    pairs     = (uint2*)alloc((size_t)NBINS * BINREG * 8);       // 35.7 MB
  uint2*    wnd       = (uint2*)alloc((size_t)NBINS * BINREG * 8);       // 35.7 MB

  hipMemsetAsync(binCursor, 0, (size_t)NBINS * 4, stream);

  k_megalite<<<nBlkK, 256, 0, stream>>>(x, mask, rsums, binCursor, pairs,
                                        bk0, bk1, sk0, sk1, n);
  k_copy256<<<1, 256, 0, stream>>>(binPrefix, binCursor);
  k_scan_single<<<1, 256, 0, stream>>>(binPrefix, (int)NBINS);
  k_scan_single<<<1, 256, 0, stream>>>(rsums, nBlkK);
  k_binsort<<<(int)NBINS, 1024, 0, stream>>>(pairs, binPrefix, wnd);
  k_final<<<nBlkK, 256, 0, stream>>>(x, mask, rsums, wnd, out, n);
}

// Round 6
// 519.913 us; speedup vs baseline: 9.5612x; 9.5612x over previous
//
#include <hip/hip_runtime.h>
#include <stdint.h>

// ---------------------------------------------------------------------------
// JAX threefry2x32 (20 rounds), bit-exact port of jax/_src/prng.py
// ---------------------------------------------------------------------------
static __host__ __device__ inline uint32_t rotl32(uint32_t x, int r) {
  return (x << r) | (x >> (32 - r));
}

static __host__ __device__ inline void tf2x32(uint32_t k0, uint32_t k1,
                                              uint32_t x0, uint32_t x1,
                                              uint32_t& o0, uint32_t& o1) {
  uint32_t k2 = k0 ^ k1 ^ 0x1BD11BDAu;
#define TFR(a) { x0 += x1; x1 = rotl32(x1, a); x1 ^= x0; }
  x0 += k0; x1 += k1;
  TFR(13) TFR(15) TFR(26) TFR(6)
  x0 += k1; x1 += k2 + 1u;
  TFR(17) TFR(29) TFR(16) TFR(24)
  x0 += k2; x1 += k0 + 2u;
  TFR(13) TFR(15) TFR(26) TFR(6)
  x0 += k0; x1 += k1 + 3u;
  TFR(17) TFR(29) TFR(16) TFR(24)
  x0 += k1; x1 += k2 + 4u;
  TFR(13) TFR(15) TFR(26) TFR(6)
  x0 += k2; x1 += k0 + 5u;
#undef TFR
  o0 = x0; o1 = x1;
}

static __device__ inline uint32_t fold_bits(uint32_t k0, uint32_t k1, uint32_t ctr) {
  uint32_t a, b;
  tf2x32(k0, k1, 0u, ctr, a, b);
  return a ^ b;
}

// Candidates: m = bits>>9 < CUT (2^20). Expected 4.19M >= R~3.36M (~440 sigma).
#define CUT       (1u << 20)
#define NBINS     1024u          // coarse bin = m >> 10
#define BINREG    4608u          // per-bin region cap (mean 4095, +8 sigma)
#define ELEMS_K1  32768
#define MASKI     0x07FFFFFFu    // idx field in .y (25 bits used; bits 25,26 = 0)

// pair packing: .x = (m<<12) | (value>>5)    [m:20 | v_hi:12]
//               .y = ((value&31)<<27) | idx  [v_lo:5 | 00 | idx:25]
// fine bucket within bin: c = (.x>>12) & 1023;  tie-break by (.y & MASKI)

// ---------------------------------------------------------------------------
// K1: per 32768-elem block: bernoulli mask + rsums; candidate flags in a 4KB
// LDS bitmask (ballot words); per-bin LDS histogram; reserve bin runs; emit
// packed pairs bin-grouped (coalesced-ish).  Lean LDS (~17KB) -> high occ.
// ---------------------------------------------------------------------------
__global__ __launch_bounds__(256) void k_megalite2(const float* __restrict__ x,
                                                   uint64_t* __restrict__ mask,
                                                   uint32_t* __restrict__ rsums,
                                                   uint32_t* __restrict__ binCursor,
                                                   uint2* __restrict__ pairs,
                                                   uint32_t bk0, uint32_t bk1,
                                                   uint32_t sk0, uint32_t sk1, int n) {
  __shared__ uint64_t lcand[ELEMS_K1 / 64];            // 4 KB candidate bitmask
  __shared__ uint32_t lhist[NBINS], lgbase[NBINS], lcur[NBINS];  // 12 KB
  __shared__ uint32_t wcnt[4];
  int tid = threadIdx.x, lane = tid & 63, wid = tid >> 6;
  int base = blockIdx.x * ELEMS_K1;
  for (int b = tid; b < (int)NBINS; b += 256) lhist[b] = 0;
  __syncthreads();

  uint32_t cnt = 0;
  for (int k = 0; k < ELEMS_K1 / 256; k++) {
    int li = k * 256 + tid;
    int i = base + li;
    bool inb = (i < n);
    float xv = inb ? x[i] : 0.0f;
    bool nonpad = inb && (xv != 0.0f);
    // bernoulli stream
    bool r = false;
    if (inb) {
      uint32_t bb = fold_bits(bk0, bk1, (uint32_t)i);
      float u = __uint_as_float((bb >> 9) | 0x3f800000u) - 1.0f;
      r = (u < 0.1f) && nonpad;
    }
    unsigned long long ball = __ballot(r);
    int wbase = base + k * 256 + wid * 64;
    if (lane == 0 && wbase < n) mask[wbase / 64] = (uint64_t)ball;
    cnt += r ? 1u : 0u;
    // shuffle-key stream: candidate flag + per-bin count
    bool cand = false;
    if (nonpad) {
      uint32_t m = fold_bits(sk0, sk1, (uint32_t)i) >> 9;
      if (m < CUT) { cand = true; atomicAdd(&lhist[m >> 10], 1u); }
    }
    unsigned long long ball2 = __ballot(cand);
    if (lane == 0) lcand[k * 4 + wid] = (uint64_t)ball2;
  }
  // rsums
  for (int d = 32; d >= 1; d >>= 1) cnt += __shfl_down(cnt, d, 64);
  if (lane == 0) wcnt[wid] = cnt;
  __syncthreads();
  if (tid == 0) rsums[blockIdx.x] = wcnt[0] + wcnt[1] + wcnt[2] + wcnt[3];
  // reserve per-bin contiguous runs
  for (int b = tid; b < (int)NBINS; b += 256) {
    uint32_t h = lhist[b];
    lgbase[b] = h ? atomicAdd((unsigned int*)&binCursor[b], h) : 0u;
    lcur[b] = 0u;
  }
  __syncthreads();
  // emission: recompute m for candidates only (~12.5%); x re-read is L2-hot
  for (int k = 0; k < ELEMS_K1 / 256; k++) {
    int li = k * 256 + tid;
    int i = base + li;
    if (i >= n) continue;
    uint64_t word = lcand[li >> 6];
    if (!((word >> (li & 63)) & 1ull)) continue;
    uint32_t m = fold_bits(sk0, sk1, (uint32_t)i) >> 9;
    uint32_t v = (uint32_t)x[i];
    uint32_t bin = m >> 10;
    uint32_t off = atomicAdd(&lcur[bin], 1u) + lgbase[bin];
    if (off < BINREG) {
      pairs[(size_t)bin * BINREG + off] =
          make_uint2((m << 12) | (v >> 5), ((v & 31u) << 27) | (uint32_t)i);
    }
  }
}

// ---------------------------------------------------------------------------
// exclusive scan in place; also writes data[n] = total (alloc n+1!)
// ---------------------------------------------------------------------------
__global__ void k_scan_single(uint32_t* __restrict__ data, int n) {
  __shared__ uint32_t wsum[4];
  int tid = threadIdx.x, lane = tid & 63, wid = tid >> 6;
  uint32_t running = 0;
  for (int base = 0; base < n; base += 256) {
    int i = base + tid;
    uint32_t v = (i < n) ? data[i] : 0u;
    uint32_t incl = v;
    for (int d = 1; d < 64; d <<= 1) {
      uint32_t t = __shfl_up(incl, (unsigned)d, 64);
      if (lane >= d) incl += t;
    }
    if (lane == 63) wsum[wid] = incl;
    __syncthreads();
    uint32_t woff = 0, tot = 0;
    for (int w = 0; w < 4; w++) { uint32_t s = wsum[w]; if (w < wid) woff += s; tot += s; }
    if (i < n) data[i] = running + woff + (incl - v);
    running += tot;
    __syncthreads();
  }
  if (tid == 0) data[n] = running;
}

// ---------------------------------------------------------------------------
// K2: one 256-thread block per bin, fully LDS-resident sort.
//   global pairs (bin region) -> LDS hist(1024) -> block scan ->
//   LDS counting-scatter -> LDS per-bucket insertion (ties by idx) ->
//   coalesced 4B donor-value stream at the bin's global donor offset.
// LDS ~41KB -> 3 blocks/CU; 1024 blocks.
// ---------------------------------------------------------------------------
__global__ __launch_bounds__(256) void k_binsort(const uint2* __restrict__ pairs,
                                                 const uint32_t* __restrict__ binPrefix,
                                                 float* __restrict__ donors) {
  __shared__ uint2    lbuf[BINREG];     // 36.9 KB
  __shared__ uint32_t hist[NBINS];      // 4 KB (1024 fine buckets in this bin)
  __shared__ uint32_t wsums[4];
  int tid = threadIdx.x, lane = tid & 63, wid = tid >> 6;
  uint32_t bin = blockIdx.x;
  uint32_t gbase = binPrefix[bin];
  uint32_t cnt = binPrefix[bin + 1] - gbase;
  if (cnt > BINREG) cnt = BINREG;
  const uint2* src = pairs + (size_t)bin * BINREG;

  for (int c = tid; c < 1024; c += 256) hist[c] = 0;
  __syncthreads();
  // pass 1: histogram (read 1: global)
  for (uint32_t j = tid; j < cnt; j += 256)
    atomicAdd(&hist[(src[j].x >> 12) & 1023u], 1u);
  __syncthreads();
  // block exclusive scan of hist[1024]; thread owns entries [4t, 4t+4)
  uint32_t h0 = hist[4 * tid], h1 = hist[4 * tid + 1],
           h2 = hist[4 * tid + 2], h3 = hist[4 * tid + 3];
  uint32_t tsum = h0 + h1 + h2 + h3;
  uint32_t incl = tsum;
  for (int d = 1; d < 64; d <<= 1) {
    uint32_t t = __shfl_up(incl, (unsigned)d, 64);
    if (lane >= d) incl += t;
  }
  if (lane == 63) wsums[wid] = incl;
  __syncthreads();
  if (wid == 0) {
    uint32_t v = (lane < 4) ? wsums[lane] : 0u;
    uint32_t in2 = v;
    for (int d = 1; d < 4; d <<= 1) {
      uint32_t t = __shfl_up(in2, (unsigned)d, 64);
      if (lane >= d) in2 += t;
    }
    if (lane < 4) wsums[lane] = in2 - v;     // exclusive wave base
  }
  __syncthreads();
  uint32_t texcl = wsums[wid] + (incl - tsum);
  uint32_t e0 = texcl, e1 = e0 + h0, e2 = e1 + h1, e3 = e2 + h2;
  __syncthreads();   // all hist reads done before overwrite
  hist[4 * tid] = e0; hist[4 * tid + 1] = e1;
  hist[4 * tid + 2] = e2; hist[4 * tid + 3] = e3;
  __syncthreads();
  // pass 2: counting-scatter into LDS at exact slots (read 2: L2-hot)
  for (uint32_t j = tid; j < cnt; j += 256) {
    uint2 p = src[j];
    uint32_t c = (p.x >> 12) & 1023u;
    uint32_t lpos = atomicAdd(&hist[c], 1u);
    lbuf[lpos] = p;
  }
  __syncthreads();
  // stabilize ties by idx in LDS (after scatter: hist[c] = end of bucket c)
  for (int c = tid; c < 1024; c += 256) {
    uint32_t lo = (c == 0) ? 0u : hist[c - 1];
    uint32_t hi = hist[c];
    for (uint32_t u = lo + 1; u < hi; u++) {
      uint2 v = lbuf[u];
      uint32_t w = u;
      while (w > lo && (lbuf[w - 1].y & MASKI) > (v.y & MASKI)) {
        lbuf[w] = lbuf[w - 1];
        w--;
      }
      lbuf[w] = v;
    }
  }
  __syncthreads();
  // coalesced donor-value stream
  for (uint32_t j = tid; j < cnt; j += 256) {
    uint2 p = lbuf[j];
    uint32_t v = ((p.x & 0xFFFu) << 5) | (p.y >> 27);
    donors[gbase + j] = (float)v;
  }
}

// ---------------------------------------------------------------------------
// K3: out[i] = repl ? donors[rank] : x[i].  rank reads are sequential.
// Blocking matches K1 (32768 elems) so rsums line up.
// ---------------------------------------------------------------------------
__global__ __launch_bounds__(256) void k_final(const float* __restrict__ x,
                                               const uint64_t* __restrict__ mask,
                                               const uint32_t* __restrict__ rsums,
                                               const float* __restrict__ donors,
                                               float* __restrict__ out, int n) {
  __shared__ uint32_t wcnt[4];
  int tid = threadIdx.x, lane = tid & 63, wid = tid >> 6;
  int base = blockIdx.x * ELEMS_K1;
  uint32_t running = rsums[blockIdx.x];
  for (int k = 0; k < ELEMS_K1 / 256; k++) {
    int i = base + k * 256 + tid;
    int wbase = base + k * 256 + wid * 64;
    uint64_t word = (wbase < n) ? mask[wbase / 64] : 0ull;
    bool r = (word >> lane) & 1ull;
    uint32_t inword = (uint32_t)__popcll(word & ((1ull << lane) - 1ull));
    uint32_t wtot = (uint32_t)__popcll(word);
    if (lane == 0) wcnt[wid] = wtot;
    __syncthreads();
    uint32_t woff = 0, tot = 0;
    for (int w = 0; w < 4; w++) { uint32_t s = wcnt[w]; if (w < wid) woff += s; tot += s; }
    if (i < n) {
      float o = x[i];
      if (r) {
        uint32_t rank = running + woff + inword;
        o = donors[rank];
      }
      out[i] = o;
    }
    running += tot;
    __syncthreads();
  }
}

// ---------------------------------------------------------------------------
extern "C" void kernel_launch(void* const* d_in, const int* in_sizes, int n_in,
                              void* d_out, int out_size, void* d_ws, size_t ws_size,
                              hipStream_t stream) {
  const float* x = (const float*)d_in[0];
  float* out = (float*)d_out;
  int n = in_sizes[0];
  (void)n_in; (void)out_size; (void)ws_size;

  uint32_t bk0, bk1, sk0, sk1;
  tf2x32(0u, 42u, 0u, 0u, bk0, bk1);
  tf2x32(0u, 42u, 0u, 1u, sk0, sk1);

  int nBlkK = (n + ELEMS_K1 - 1) / ELEMS_K1;   // 1024

  size_t off = 0;
  auto alloc = [&](size_t bytes) -> void* {
    void* p = (uint8_t*)d_ws + off;
    off += (bytes + 255) & ~(size_t)255;
    return p;
  };
  uint32_t* binCursor = (uint32_t*)alloc((size_t)(NBINS + 1) * 4);  // counts -> prefix
  uint32_t* rsums     = (uint32_t*)alloc((size_t)(nBlkK + 1) * 4);
  uint64_t* mask      = (uint64_t*)alloc((size_t)((n + 63) / 64) * 8);     // 4 MB
  uint2*    pairs     = (uint2*)alloc((size_t)NBINS * BINREG * 8);         // 37.7 MB
  float*    donors    = (float*)alloc((size_t)NBINS * BINREG * 4);         // 18.9 MB

  hipMemsetAsync(binCursor, 0, (size_t)NBINS * 4, stream);

  k_megalite2<<<nBlkK, 256, 0, stream>>>(x, mask, rsums, binCursor, pairs,
                                         bk0, bk1, sk0, sk1, n);
  k_scan_single<<<1, 256, 0, stream>>>(binCursor, (int)NBINS);  // counts -> exclusive prefix (+total)
  k_scan_single<<<1, 256, 0, stream>>>(rsums, nBlkK);
  k_binsort<<<(int)NBINS, 256, 0, stream>>>(pairs, binCursor, donors);
  k_final<<<nBlkK, 256, 0, stream>>>(x, mask, rsums, donors, out, n);
}

// Round 7
// 479.746 us; speedup vs baseline: 10.3617x; 1.0837x over previous
//
#include <hip/hip_runtime.h>
#include <stdint.h>

// ---------------------------------------------------------------------------
// JAX threefry2x32 (20 rounds), bit-exact port of jax/_src/prng.py
// ---------------------------------------------------------------------------
static __host__ __device__ inline uint32_t rotl32(uint32_t x, int r) {
  return (x << r) | (x >> (32 - r));
}

static __host__ __device__ inline void tf2x32(uint32_t k0, uint32_t k1,
                                              uint32_t x0, uint32_t x1,
                                              uint32_t& o0, uint32_t& o1) {
  uint32_t k2 = k0 ^ k1 ^ 0x1BD11BDAu;
#define TFR(a) { x0 += x1; x1 = rotl32(x1, a); x1 ^= x0; }
  x0 += k0; x1 += k1;
  TFR(13) TFR(15) TFR(26) TFR(6)
  x0 += k1; x1 += k2 + 1u;
  TFR(17) TFR(29) TFR(16) TFR(24)
  x0 += k2; x1 += k0 + 2u;
  TFR(13) TFR(15) TFR(26) TFR(6)
  x0 += k0; x1 += k1 + 3u;
  TFR(17) TFR(29) TFR(16) TFR(24)
  x0 += k1; x1 += k2 + 4u;
  TFR(13) TFR(15) TFR(26) TFR(6)
  x0 += k2; x1 += k0 + 5u;
#undef TFR
  o0 = x0; o1 = x1;
}

static __device__ inline uint32_t fold_bits(uint32_t k0, uint32_t k1, uint32_t ctr) {
  uint32_t a, b;
  tf2x32(k0, k1, 0u, ctr, a, b);
  return a ^ b;
}

// Candidates: m = bits>>9 < CUT (2^20). Expected 4.19M >= R~3.36M (~440 sigma).
#define CUT       (1u << 20)
#define NBINS     1024u          // fine bin = m >> 10
#define ELEMS_K1  32768
#define POOLCAP   4608u          // per-block LDS pool (mean 4096, +8.5 sigma)
#define WIN       8192           // regroup window (entries)
#define MASKI     0x07FFFFFFu

// pair packing: .x = (m<<12) | (value>>5)    [m:20 | v_hi:12]  (bin = .x>>22)
//               .y = ((value&31)<<27) | idx  [v_lo:5 | 00 | idx:25]
// value in [0,100000) fits 17 bits; n = 2^25 fits 25 bits.

// ---------------------------------------------------------------------------
// K1: threefry + mask/rsums + LDS pool append + coalesced dense dump stream.
// One global atomic per block. Lean LDS (~37KB) -> 4 blocks/CU.
// ---------------------------------------------------------------------------
__global__ __launch_bounds__(256) void k_gen(const float* __restrict__ x,
                                             uint64_t* __restrict__ mask,
                                             uint32_t* __restrict__ rsums,
                                             uint32_t* __restrict__ dumpCursor,
                                             uint2* __restrict__ dump, uint32_t capdump,
                                             uint32_t bk0, uint32_t bk1,
                                             uint32_t sk0, uint32_t sk1, int n) {
  __shared__ uint2 pool[POOLCAP];        // 36.9 KB
  __shared__ uint32_t wcnt[4];
  __shared__ uint32_t lpoolCnt, lgbase;
  int tid = threadIdx.x, lane = tid & 63, wid = tid >> 6;
  int base = blockIdx.x * ELEMS_K1;
  if (tid == 0) lpoolCnt = 0;
  __syncthreads();

  uint32_t cnt = 0;
  for (int k = 0; k < ELEMS_K1 / 256; k++) {
    int i = base + k * 256 + tid;
    bool inb = (i < n);
    float xv = inb ? x[i] : 0.0f;
    bool nonpad = inb && (xv != 0.0f);
    // bernoulli stream (independent chain 1)
    bool r = false;
    if (inb) {
      uint32_t bb = fold_bits(bk0, bk1, (uint32_t)i);
      float u = __uint_as_float((bb >> 9) | 0x3f800000u) - 1.0f;
      r = (u < 0.1f) && nonpad;
    }
    unsigned long long ball = __ballot(r);
    int wbase = base + k * 256 + wid * 64;
    if (lane == 0 && wbase < n) mask[wbase / 64] = (uint64_t)ball;
    cnt += r ? 1u : 0u;
    // shuffle-key stream (independent chain 2)
    bool cand = false; uint32_t m = 0;
    if (nonpad) {
      m = fold_bits(sk0, sk1, (uint32_t)i) >> 9;
      cand = (m < CUT);
    }
    // wave-aggregated LDS pool append
    unsigned long long ball2 = __ballot(cand);
    uint32_t cnt2 = (uint32_t)__popcll(ball2);
    uint32_t pb = 0;
    if (lane == 0 && cnt2) pb = atomicAdd(&lpoolCnt, cnt2);
    pb = __shfl(pb, 0);
    if (cand) {
      uint32_t slot = pb + (uint32_t)__popcll(ball2 & ((1ull << lane) - 1ull));
      if (slot < POOLCAP) {
        uint32_t v = (uint32_t)xv;
        pool[slot] = make_uint2((m << 12) | (v >> 5), ((v & 31u) << 27) | (uint32_t)i);
      }
    }
  }
  // rsums
  for (int d = 32; d >= 1; d >>= 1) cnt += __shfl_down(cnt, d, 64);
  if (lane == 0) wcnt[wid] = cnt;
  __syncthreads();
  if (tid == 0) {
    rsums[blockIdx.x] = wcnt[0] + wcnt[1] + wcnt[2] + wcnt[3];
    uint32_t pc = lpoolCnt; if (pc > POOLCAP) pc = POOLCAP;
    lgbase = atomicAdd((unsigned int*)dumpCursor, pc);   // ONE atomic per block
  }
  __syncthreads();
  uint32_t pc = lpoolCnt; if (pc > POOLCAP) pc = POOLCAP;
  uint32_t gb = lgbase;
  for (uint32_t j = tid; j < pc; j += 256) {
    uint32_t d = gb + j;
    if (d < capdump) dump[d] = pool[j];                  // coalesced stream
  }
}

// ---------------------------------------------------------------------------
// exclusive scan in place; also writes data[n] = total (alloc n+1!)
// ---------------------------------------------------------------------------
__global__ void k_scan_single(uint32_t* __restrict__ data, int n) {
  __shared__ uint32_t wsum[4];
  int tid = threadIdx.x, lane = tid & 63, wid = tid >> 6;
  uint32_t running = 0;
  for (int base = 0; base < n; base += 256) {
    int i = base + tid;
    uint32_t v = (i < n) ? data[i] : 0u;
    uint32_t incl = v;
    for (int d = 1; d < 64; d <<= 1) {
      uint32_t t = __shfl_up(incl, (unsigned)d, 64);
      if (lane >= d) incl += t;
    }
    if (lane == 63) wsum[wid] = incl;
    __syncthreads();
    uint32_t woff = 0, tot = 0;
    for (int w = 0; w < 4; w++) { uint32_t s = wsum[w]; if (w < wid) woff += s; tot += s; }
    if (i < n) data[i] = running + woff + (incl - v);
    running += tot;
    __syncthreads();
  }
  if (tid == 0) data[n] = running;
}

// ---------------------------------------------------------------------------
// K2: regroup dense dump -> 1024 fixed-stride fine-bin regions.
// Window of 8192 entries: regs -> LDS hist -> reserve runs -> block scan ->
// LDS reorder -> bin-grouped writes (runs of ~8 = 64B).
// ---------------------------------------------------------------------------
__global__ __launch_bounds__(256) void k_regroup(const uint2* __restrict__ dump,
                                                 const uint32_t* __restrict__ dumpCursor,
                                                 uint32_t capdump,
                                                 uint32_t* __restrict__ fineCursor,
                                                 uint2* __restrict__ fine, uint32_t stride) {
  __shared__ uint2    pool2[WIN];        // 65.5 KB
  __shared__ uint32_t lhist[NBINS];      // 4 KB: counts -> prefix -> running -> end
  __shared__ uint32_t lgbase[NBINS];     // 4 KB
  __shared__ uint32_t wsums[4];
  int tid = threadIdx.x, lane = tid & 63, wid = tid >> 6;
  uint32_t total = dumpCursor[0];
  if (total > capdump) total = capdump;
  uint32_t wbase = blockIdx.x * (uint32_t)WIN;
  if (wbase >= total) return;
  uint32_t valid = total - wbase;
  if (valid > WIN) valid = WIN;

  for (int b = tid; b < (int)NBINS; b += 256) lhist[b] = 0;
  __syncthreads();
  // load to registers (coalesced) + histogram
  uint2 e[WIN / 256];
#pragma unroll
  for (int q = 0; q < WIN / 256; q++) {
    uint32_t j = (uint32_t)q * 256u + (uint32_t)tid;
    e[q] = (j < valid) ? dump[wbase + j] : make_uint2(0u, 0u);
    if (j < valid) atomicAdd(&lhist[e[q].x >> 22], 1u);
  }
  __syncthreads();
  // reserve global runs per bin
  for (int b = tid; b < (int)NBINS; b += 256) {
    uint32_t h = lhist[b];
    lgbase[b] = h ? atomicAdd((unsigned int*)&fineCursor[b], h) : 0u;
  }
  __syncthreads();
  // block exclusive scan of lhist[1024]; thread owns entries [4t, 4t+4)
  uint32_t h0 = lhist[4 * tid], h1 = lhist[4 * tid + 1],
           h2 = lhist[4 * tid + 2], h3 = lhist[4 * tid + 3];
  uint32_t tsum = h0 + h1 + h2 + h3;
  uint32_t incl = tsum;
  for (int d = 1; d < 64; d <<= 1) {
    uint32_t t = __shfl_up(incl, (unsigned)d, 64);
    if (lane >= d) incl += t;
  }
  if (lane == 63) wsums[wid] = incl;
  __syncthreads();
  if (wid == 0) {
    uint32_t v = (lane < 4) ? wsums[lane] : 0u;
    uint32_t in2 = v;
    for (int d = 1; d < 4; d <<= 1) {
      uint32_t t = __shfl_up(in2, (unsigned)d, 64);
      if (lane >= d) in2 += t;
    }
    if (lane < 4) wsums[lane] = in2 - v;   // exclusive wave base
  }
  __syncthreads();
  uint32_t texcl = wsums[wid] + (incl - tsum);
  uint32_t e0 = texcl, e1 = e0 + h0, e2 = e1 + h1, e3 = e2 + h2;
  __syncthreads();   // all hist reads done before overwrite
  lhist[4 * tid] = e0; lhist[4 * tid + 1] = e1;
  lhist[4 * tid + 2] = e2; lhist[4 * tid + 3] = e3;
  __syncthreads();
  // scatter registers -> pool2 grouped by bin
#pragma unroll
  for (int q = 0; q < WIN / 256; q++) {
    uint32_t j = (uint32_t)q * 256u + (uint32_t)tid;
    if (j < valid) {
      uint32_t b = e[q].x >> 22;
      uint32_t lpos = atomicAdd(&lhist[b], 1u);
      pool2[lpos] = e[q];
    }
  }
  __syncthreads();
  // bin-grouped global writes; start[b] = (b==0)?0:lhist[b-1] (= end[b-1])
  for (uint32_t j = tid; j < valid; j += 256) {
    uint2 p = pool2[j];
    uint32_t b = p.x >> 22;
    uint32_t st = (b == 0) ? 0u : lhist[b - 1];
    uint32_t dst = lgbase[b] + (j - st);
    if (dst < stride) fine[(size_t)b * stride + dst] = p;
  }
}

// ---------------------------------------------------------------------------
// K3: one 256-thread block per bin, fully LDS-resident sort (proven in R6).
// ---------------------------------------------------------------------------
__global__ __launch_bounds__(256) void k_binsort(const uint2* __restrict__ pairs,
                                                 const uint32_t* __restrict__ binPrefix,
                                                 float* __restrict__ donors, uint32_t stride) {
  __shared__ uint2    lbuf[POOLCAP];    // 36.9 KB
  __shared__ uint32_t hist[NBINS];      // 4 KB (1024 fine buckets: m & 1023)
  __shared__ uint32_t wsums[4];
  int tid = threadIdx.x, lane = tid & 63, wid = tid >> 6;
  uint32_t bin = blockIdx.x;
  uint32_t gbase = binPrefix[bin];
  uint32_t cnt = binPrefix[bin + 1] - gbase;
  if (cnt > stride) cnt = stride;
  if (cnt > POOLCAP) cnt = POOLCAP;
  const uint2* src = pairs + (size_t)bin * stride;

  for (int c = tid; c < 1024; c += 256) hist[c] = 0;
  __syncthreads();
  for (uint32_t j = tid; j < cnt; j += 256)
    atomicAdd(&hist[(src[j].x >> 12) & 1023u], 1u);
  __syncthreads();
  uint32_t h0 = hist[4 * tid], h1 = hist[4 * tid + 1],
           h2 = hist[4 * tid + 2], h3 = hist[4 * tid + 3];
  uint32_t tsum = h0 + h1 + h2 + h3;
  uint32_t incl = tsum;
  for (int d = 1; d < 64; d <<= 1) {
    uint32_t t = __shfl_up(incl, (unsigned)d, 64);
    if (lane >= d) incl += t;
  }
  if (lane == 63) wsums[wid] = incl;
  __syncthreads();
  if (wid == 0) {
    uint32_t v = (lane < 4) ? wsums[lane] : 0u;
    uint32_t in2 = v;
    for (int d = 1; d < 4; d <<= 1) {
      uint32_t t = __shfl_up(in2, (unsigned)d, 64);
      if (lane >= d) in2 += t;
    }
    if (lane < 4) wsums[lane] = in2 - v;
  }
  __syncthreads();
  uint32_t texcl = wsums[wid] + (incl - tsum);
  uint32_t e0 = texcl, e1 = e0 + h0, e2 = e1 + h1, e3 = e2 + h2;
  __syncthreads();
  hist[4 * tid] = e0; hist[4 * tid + 1] = e1;
  hist[4 * tid + 2] = e2; hist[4 * tid + 3] = e3;
  __syncthreads();
  for (uint32_t j = tid; j < cnt; j += 256) {
    uint2 p = src[j];
    uint32_t c = (p.x >> 12) & 1023u;
    uint32_t lpos = atomicAdd(&hist[c], 1u);
    lbuf[lpos] = p;
  }
  __syncthreads();
  for (int c = tid; c < 1024; c += 256) {
    uint32_t lo = (c == 0) ? 0u : hist[c - 1];
    uint32_t hi = hist[c];
    for (uint32_t u = lo + 1; u < hi; u++) {
      uint2 v = lbuf[u];
      uint32_t w = u;
      while (w > lo && (lbuf[w - 1].y & MASKI) > (v.y & MASKI)) {
        lbuf[w] = lbuf[w - 1];
        w--;
      }
      lbuf[w] = v;
    }
  }
  __syncthreads();
  for (uint32_t j = tid; j < cnt; j += 256) {
    uint2 p = lbuf[j];
    uint32_t v = ((p.x & 0xFFFu) << 5) | (p.y >> 27);
    donors[gbase + j] = (float)v;
  }
}

// ---------------------------------------------------------------------------
// K4: out[i] = repl ? donors[rank] : x[i] (proven in R6).
// ---------------------------------------------------------------------------
__global__ __launch_bounds__(256) void k_final(const float* __restrict__ x,
                                               const uint64_t* __restrict__ mask,
                                               const uint32_t* __restrict__ rsums,
                                               const float* __restrict__ donors,
                                               float* __restrict__ out, int n) {
  __shared__ uint32_t wcnt[4];
  int tid = threadIdx.x, lane = tid & 63, wid = tid >> 6;
  int base = blockIdx.x * ELEMS_K1;
  uint32_t running = rsums[blockIdx.x];
  for (int k = 0; k < ELEMS_K1 / 256; k++) {
    int i = base + k * 256 + tid;
    int wbase = base + k * 256 + wid * 64;
    uint64_t word = (wbase < n) ? mask[wbase / 64] : 0ull;
    bool r = (word >> lane) & 1ull;
    uint32_t inword = (uint32_t)__popcll(word & ((1ull << lane) - 1ull));
    uint32_t wtot = (uint32_t)__popcll(word);
    if (lane == 0) wcnt[wid] = wtot;
    __syncthreads();
    uint32_t woff = 0, tot = 0;
    for (int w = 0; w < 4; w++) { uint32_t s = wcnt[w]; if (w < wid) woff += s; tot += s; }
    if (i < n) {
      float o = x[i];
      if (r) {
        uint32_t rank = running + woff + inword;
        o = donors[rank];
      }
      out[i] = o;
    }
    running += tot;
    __syncthreads();
  }
}

// ---------------------------------------------------------------------------
extern "C" void kernel_launch(void* const* d_in, const int* in_sizes, int n_in,
                              void* d_out, int out_size, void* d_ws, size_t ws_size,
                              hipStream_t stream) {
  const float* x = (const float*)d_in[0];
  float* out = (float*)d_out;
  int n = in_sizes[0];
  (void)n_in; (void)out_size;

  uint32_t bk0, bk1, sk0, sk1;
  tf2x32(0u, 42u, 0u, 0u, bk0, bk1);
  tf2x32(0u, 42u, 0u, 1u, sk0, sk1);

  int nBlkK = (n + ELEMS_K1 - 1) / ELEMS_K1;   // 1024

  size_t off = 0;
  auto alloc = [&](size_t bytes) -> void* {
    void* p = (uint8_t*)d_ws + off;
    off += (bytes + 255) & ~(size_t)255;
    return p;
  };
  uint32_t* dumpCursor = (uint32_t*)alloc(4);                          // zeroed
  uint32_t* fineCursor = (uint32_t*)alloc((size_t)(NBINS + 1) * 4);    // zeroed
  uint32_t* rsums      = (uint32_t*)alloc((size_t)(nBlkK + 1) * 4);
  uint64_t* mask       = (uint64_t*)alloc((size_t)((n + 63) / 64) * 8); // 4 MB
  size_t baseOff = off;

  // ws-adaptive caps (proven ws >= 75.5 MB from R5; prefer generous if bigger)
  size_t avail = (ws_size > baseOff) ? (ws_size - baseOff) : 0;
  uint32_t capdump, stride;
  if (avail >= ((size_t)4718592 + (size_t)NBINS * 4608) * 8 + 1024) {
    capdump = 4718592u; stride = 4608u;              // +270 sigma / +8 sigma
  } else if (avail >= ((size_t)4390912 + (size_t)NBINS * 4512) * 8 + 1024) {
    capdump = 4390912u; stride = 4512u;              // +102 sigma / +6.5 sigma
  } else {
    capdump = 4259840u; stride = 4480u;              // +34 sigma / +6 sigma
  }
  uint2* dump = (uint2*)alloc((size_t)capdump * 8);
  uint2* fine = (uint2*)alloc((size_t)NBINS * stride * 8);
  float* donors = (float*)dump;   // alias: dump dead after k_regroup

  // zero the two cursor blocks (adjacent, tiny)
  hipMemsetAsync(dumpCursor, 0, (size_t)((NBINS + 2) * 4 + 512), stream);

  k_gen<<<nBlkK, 256, 0, stream>>>(x, mask, rsums, dumpCursor, dump, capdump,
                                   bk0, bk1, sk0, sk1, n);
  k_scan_single<<<1, 256, 0, stream>>>(rsums, nBlkK);
  int nWin = (int)((capdump + WIN - 1) / WIN);
  k_regroup<<<nWin, 256, 0, stream>>>(dump, dumpCursor, capdump, fineCursor, fine, stride);
  k_scan_single<<<1, 256, 0, stream>>>(fineCursor, (int)NBINS);
  k_binsort<<<(int)NBINS, 256, 0, stream>>>(fine, fineCursor, donors, stride);
  k_final<<<nBlkK, 256, 0, stream>>>(x, mask, rsums, donors, out, n);
}

// Round 8
// 396.442 us; speedup vs baseline: 12.5390x; 1.2101x over previous
//
#include <hip/hip_runtime.h>
#include <stdint.h>

// ---------------------------------------------------------------------------
// JAX threefry2x32 (20 rounds), bit-exact port of jax/_src/prng.py
// ---------------------------------------------------------------------------
static __host__ __device__ inline uint32_t rotl32(uint32_t x, int r) {
  return (x << r) | (x >> (32 - r));
}

static __host__ __device__ inline void tf2x32(uint32_t k0, uint32_t k1,
                                              uint32_t x0, uint32_t x1,
                                              uint32_t& o0, uint32_t& o1) {
  uint32_t k2 = k0 ^ k1 ^ 0x1BD11BDAu;
#define TFR(a) { x0 += x1; x1 = rotl32(x1, a); x1 ^= x0; }
  x0 += k0; x1 += k1;
  TFR(13) TFR(15) TFR(26) TFR(6)
  x0 += k1; x1 += k2 + 1u;
  TFR(17) TFR(29) TFR(16) TFR(24)
  x0 += k2; x1 += k0 + 2u;
  TFR(13) TFR(15) TFR(26) TFR(6)
  x0 += k0; x1 += k1 + 3u;
  TFR(17) TFR(29) TFR(16) TFR(24)
  x0 += k1; x1 += k2 + 4u;
  TFR(13) TFR(15) TFR(26) TFR(6)
  x0 += k2; x1 += k0 + 5u;
#undef TFR
  o0 = x0; o1 = x1;
}

static __device__ inline uint32_t fold_bits(uint32_t k0, uint32_t k1, uint32_t ctr) {
  uint32_t a, b;
  tf2x32(k0, k1, 0u, ctr, a, b);
  return a ^ b;
}

// Candidates: m = bits>>9 < CUT (2^20). Expected 4.19M >= R~3.36M (~440 sigma).
#define CUT       (1u << 20)
#define NBINS     1024u          // fine bin = m >> 10
#define ELEMS_G   16384          // k_gen / k_final block span
#define GPOOL     2560u          // k_gen LDS pool (mean 2048, +12 sigma)
#define BSCAP     4608u          // binsort LDS buf (bin mean 4095, +8 sigma)
#define WIN       8192           // regroup window (entries)
#define MASKI     0x07FFFFFFu
// bernoulli: u < 0.1f  <=>  mant < 838861  (exact; 0.1f = 0x3DCCCCCD)
#define BERN_THR  838861u

// pair packing: .x = (m<<12) | (value>>5)    [m:20 | v_hi:12]  (bin = .x>>22)
//               .y = ((value&31)<<27) | idx  [v_lo:5 | 00 | idx:25]

// ---------------------------------------------------------------------------
// K1: threefry + mask/rsums + LDS pool append + coalesced dense dump stream.
// Lean LDS (~20.7KB) -> 7 blocks/CU.  One global atomic per block.
// ---------------------------------------------------------------------------
__global__ __launch_bounds__(256) void k_gen(const float* __restrict__ x,
                                             uint64_t* __restrict__ mask,
                                             uint32_t* __restrict__ rsums,
                                             uint32_t* __restrict__ dumpCursor,
                                             uint2* __restrict__ dump, uint32_t capdump,
                                             uint32_t bk0, uint32_t bk1,
                                             uint32_t sk0, uint32_t sk1, int n) {
  __shared__ uint2 pool[GPOOL];          // 20.5 KB
  __shared__ uint32_t wcnt[4];
  __shared__ uint32_t lpoolCnt, lgbase;
  int tid = threadIdx.x, lane = tid & 63, wid = tid >> 6;
  int base = blockIdx.x * ELEMS_G;
  if (tid == 0) lpoolCnt = 0;
  __syncthreads();

  uint32_t cnt = 0;
  for (int k = 0; k < ELEMS_G / 256; k++) {
    int i = base + k * 256 + tid;
    bool inb = (i < n);
    float xv = inb ? x[i] : 0.0f;
    bool nonpad = inb && (xv != 0.0f);
    // bernoulli stream (integer compare, bit-exact)
    bool r = false;
    if (inb) {
      uint32_t bb = fold_bits(bk0, bk1, (uint32_t)i);
      r = ((bb >> 9) < BERN_THR) && nonpad;
    }
    unsigned long long ball = __ballot(r);
    int wbase = base + k * 256 + wid * 64;
    if (lane == 0 && wbase < n) mask[wbase / 64] = (uint64_t)ball;
    cnt += r ? 1u : 0u;
    // shuffle-key stream
    bool cand = false; uint32_t m = 0;
    if (nonpad) {
      m = fold_bits(sk0, sk1, (uint32_t)i) >> 9;
      cand = (m < CUT);
    }
    // wave-aggregated LDS pool append
    unsigned long long ball2 = __ballot(cand);
    uint32_t cnt2 = (uint32_t)__popcll(ball2);
    uint32_t pb = 0;
    if (lane == 0 && cnt2) pb = atomicAdd(&lpoolCnt, cnt2);
    pb = __shfl(pb, 0);
    if (cand) {
      uint32_t slot = pb + (uint32_t)__popcll(ball2 & ((1ull << lane) - 1ull));
      if (slot < GPOOL) {
        uint32_t v = (uint32_t)xv;
        pool[slot] = make_uint2((m << 12) | (v >> 5), ((v & 31u) << 27) | (uint32_t)i);
      }
    }
  }
  // rsums
  for (int d = 32; d >= 1; d >>= 1) cnt += __shfl_down(cnt, d, 64);
  if (lane == 0) wcnt[wid] = cnt;
  __syncthreads();
  if (tid == 0) {
    rsums[blockIdx.x] = wcnt[0] + wcnt[1] + wcnt[2] + wcnt[3];
    uint32_t pc = lpoolCnt; if (pc > GPOOL) pc = GPOOL;
    lgbase = atomicAdd((unsigned int*)dumpCursor, pc);   // ONE atomic per block
  }
  __syncthreads();
  uint32_t pc = lpoolCnt; if (pc > GPOOL) pc = GPOOL;
  uint32_t gb = lgbase;
  for (uint32_t j = tid; j < pc; j += 256) {
    uint32_t d = gb + j;
    if (d < capdump) dump[d] = pool[j];                  // coalesced stream
  }
}

// ---------------------------------------------------------------------------
// exclusive scan in place; also writes data[n] = total (alloc n+1!)
// ---------------------------------------------------------------------------
__global__ void k_scan_single(uint32_t* __restrict__ data, int n) {
  __shared__ uint32_t wsum[4];
  int tid = threadIdx.x, lane = tid & 63, wid = tid >> 6;
  uint32_t running = 0;
  for (int base = 0; base < n; base += 256) {
    int i = base + tid;
    uint32_t v = (i < n) ? data[i] : 0u;
    uint32_t incl = v;
    for (int d = 1; d < 64; d <<= 1) {
      uint32_t t = __shfl_up(incl, (unsigned)d, 64);
      if (lane >= d) incl += t;
    }
    if (lane == 63) wsum[wid] = incl;
    __syncthreads();
    uint32_t woff = 0, tot = 0;
    for (int w = 0; w < 4; w++) { uint32_t s = wsum[w]; if (w < wid) woff += s; tot += s; }
    if (i < n) data[i] = running + woff + (incl - v);
    running += tot;
    __syncthreads();
  }
  if (tid == 0) data[n] = running;
}

// ---------------------------------------------------------------------------
// K2: regroup dense dump -> 1024 fixed-stride fine-bin regions (proven R7).
// ---------------------------------------------------------------------------
__global__ __launch_bounds__(256) void k_regroup(const uint2* __restrict__ dump,
                                                 const uint32_t* __restrict__ dumpCursor,
                                                 uint32_t capdump,
                                                 uint32_t* __restrict__ fineCursor,
                                                 uint2* __restrict__ fine, uint32_t stride) {
  __shared__ uint2    pool2[WIN];        // 65.5 KB
  __shared__ uint32_t lhist[NBINS];      // 4 KB
  __shared__ uint32_t lgbase[NBINS];     // 4 KB
  __shared__ uint32_t wsums[4];
  int tid = threadIdx.x, lane = tid & 63, wid = tid >> 6;
  uint32_t total = dumpCursor[0];
  if (total > capdump) total = capdump;
  uint32_t wbase = blockIdx.x * (uint32_t)WIN;
  if (wbase >= total) return;
  uint32_t valid = total - wbase;
  if (valid > WIN) valid = WIN;

  for (int b = tid; b < (int)NBINS; b += 256) lhist[b] = 0;
  __syncthreads();
  uint2 e[WIN / 256];
#pragma unroll
  for (int q = 0; q < WIN / 256; q++) {
    uint32_t j = (uint32_t)q * 256u + (uint32_t)tid;
    e[q] = (j < valid) ? dump[wbase + j] : make_uint2(0u, 0u);
    if (j < valid) atomicAdd(&lhist[e[q].x >> 22], 1u);
  }
  __syncthreads();
  for (int b = tid; b < (int)NBINS; b += 256) {
    uint32_t h = lhist[b];
    lgbase[b] = h ? atomicAdd((unsigned int*)&fineCursor[b], h) : 0u;
  }
  __syncthreads();
  uint32_t h0 = lhist[4 * tid], h1 = lhist[4 * tid + 1],
           h2 = lhist[4 * tid + 2], h3 = lhist[4 * tid + 3];
  uint32_t tsum = h0 + h1 + h2 + h3;
  uint32_t incl = tsum;
  for (int d = 1; d < 64; d <<= 1) {
    uint32_t t = __shfl_up(incl, (unsigned)d, 64);
    if (lane >= d) incl += t;
  }
  if (lane == 63) wsums[wid] = incl;
  __syncthreads();
  if (wid == 0) {
    uint32_t v = (lane < 4) ? wsums[lane] : 0u;
    uint32_t in2 = v;
    for (int d = 1; d < 4; d <<= 1) {
      uint32_t t = __shfl_up(in2, (unsigned)d, 64);
      if (lane >= d) in2 += t;
    }
    if (lane < 4) wsums[lane] = in2 - v;
  }
  __syncthreads();
  uint32_t texcl = wsums[wid] + (incl - tsum);
  uint32_t e0 = texcl, e1 = e0 + h0, e2 = e1 + h1, e3 = e2 + h2;
  __syncthreads();
  lhist[4 * tid] = e0; lhist[4 * tid + 1] = e1;
  lhist[4 * tid + 2] = e2; lhist[4 * tid + 3] = e3;
  __syncthreads();
#pragma unroll
  for (int q = 0; q < WIN / 256; q++) {
    uint32_t j = (uint32_t)q * 256u + (uint32_t)tid;
    if (j < valid) {
      uint32_t b = e[q].x >> 22;
      uint32_t lpos = atomicAdd(&lhist[b], 1u);
      pool2[lpos] = e[q];
    }
  }
  __syncthreads();
  for (uint32_t j = tid; j < valid; j += 256) {
    uint2 p = pool2[j];
    uint32_t b = p.x >> 22;
    uint32_t st = (b == 0) ? 0u : lhist[b - 1];
    uint32_t dst = lgbase[b] + (j - st);
    if (dst < stride) fine[(size_t)b * stride + dst] = p;
  }
}

// ---------------------------------------------------------------------------
// K3: one 256-thread block per bin, fully LDS-resident sort (proven R6/R7).
// ---------------------------------------------------------------------------
__global__ __launch_bounds__(256) void k_binsort(const uint2* __restrict__ pairs,
                                                 const uint32_t* __restrict__ binPrefix,
                                                 float* __restrict__ donors, uint32_t stride) {
  __shared__ uint2    lbuf[BSCAP];      // 36.9 KB
  __shared__ uint32_t hist[NBINS];      // 4 KB
  __shared__ uint32_t wsums[4];
  int tid = threadIdx.x, lane = tid & 63, wid = tid >> 6;
  uint32_t bin = blockIdx.x;
  uint32_t gbase = binPrefix[bin];
  uint32_t cnt = binPrefix[bin + 1] - gbase;
  if (cnt > stride) cnt = stride;
  if (cnt > BSCAP) cnt = BSCAP;
  const uint2* src = pairs + (size_t)bin * stride;

  for (int c = tid; c < 1024; c += 256) hist[c] = 0;
  __syncthreads();
  for (uint32_t j = tid; j < cnt; j += 256)
    atomicAdd(&hist[(src[j].x >> 12) & 1023u], 1u);
  __syncthreads();
  uint32_t h0 = hist[4 * tid], h1 = hist[4 * tid + 1],
           h2 = hist[4 * tid + 2], h3 = hist[4 * tid + 3];
  uint32_t tsum = h0 + h1 + h2 + h3;
  uint32_t incl = tsum;
  for (int d = 1; d < 64; d <<= 1) {
    uint32_t t = __shfl_up(incl, (unsigned)d, 64);
    if (lane >= d) incl += t;
  }
  if (lane == 63) wsums[wid] = incl;
  __syncthreads();
  if (wid == 0) {
    uint32_t v = (lane < 4) ? wsums[lane] : 0u;
    uint32_t in2 = v;
    for (int d = 1; d < 4; d <<= 1) {
      uint32_t t = __shfl_up(in2, (unsigned)d, 64);
      if (lane >= d) in2 += t;
    }
    if (lane < 4) wsums[lane] = in2 - v;
  }
  __syncthreads();
  uint32_t texcl = wsums[wid] + (incl - tsum);
  uint32_t e0 = texcl, e1 = e0 + h0, e2 = e1 + h1, e3 = e2 + h2;
  __syncthreads();
  hist[4 * tid] = e0; hist[4 * tid + 1] = e1;
  hist[4 * tid + 2] = e2; hist[4 * tid + 3] = e3;
  __syncthreads();
  for (uint32_t j = tid; j < cnt; j += 256) {
    uint2 p = src[j];
    uint32_t c = (p.x >> 12) & 1023u;
    uint32_t lpos = atomicAdd(&hist[c], 1u);
    lbuf[lpos] = p;
  }
  __syncthreads();
  for (int c = tid; c < 1024; c += 256) {
    uint32_t lo = (c == 0) ? 0u : hist[c - 1];
    uint32_t hi = hist[c];
    for (uint32_t u = lo + 1; u < hi; u++) {
      uint2 v = lbuf[u];
      uint32_t w = u;
      while (w > lo && (lbuf[w - 1].y & MASKI) > (v.y & MASKI)) {
        lbuf[w] = lbuf[w - 1];
        w--;
      }
      lbuf[w] = v;
    }
  }
  __syncthreads();
  for (uint32_t j = tid; j < cnt; j += 256) {
    uint2 p = lbuf[j];
    uint32_t v = ((p.x & 0xFFFu) << 5) | (p.y >> 27);
    donors[gbase + j] = (float)v;
  }
}

// ---------------------------------------------------------------------------
// K4: out[i] = repl ? donors[rank] : x[i], barrier-free main loop.
// Block spans 16384 elems = 256 mask words; wave w owns words [w*64,(w+1)*64).
// One-shot wave prefix, then autonomous per-wave walk (no barriers).
// ---------------------------------------------------------------------------
__global__ __launch_bounds__(256) void k_final(const float* __restrict__ x,
                                               const uint64_t* __restrict__ mask,
                                               const uint32_t* __restrict__ rsums,
                                               const float* __restrict__ donors,
                                               float* __restrict__ out, int n) {
  __shared__ uint64_t lwords[ELEMS_G / 64];   // 2 KB
  __shared__ uint32_t wtotS[4];
  int tid = threadIdx.x, lane = tid & 63, wid = tid >> 6;
  int base = blockIdx.x * ELEMS_G;
  int wordBase = base >> 6;                   // 256 words per block
  // phase 1: load all words, per-wave popcount totals
  int wIdx = wordBase + tid;
  uint64_t myw = ((size_t)wIdx * 64 < (size_t)n) ? mask[wIdx] : 0ull;
  lwords[tid] = myw;
  uint32_t pc = (uint32_t)__popcll(myw);
  for (int d = 32; d >= 1; d >>= 1) pc += __shfl_down(pc, d, 64);
  if (lane == 0) wtotS[wid] = pc;
  __syncthreads();
  uint32_t running = rsums[blockIdx.x];
  for (int w = 0; w < 4; w++) { if (w < wid) running += wtotS[w]; }
  // phase 2: wave-autonomous walk, no barriers
  for (int k = 0; k < 64; k++) {
    int lw = wid * 64 + k;
    uint64_t word = lwords[lw];
    int i = base + lw * 64 + lane;
    bool r = (word >> lane) & 1ull;
    uint32_t inword = (uint32_t)__popcll(word & ((1ull << lane) - 1ull));
    if (i < n) {
      float o = x[i];
      if (r) o = donors[running + inword];
      out[i] = o;
    }
    running += (uint32_t)__popcll(word);
  }
}

// ---------------------------------------------------------------------------
extern "C" void kernel_launch(void* const* d_in, const int* in_sizes, int n_in,
                              void* d_out, int out_size, void* d_ws, size_t ws_size,
                              hipStream_t stream) {
  const float* x = (const float*)d_in[0];
  float* out = (float*)d_out;
  int n = in_sizes[0];
  (void)n_in; (void)out_size;

  uint32_t bk0, bk1, sk0, sk1;
  tf2x32(0u, 42u, 0u, 0u, bk0, bk1);
  tf2x32(0u, 42u, 0u, 1u, sk0, sk1);

  int nBlkG = (n + ELEMS_G - 1) / ELEMS_G;     // 2048

  size_t off = 0;
  auto alloc = [&](size_t bytes) -> void* {
    void* p = (uint8_t*)d_ws + off;
    off += (bytes + 255) & ~(size_t)255;
    return p;
  };
  uint32_t* dumpCursor = (uint32_t*)alloc(4);
  uint32_t* fineCursor = (uint32_t*)alloc((size_t)(NBINS + 1) * 4);
  uint32_t* rsums      = (uint32_t*)alloc((size_t)(nBlkG + 1) * 4);
  uint64_t* mask       = (uint64_t*)alloc((size_t)((n + 63) / 64) * 8);  // 4 MB
  size_t baseOff = off;

  size_t avail = (ws_size > baseOff) ? (ws_size - baseOff) : 0;
  uint32_t capdump, stride;
  if (avail >= ((size_t)4718592 + (size_t)NBINS * 4608) * 8 + 1024) {
    capdump = 4718592u; stride = 4608u;
  } else if (avail >= ((size_t)4390912 + (size_t)NBINS * 4512) * 8 + 1024) {
    capdump = 4390912u; stride = 4512u;
  } else {
    capdump = 4259840u; stride = 4480u;
  }
  uint2* dump = (uint2*)alloc((size_t)capdump * 8);
  uint2* fine = (uint2*)alloc((size_t)NBINS * stride * 8);
  float* donors = (float*)dump;   // alias: dump dead after k_regroup

  hipMemsetAsync(dumpCursor, 0, (size_t)((NBINS + 2) * 4 + 512), stream);

  k_gen<<<nBlkG, 256, 0, stream>>>(x, mask, rsums, dumpCursor, dump, capdump,
                                   bk0, bk1, sk0, sk1, n);
  k_scan_single<<<1, 256, 0, stream>>>(rsums, nBlkG);
  int nWin = (int)((capdump + WIN - 1) / WIN);
  k_regroup<<<nWin, 256, 0, stream>>>(dump, dumpCursor, capdump, fineCursor, fine, stride);
  k_scan_single<<<1, 256, 0, stream>>>(fineCursor, (int)NBINS);
  k_binsort<<<(int)NBINS, 256, 0, stream>>>(fine, fineCursor, donors, stride);
  k_final<<<nBlkG, 256, 0, stream>>>(x, mask, rsums, donors, out, n);
}

// Round 9
// 355.828 us; speedup vs baseline: 13.9702x; 1.1141x over previous
//
#include <hip/hip_runtime.h>
#include <stdint.h>

// ---------------------------------------------------------------------------
// JAX threefry2x32 (20 rounds), bit-exact port of jax/_src/prng.py
// ---------------------------------------------------------------------------
static __host__ __device__ inline uint32_t rotl32(uint32_t x, int r) {
  return (x << r) | (x >> (32 - r));
}

static __host__ __device__ inline void tf2x32(uint32_t k0, uint32_t k1,
                                              uint32_t x0, uint32_t x1,
                                              uint32_t& o0, uint32_t& o1) {
  uint32_t k2 = k0 ^ k1 ^ 0x1BD11BDAu;
#define TFR(a) { x0 += x1; x1 = rotl32(x1, a); x1 ^= x0; }
  x0 += k0; x1 += k1;
  TFR(13) TFR(15) TFR(26) TFR(6)
  x0 += k1; x1 += k2 + 1u;
  TFR(17) TFR(29) TFR(16) TFR(24)
  x0 += k2; x1 += k0 + 2u;
  TFR(13) TFR(15) TFR(26) TFR(6)
  x0 += k0; x1 += k1 + 3u;
  TFR(17) TFR(29) TFR(16) TFR(24)
  x0 += k1; x1 += k2 + 4u;
  TFR(13) TFR(15) TFR(26) TFR(6)
  x0 += k2; x1 += k0 + 5u;
#undef TFR
  o0 = x0; o1 = x1;
}

static __device__ inline uint32_t fold_bits(uint32_t k0, uint32_t k1, uint32_t ctr) {
  uint32_t a, b;
  tf2x32(k0, k1, 0u, ctr, a, b);
  return a ^ b;
}

// Candidates: m = bits>>9 < CUT2 (=7*2^17, 10.94%). E[C]=3.670M >= R~3.355M
// (+125 sigma). Fine bin = m>>10 in [0,896); within-bin bucket = m & 1023.
#define CUT2      917504u        // 7 << 17
#define NBINS2    896u           // used bins
#define NH        1024           // histogram array size (pow2 for scans)
#define ELEMS_G   8192           // k_gen / k_final block span
#define GPOOL     1216u          // k_gen LDS pool (mean 896, +11 sigma)
#define BSCAP     4608u          // binsort LDS buf (bin mean 4096, +8 sigma)
#define WIN       8192           // regroup window (entries)
#define CAPDUMP   3932160u       // dump capacity (mean 3.670M, +145 sigma)
#define STRIDE    4608u          // fine region stride
#define MASKI     0x07FFFFFFu
// bernoulli: u < 0.1f  <=>  mant < 838861  (exact; 0.1f = 0x3DCCCCCD)
#define BERN_THR  838861u

// pair packing: .x = (m<<12) | (value>>5)    [m:20 | v_hi:12]  (bin = .x>>22)
//               .y = ((value&31)<<27) | idx  [v_lo:5 | 00 | idx:25]

// ---------------------------------------------------------------------------
// K1: threefry + mask/rsums + per-candidate LDS append + coalesced dump.
// Lean LDS (~9.8KB) -> 8 blocks/CU (100% occ). One global atomic per block.
// No ballot aggregation: direct LDS atomic per candidate (~11% of lanes).
// ---------------------------------------------------------------------------
template<bool BOUNDS>
__global__ __launch_bounds__(256) void k_gen(const float* __restrict__ x,
                                             uint64_t* __restrict__ mask,
                                             uint32_t* __restrict__ rsums,
                                             uint32_t* __restrict__ dumpCursor,
                                             uint2* __restrict__ dump,
                                             uint32_t bk0, uint32_t bk1,
                                             uint32_t sk0, uint32_t sk1, int n) {
  __shared__ uint2 pool[GPOOL];          // 9.7 KB
  __shared__ uint32_t wcnt[4];
  __shared__ uint32_t lpoolCnt, lgbase;
  int tid = threadIdx.x, lane = tid & 63, wid = tid >> 6;
  int base = blockIdx.x * ELEMS_G;
  if (tid == 0) lpoolCnt = 0;
  __syncthreads();

  uint32_t cnt = 0;
  for (int k = 0; k < ELEMS_G / 256; k++) {
    int i = base + k * 256 + tid;
    bool inb = !BOUNDS || (i < n);
    float xv = inb ? x[i] : 0.0f;
    bool nonpad = (xv != 0.0f) && inb;
    // bernoulli stream (integer compare, bit-exact)
    uint32_t bb = fold_bits(bk0, bk1, (uint32_t)i);
    bool r = nonpad && ((bb >> 9) < BERN_THR);
    unsigned long long ball = __ballot(r);
    int wword = (base + k * 256 + wid * 64) >> 6;
    if (lane == 0 && (!BOUNDS || wword * 64 < n)) mask[wword] = (uint64_t)ball;
    cnt += r ? 1u : 0u;
    // shuffle-key stream: direct per-candidate append
    uint32_t mm = fold_bits(sk0, sk1, (uint32_t)i) >> 9;
    if (nonpad && mm < CUT2) {
      uint32_t slot = atomicAdd(&lpoolCnt, 1u);
      uint32_t v = (uint32_t)xv;
      if (slot < GPOOL)
        pool[slot] = make_uint2((mm << 12) | (v >> 5), ((v & 31u) << 27) | (uint32_t)i);
    }
  }
  // rsums
  for (int d = 32; d >= 1; d >>= 1) cnt += __shfl_down(cnt, d, 64);
  if (lane == 0) wcnt[wid] = cnt;
  __syncthreads();
  if (tid == 0) {
    rsums[blockIdx.x] = wcnt[0] + wcnt[1] + wcnt[2] + wcnt[3];
    uint32_t pc = lpoolCnt; if (pc > GPOOL) pc = GPOOL;
    lgbase = atomicAdd((unsigned int*)dumpCursor, pc);   // ONE atomic per block
  }
  __syncthreads();
  uint32_t pc = lpoolCnt; if (pc > GPOOL) pc = GPOOL;
  uint32_t gb = lgbase;
  for (uint32_t j = tid; j < pc; j += 256) {
    uint32_t d = gb + j;
    if (d < CAPDUMP) dump[d] = pool[j];                  // coalesced stream
  }
}

// ---------------------------------------------------------------------------
// exclusive scan in place; also writes data[n] = total (alloc n+1!)
// ---------------------------------------------------------------------------
__global__ void k_scan_single(uint32_t* __restrict__ data, int n) {
  __shared__ uint32_t wsum[4];
  int tid = threadIdx.x, lane = tid & 63, wid = tid >> 6;
  uint32_t running = 0;
  for (int base = 0; base < n; base += 256) {
    int i = base + tid;
    uint32_t v = (i < n) ? data[i] : 0u;
    uint32_t incl = v;
    for (int d = 1; d < 64; d <<= 1) {
      uint32_t t = __shfl_up(incl, (unsigned)d, 64);
      if (lane >= d) incl += t;
    }
    if (lane == 63) wsum[wid] = incl;
    __syncthreads();
    uint32_t woff = 0, tot = 0;
    for (int w = 0; w < 4; w++) { uint32_t s = wsum[w]; if (w < wid) woff += s; tot += s; }
    if (i < n) data[i] = running + woff + (incl - v);
    running += tot;
    __syncthreads();
  }
  if (tid == 0) data[n] = running;
}

// ---------------------------------------------------------------------------
// K2: regroup dense dump -> fixed-stride fine-bin regions (proven R7/R8).
// ---------------------------------------------------------------------------
__global__ __launch_bounds__(256) void k_regroup(const uint2* __restrict__ dump,
                                                 const uint32_t* __restrict__ dumpCursor,
                                                 uint32_t* __restrict__ fineCursor,
                                                 uint2* __restrict__ fine) {
  __shared__ uint2    pool2[WIN];        // 65.5 KB
  __shared__ uint32_t lhist[NH];         // 4 KB
  __shared__ uint32_t lgbase[NH];        // 4 KB
  __shared__ uint32_t wsums[4];
  int tid = threadIdx.x, lane = tid & 63, wid = tid >> 6;
  uint32_t total = dumpCursor[0];
  if (total > CAPDUMP) total = CAPDUMP;
  uint32_t wbase = blockIdx.x * (uint32_t)WIN;
  if (wbase >= total) return;
  uint32_t valid = total - wbase;
  if (valid > WIN) valid = WIN;

  for (int b = tid; b < NH; b += 256) lhist[b] = 0;
  __syncthreads();
  uint2 e[WIN / 256];
#pragma unroll
  for (int q = 0; q < WIN / 256; q++) {
    uint32_t j = (uint32_t)q * 256u + (uint32_t)tid;
    e[q] = (j < valid) ? dump[wbase + j] : make_uint2(0u, 0u);
    if (j < valid) atomicAdd(&lhist[e[q].x >> 22], 1u);
  }
  __syncthreads();
  for (int b = tid; b < NH; b += 256) {
    uint32_t h = lhist[b];
    lgbase[b] = h ? atomicAdd((unsigned int*)&fineCursor[b], h) : 0u;
  }
  __syncthreads();
  uint32_t h0 = lhist[4 * tid], h1 = lhist[4 * tid + 1],
           h2 = lhist[4 * tid + 2], h3 = lhist[4 * tid + 3];
  uint32_t tsum = h0 + h1 + h2 + h3;
  uint32_t incl = tsum;
  for (int d = 1; d < 64; d <<= 1) {
    uint32_t t = __shfl_up(incl, (unsigned)d, 64);
    if (lane >= d) incl += t;
  }
  if (lane == 63) wsums[wid] = incl;
  __syncthreads();
  if (wid == 0) {
    uint32_t v = (lane < 4) ? wsums[lane] : 0u;
    uint32_t in2 = v;
    for (int d = 1; d < 4; d <<= 1) {
      uint32_t t = __shfl_up(in2, (unsigned)d, 64);
      if (lane >= d) in2 += t;
    }
    if (lane < 4) wsums[lane] = in2 - v;
  }
  __syncthreads();
  uint32_t texcl = wsums[wid] + (incl - tsum);
  uint32_t e0 = texcl, e1 = e0 + h0, e2 = e1 + h1, e3 = e2 + h2;
  __syncthreads();
  lhist[4 * tid] = e0; lhist[4 * tid + 1] = e1;
  lhist[4 * tid + 2] = e2; lhist[4 * tid + 3] = e3;
  __syncthreads();
#pragma unroll
  for (int q = 0; q < WIN / 256; q++) {
    uint32_t j = (uint32_t)q * 256u + (uint32_t)tid;
    if (j < valid) {
      uint32_t b = e[q].x >> 22;
      uint32_t lpos = atomicAdd(&lhist[b], 1u);
      pool2[lpos] = e[q];
    }
  }
  __syncthreads();
  for (uint32_t j = tid; j < valid; j += 256) {
    uint2 p = pool2[j];
    uint32_t b = p.x >> 22;
    uint32_t st = (b == 0) ? 0u : lhist[b - 1];
    uint32_t dst = lgbase[b] + (j - st);
    if (dst < STRIDE) fine[(size_t)b * STRIDE + dst] = p;
  }
}

// ---------------------------------------------------------------------------
// K3: one 256-thread block per bin, fully LDS-resident sort (proven R6-R8).
// ---------------------------------------------------------------------------
__global__ __launch_bounds__(256) void k_binsort(const uint2* __restrict__ pairs,
                                                 const uint32_t* __restrict__ binPrefix,
                                                 float* __restrict__ donors) {
  __shared__ uint2    lbuf[BSCAP];      // 36.9 KB
  __shared__ uint32_t hist[NH];         // 4 KB
  __shared__ uint32_t wsums[4];
  int tid = threadIdx.x, lane = tid & 63, wid = tid >> 6;
  uint32_t bin = blockIdx.x;
  uint32_t gbase = binPrefix[bin];
  uint32_t cnt = binPrefix[bin + 1] - gbase;
  if (cnt > STRIDE) cnt = STRIDE;
  if (cnt > BSCAP) cnt = BSCAP;
  const uint2* src = pairs + (size_t)bin * STRIDE;

  for (int c = tid; c < 1024; c += 256) hist[c] = 0;
  __syncthreads();
  for (uint32_t j = tid; j < cnt; j += 256)
    atomicAdd(&hist[(src[j].x >> 12) & 1023u], 1u);
  __syncthreads();
  uint32_t h0 = hist[4 * tid], h1 = hist[4 * tid + 1],
           h2 = hist[4 * tid + 2], h3 = hist[4 * tid + 3];
  uint32_t tsum = h0 + h1 + h2 + h3;
  uint32_t incl = tsum;
  for (int d = 1; d < 64; d <<= 1) {
    uint32_t t = __shfl_up(incl, (unsigned)d, 64);
    if (lane >= d) incl += t;
  }
  if (lane == 63) wsums[wid] = incl;
  __syncthreads();
  if (wid == 0) {
    uint32_t v = (lane < 4) ? wsums[lane] : 0u;
    uint32_t in2 = v;
    for (int d = 1; d < 4; d <<= 1) {
      uint32_t t = __shfl_up(in2, (unsigned)d, 64);
      if (lane >= d) in2 += t;
    }
    if (lane < 4) wsums[lane] = in2 - v;
  }
  __syncthreads();
  uint32_t texcl = wsums[wid] + (incl - tsum);
  uint32_t e0 = texcl, e1 = e0 + h0, e2 = e1 + h1, e3 = e2 + h2;
  __syncthreads();
  hist[4 * tid] = e0; hist[4 * tid + 1] = e1;
  hist[4 * tid + 2] = e2; hist[4 * tid + 3] = e3;
  __syncthreads();
  for (uint32_t j = tid; j < cnt; j += 256) {
    uint2 p = src[j];
    uint32_t c = (p.x >> 12) & 1023u;
    uint32_t lpos = atomicAdd(&hist[c], 1u);
    lbuf[lpos] = p;
  }
  __syncthreads();
  for (int c = tid; c < 1024; c += 256) {
    uint32_t lo = (c == 0) ? 0u : hist[c - 1];
    uint32_t hi = hist[c];
    for (uint32_t u = lo + 1; u < hi; u++) {
      uint2 v = lbuf[u];
      uint32_t w = u;
      while (w > lo && (lbuf[w - 1].y & MASKI) > (v.y & MASKI)) {
        lbuf[w] = lbuf[w - 1];
        w--;
      }
      lbuf[w] = v;
    }
  }
  __syncthreads();
  for (uint32_t j = tid; j < cnt; j += 256) {
    uint2 p = lbuf[j];
    uint32_t v = ((p.x & 0xFFFu) << 5) | (p.y >> 27);
    donors[gbase + j] = (float)v;
  }
}

// ---------------------------------------------------------------------------
// K4: out[i] = repl ? donors[rank] : x[i], barrier-free main walk.
// Block spans 8192 elems = 128 mask words; wave w owns words [32w, 32w+32).
// ---------------------------------------------------------------------------
template<bool BOUNDS>
__global__ __launch_bounds__(256) void k_final(const float* __restrict__ x,
                                               const uint64_t* __restrict__ mask,
                                               const uint32_t* __restrict__ rsums,
                                               const float* __restrict__ donors,
                                               float* __restrict__ out, int n) {
  __shared__ uint64_t lwords[ELEMS_G / 64];   // 128 words, 1 KB
  __shared__ uint32_t pcS[ELEMS_G / 64];      // 512 B
  __shared__ uint32_t spanS[4];
  int tid = threadIdx.x, lane = tid & 63, wid = tid >> 6;
  int base = blockIdx.x * ELEMS_G;
  int wordBase = base >> 6;
  if (tid < ELEMS_G / 64) {
    uint64_t w = (!BOUNDS || (size_t)(wordBase + tid) * 64 < (size_t)n)
                     ? mask[wordBase + tid] : 0ull;
    lwords[tid] = w;
    pcS[tid] = (uint32_t)__popcll(w);
  }
  __syncthreads();
  if (tid < 4) {
    uint32_t s = 0;
    for (int q = 0; q < 32; q++) s += pcS[tid * 32 + q];
    spanS[tid] = s;
  }
  __syncthreads();
  uint32_t running = rsums[blockIdx.x];
  for (int w = 0; w < 4; w++) { if (w < wid) running += spanS[w]; }
  // barrier-free wave-autonomous walk over 32 words
  for (int k = 0; k < 32; k++) {
    int lw = wid * 32 + k;
    uint64_t word = lwords[lw];
    int i = base + lw * 64 + lane;
    bool r = (word >> lane) & 1ull;
    uint32_t inword = (uint32_t)__popcll(word & ((1ull << lane) - 1ull));
    if (!BOUNDS || i < n) {
      float o = x[i];
      if (r) o = donors[running + inword];
      out[i] = o;
    }
    running += (uint32_t)__popcll(word);
  }
}

// ---------------------------------------------------------------------------
extern "C" void kernel_launch(void* const* d_in, const int* in_sizes, int n_in,
                              void* d_out, int out_size, void* d_ws, size_t ws_size,
                              hipStream_t stream) {
  const float* x = (const float*)d_in[0];
  float* out = (float*)d_out;
  int n = in_sizes[0];
  (void)n_in; (void)out_size; (void)ws_size;

  uint32_t bk0, bk1, sk0, sk1;
  tf2x32(0u, 42u, 0u, 0u, bk0, bk1);
  tf2x32(0u, 42u, 0u, 1u, sk0, sk1);

  int nBlkG = (n + ELEMS_G - 1) / ELEMS_G;     // 4096
  bool exact = ((n % ELEMS_G) == 0);

  size_t off = 0;
  auto alloc = [&](size_t bytes) -> void* {
    void* p = (uint8_t*)d_ws + off;
    off += (bytes + 255) & ~(size_t)255;
    return p;
  };
  uint32_t* dumpCursor = (uint32_t*)alloc(4);
  uint32_t* fineCursor = (uint32_t*)alloc((size_t)(NH + 1) * 4);
  uint32_t* rsums      = (uint32_t*)alloc((size_t)(nBlkG + 1) * 4);
  uint64_t* mask       = (uint64_t*)alloc((size_t)((n + 63) / 64) * 8);    // 4 MB
  uint2*    dump       = (uint2*)alloc((size_t)CAPDUMP * 8);               // 31.5 MB
  uint2*    fine       = (uint2*)alloc((size_t)NBINS2 * STRIDE * 8);       // 33.0 MB
  float*    donors     = (float*)dump;   // alias: dump dead after k_regroup

  hipMemsetAsync(dumpCursor, 0, (size_t)(NH + 2) * 4 + 512, stream);

  if (exact)
    k_gen<false><<<nBlkG, 256, 0, stream>>>(x, mask, rsums, dumpCursor, dump,
                                            bk0, bk1, sk0, sk1, n);
  else
    k_gen<true><<<nBlkG, 256, 0, stream>>>(x, mask, rsums, dumpCursor, dump,
                                           bk0, bk1, sk0, sk1, n);
  k_scan_single<<<1, 256, 0, stream>>>(rsums, nBlkG);
  int nWin = (int)((CAPDUMP + WIN - 1) / WIN);    // 480
  k_regroup<<<nWin, 256, 0, stream>>>(dump, dumpCursor, fineCursor, fine);
  k_scan_single<<<1, 256, 0, stream>>>(fineCursor, (int)NBINS2);
  k_binsort<<<(int)NBINS2, 256, 0, stream>>>(fine, fineCursor, donors);
  if (exact)
    k_final<false><<<nBlkG, 256, 0, stream>>>(x, mask, rsums, donors, out, n);
  else
    k_final<true><<<nBlkG, 256, 0, stream>>>(x, mask, rsums, donors, out, n);
}

// Round 10
// 339.001 us; speedup vs baseline: 14.6636x; 1.0496x over previous
//
#include <hip/hip_runtime.h>
#include <stdint.h>

// ---------------------------------------------------------------------------
// JAX threefry2x32 (20 rounds), bit-exact port of jax/_src/prng.py
// ---------------------------------------------------------------------------
static __host__ __device__ inline uint32_t rotl32(uint32_t x, int r) {
  return (x << r) | (x >> (32 - r));
}

static __host__ __device__ inline void tf2x32(uint32_t k0, uint32_t k1,
                                              uint32_t x0, uint32_t x1,
                                              uint32_t& o0, uint32_t& o1) {
  uint32_t k2 = k0 ^ k1 ^ 0x1BD11BDAu;
#define TFR(a) { x0 += x1; x1 = rotl32(x1, a); x1 ^= x0; }
  x0 += k0; x1 += k1;
  TFR(13) TFR(15) TFR(26) TFR(6)
  x0 += k1; x1 += k2 + 1u;
  TFR(17) TFR(29) TFR(16) TFR(24)
  x0 += k2; x1 += k0 + 2u;
  TFR(13) TFR(15) TFR(26) TFR(6)
  x0 += k0; x1 += k1 + 3u;
  TFR(17) TFR(29) TFR(16) TFR(24)
  x0 += k1; x1 += k2 + 4u;
  TFR(13) TFR(15) TFR(26) TFR(6)
  x0 += k2; x1 += k0 + 5u;
#undef TFR
  o0 = x0; o1 = x1;
}

static __device__ inline uint32_t fold_bits(uint32_t k0, uint32_t k1, uint32_t ctr) {
  uint32_t a, b;
  tf2x32(k0, k1, 0u, ctr, a, b);
  return a ^ b;
}

// Candidates: m = bits>>9 < CUT2 (=7*2^17, 10.94%). E[C]=3.670M >= R~3.355M
// (+125 sigma). Fine bin = m>>10 in [0,896); within-bin bucket = m & 1023.
#define CUT2      917504u        // 7 << 17
#define NBINS2    896u           // used bins
#define NH        1024           // histogram array size (pow2 for scans)
#define ELEMS_G   8192           // k_gen / k_final block span
#define GPOOL     1216u          // k_gen LDS pool (mean 896, +11 sigma)
#define BSCAP     4608u          // binsort LDS buf (bin mean 4096, +8 sigma)
#define WIN       8192           // regroup window (entries)
#define CAPDUMP   3932160u       // dump capacity (mean 3.670M, +145 sigma)
#define STRIDE    4608u          // fine region stride
#define MASKI     0x07FFFFFFu
// bernoulli: u < 0.1f  <=>  mant < 838861  (exact; 0.1f = 0x3DCCCCCD)
#define BERN_THR  838861u

// pair packing: .x = (m<<12) | (value>>5)    [m:20 | v_hi:12]  (bin = .x>>22)
//               .y = ((value&31)<<27) | idx  [v_lo:5 | 00 | idx:25]

// MASK FORMAT (internal contract between k_gen and k_final):
// chunk = 256 consecutive elements handled by one wave-iteration; lane L holds
// elements chunkBase + 4L + e (e=0..3). mask[chunk*4 + e] = __ballot(repl_e)
// (bit L = element chunkBase+4L+e). Chunk index = blockIdx*32 + it*4 + wid.

// ---------------------------------------------------------------------------
// K1: threefry + ballot-mask/rsums + per-candidate LDS append + coalesced
// dump. float4 loads, 4 elems/lane: 8 independent threefry chains per lane.
// ---------------------------------------------------------------------------
template<bool BOUNDS>
__global__ __launch_bounds__(256) void k_gen(const float* __restrict__ x,
                                             uint64_t* __restrict__ mask,
                                             uint32_t* __restrict__ rsums,
                                             uint32_t* __restrict__ dumpCursor,
                                             uint2* __restrict__ dump,
                                             uint32_t bk0, uint32_t bk1,
                                             uint32_t sk0, uint32_t sk1, int n) {
  __shared__ uint2 pool[GPOOL];          // 9.7 KB
  __shared__ uint32_t wcnt[4];
  __shared__ uint32_t lpoolCnt, lgbase;
  int tid = threadIdx.x, lane = tid & 63, wid = tid >> 6;
  int base = blockIdx.x * ELEMS_G;
  if (tid == 0) lpoolCnt = 0;
  __syncthreads();

  uint32_t cnt = 0;
  unsigned long long bball[4];
  for (int it = 0; it < ELEMS_G / 1024; it++) {        // 8 iterations x 1024 elems
    int e0 = base + it * 1024 + wid * 256 + lane * 4;  // 16B-aligned
    float4 xv;
    if (!BOUNDS || e0 + 3 < n) {
      xv = *reinterpret_cast<const float4*>(x + e0);
    } else {
      xv.x = (e0 + 0 < n) ? x[e0 + 0] : 0.0f;
      xv.y = (e0 + 1 < n) ? x[e0 + 1] : 0.0f;
      xv.z = (e0 + 2 < n) ? x[e0 + 2] : 0.0f;
      xv.w = (e0 + 3 < n) ? x[e0 + 3] : 0.0f;
    }
#define GENE(e, comp)                                                     \
    {                                                                     \
      uint32_t ii = (uint32_t)(e0 + e);                                   \
      bool np = (comp != 0.0f);                                           \
      uint32_t bb = fold_bits(bk0, bk1, ii);                              \
      bool rr = np && ((bb >> 9) < BERN_THR);                             \
      bball[e] = __ballot(rr);                                            \
      cnt += rr ? 1u : 0u;                                                \
      uint32_t mm = fold_bits(sk0, sk1, ii) >> 9;                         \
      if (np && mm < CUT2) {                                              \
        uint32_t slot = atomicAdd(&lpoolCnt, 1u);                         \
        uint32_t v = (uint32_t)comp;                                      \
        if (slot < GPOOL)                                                 \
          pool[slot] = make_uint2((mm << 12) | (v >> 5),                  \
                                  ((v & 31u) << 27) | ii);                \
      }                                                                   \
    }
    GENE(0, xv.x) GENE(1, xv.y) GENE(2, xv.z) GENE(3, xv.w)
#undef GENE
    if (lane == 0) {
      uint32_t ci = (uint32_t)blockIdx.x * 32u + (uint32_t)it * 4u + (uint32_t)wid;
      if (!BOUNDS) {
        mask[ci * 4 + 0] = bball[0]; mask[ci * 4 + 1] = bball[1];
        mask[ci * 4 + 2] = bball[2]; mask[ci * 4 + 3] = bball[3];
      } else {
        for (int e = 0; e < 4; e++)
          if ((int)(ci * 256u + (uint32_t)e * 64u) < n) mask[ci * 4 + e] = bball[e];
      }
    }
  }
  // rsums
  for (int d = 32; d >= 1; d >>= 1) cnt += __shfl_down(cnt, d, 64);
  if (lane == 0) wcnt[wid] = cnt;
  __syncthreads();
  if (tid == 0) {
    rsums[blockIdx.x] = wcnt[0] + wcnt[1] + wcnt[2] + wcnt[3];
    uint32_t pc = lpoolCnt; if (pc > GPOOL) pc = GPOOL;
    lgbase = atomicAdd((unsigned int*)dumpCursor, pc);   // ONE atomic per block
  }
  __syncthreads();
  uint32_t pc = lpoolCnt; if (pc > GPOOL) pc = GPOOL;
  uint32_t gb = lgbase;
  for (uint32_t j = tid; j < pc; j += 256) {
    uint32_t d = gb + j;
    if (d < CAPDUMP) dump[d] = pool[j];                  // coalesced stream
  }
}

// ---------------------------------------------------------------------------
// exclusive scan in place; also writes data[n] = total (alloc n+1!)
// ---------------------------------------------------------------------------
__global__ void k_scan_single(uint32_t* __restrict__ data, int n) {
  __shared__ uint32_t wsum[4];
  int tid = threadIdx.x, lane = tid & 63, wid = tid >> 6;
  uint32_t running = 0;
  for (int base = 0; base < n; base += 256) {
    int i = base + tid;
    uint32_t v = (i < n) ? data[i] : 0u;
    uint32_t incl = v;
    for (int d = 1; d < 64; d <<= 1) {
      uint32_t t = __shfl_up(incl, (unsigned)d, 64);
      if (lane >= d) incl += t;
    }
    if (lane == 63) wsum[wid] = incl;
    __syncthreads();
    uint32_t woff = 0, tot = 0;
    for (int w = 0; w < 4; w++) { uint32_t s = wsum[w]; if (w < wid) woff += s; tot += s; }
    if (i < n) data[i] = running + woff + (incl - v);
    running += tot;
    __syncthreads();
  }
  if (tid == 0) data[n] = running;
}

// ---------------------------------------------------------------------------
// K2: regroup dense dump -> fixed-stride fine-bin regions (proven R7-R9).
// ---------------------------------------------------------------------------
__global__ __launch_bounds__(256) void k_regroup(const uint2* __restrict__ dump,
                                                 const uint32_t* __restrict__ dumpCursor,
                                                 uint32_t* __restrict__ fineCursor,
                                                 uint2* __restrict__ fine) {
  __shared__ uint2    pool2[WIN];        // 65.5 KB
  __shared__ uint32_t lhist[NH];         // 4 KB
  __shared__ uint32_t lgbase[NH];        // 4 KB
  __shared__ uint32_t wsums[4];
  int tid = threadIdx.x, lane = tid & 63, wid = tid >> 6;
  uint32_t total = dumpCursor[0];
  if (total > CAPDUMP) total = CAPDUMP;
  uint32_t wbase = blockIdx.x * (uint32_t)WIN;
  if (wbase >= total) return;
  uint32_t valid = total - wbase;
  if (valid > WIN) valid = WIN;

  for (int b = tid; b < NH; b += 256) lhist[b] = 0;
  __syncthreads();
  uint2 e[WIN / 256];
#pragma unroll
  for (int q = 0; q < WIN / 256; q++) {
    uint32_t j = (uint32_t)q * 256u + (uint32_t)tid;
    e[q] = (j < valid) ? dump[wbase + j] : make_uint2(0u, 0u);
    if (j < valid) atomicAdd(&lhist[e[q].x >> 22], 1u);
  }
  __syncthreads();
  for (int b = tid; b < NH; b += 256) {
    uint32_t h = lhist[b];
    lgbase[b] = h ? atomicAdd((unsigned int*)&fineCursor[b], h) : 0u;
  }
  __syncthreads();
  uint32_t h0 = lhist[4 * tid], h1 = lhist[4 * tid + 1],
           h2 = lhist[4 * tid + 2], h3 = lhist[4 * tid + 3];
  uint32_t tsum = h0 + h1 + h2 + h3;
  uint32_t incl = tsum;
  for (int d = 1; d < 64; d <<= 1) {
    uint32_t t = __shfl_up(incl, (unsigned)d, 64);
    if (lane >= d) incl += t;
  }
  if (lane == 63) wsums[wid] = incl;
  __syncthreads();
  if (wid == 0) {
    uint32_t v = (lane < 4) ? wsums[lane] : 0u;
    uint32_t in2 = v;
    for (int d = 1; d < 4; d <<= 1) {
      uint32_t t = __shfl_up(in2, (unsigned)d, 64);
      if (lane >= d) in2 += t;
    }
    if (lane < 4) wsums[lane] = in2 - v;
  }
  __syncthreads();
  uint32_t texcl = wsums[wid] + (incl - tsum);
  uint32_t e0 = texcl, e1 = e0 + h0, e2 = e1 + h1, e3 = e2 + h2;
  __syncthreads();
  lhist[4 * tid] = e0; lhist[4 * tid + 1] = e1;
  lhist[4 * tid + 2] = e2; lhist[4 * tid + 3] = e3;
  __syncthreads();
#pragma unroll
  for (int q = 0; q < WIN / 256; q++) {
    uint32_t j = (uint32_t)q * 256u + (uint32_t)tid;
    if (j < valid) {
      uint32_t b = e[q].x >> 22;
      uint32_t lpos = atomicAdd(&lhist[b], 1u);
      pool2[lpos] = e[q];
    }
  }
  __syncthreads();
  for (uint32_t j = tid; j < valid; j += 256) {
    uint2 p = pool2[j];
    uint32_t b = p.x >> 22;
    uint32_t st = (b == 0) ? 0u : lhist[b - 1];
    uint32_t dst = lgbase[b] + (j - st);
    if (dst < STRIDE) fine[(size_t)b * STRIDE + dst] = p;
  }
}

// ---------------------------------------------------------------------------
// K3: one 256-thread block per bin, fully LDS-resident sort (proven R6-R9).
// ---------------------------------------------------------------------------
__global__ __launch_bounds__(256) void k_binsort(const uint2* __restrict__ pairs,
                                                 const uint32_t* __restrict__ binPrefix,
                                                 float* __restrict__ donors) {
  __shared__ uint2    lbuf[BSCAP];      // 36.9 KB
  __shared__ uint32_t hist[NH];         // 4 KB
  __shared__ uint32_t wsums[4];
  int tid = threadIdx.x, lane = tid & 63, wid = tid >> 6;
  uint32_t bin = blockIdx.x;
  uint32_t gbase = binPrefix[bin];
  uint32_t cnt = binPrefix[bin + 1] - gbase;
  if (cnt > STRIDE) cnt = STRIDE;
  if (cnt > BSCAP) cnt = BSCAP;
  const uint2* src = pairs + (size_t)bin * STRIDE;

  for (int c = tid; c < 1024; c += 256) hist[c] = 0;
  __syncthreads();
  for (uint32_t j = tid; j < cnt; j += 256)
    atomicAdd(&hist[(src[j].x >> 12) & 1023u], 1u);
  __syncthreads();
  uint32_t h0 = hist[4 * tid], h1 = hist[4 * tid + 1],
           h2 = hist[4 * tid + 2], h3 = hist[4 * tid + 3];
  uint32_t tsum = h0 + h1 + h2 + h3;
  uint32_t incl = tsum;
  for (int d = 1; d < 64; d <<= 1) {
    uint32_t t = __shfl_up(incl, (unsigned)d, 64);
    if (lane >= d) incl += t;
  }
  if (lane == 63) wsums[wid] = incl;
  __syncthreads();
  if (wid == 0) {
    uint32_t v = (lane < 4) ? wsums[lane] : 0u;
    uint32_t in2 = v;
    for (int d = 1; d < 4; d <<= 1) {
      uint32_t t = __shfl_up(in2, (unsigned)d, 64);
      if (lane >= d) in2 += t;
    }
    if (lane < 4) wsums[lane] = in2 - v;
  }
  __syncthreads();
  uint32_t texcl = wsums[wid] + (incl - tsum);
  uint32_t e0 = texcl, e1 = e0 + h0, e2 = e1 + h1, e3 = e2 + h2;
  __syncthreads();
  hist[4 * tid] = e0; hist[4 * tid + 1] = e1;
  hist[4 * tid + 2] = e2; hist[4 * tid + 3] = e3;
  __syncthreads();
  for (uint32_t j = tid; j < cnt; j += 256) {
    uint2 p = src[j];
    uint32_t c = (p.x >> 12) & 1023u;
    uint32_t lpos = atomicAdd(&hist[c], 1u);
    lbuf[lpos] = p;
  }
  __syncthreads();
  for (int c = tid; c < 1024; c += 256) {
    uint32_t lo = (c == 0) ? 0u : hist[c - 1];
    uint32_t hi = hist[c];
    for (uint32_t u = lo + 1; u < hi; u++) {
      uint2 v = lbuf[u];
      uint32_t w = u;
      while (w > lo && (lbuf[w - 1].y & MASKI) > (v.y & MASKI)) {
        lbuf[w] = lbuf[w - 1];
        w--;
      }
      lbuf[w] = v;
    }
  }
  __syncthreads();
  for (uint32_t j = tid; j < cnt; j += 256) {
    uint2 p = lbuf[j];
    uint32_t v = ((p.x & 0xFFFu) << 5) | (p.y >> 27);
    donors[gbase + j] = (float)v;
  }
}

// ---------------------------------------------------------------------------
// K4: out[i] = repl ? donors[rank] : x[i].  Ballot-layout mask; float4 x-read
// and out-write; barrier-free per-wave walk after a one-shot chunk prefix.
// ---------------------------------------------------------------------------
template<bool BOUNDS>
__global__ __launch_bounds__(256) void k_final(const float* __restrict__ x,
                                               const uint64_t* __restrict__ mask,
                                               const uint32_t* __restrict__ rsums,
                                               const float* __restrict__ donors,
                                               float* __restrict__ out, int n) {
  __shared__ uint64_t lw[ELEMS_G / 64];       // 128 words, 1 KB
  __shared__ uint32_t ctot[32], cpre[32];
  int tid = threadIdx.x, lane = tid & 63, wid = tid >> 6;
  int base = blockIdx.x * ELEMS_G;
  int wordBase = blockIdx.x * (ELEMS_G / 64);
  if (tid < ELEMS_G / 64) {
    uint64_t w = 0ull;
    int wI = wordBase + tid;
    // chunk c word e covers elems c*256+e*64 .. +63 relative to block? No:
    // global word index wI covers ballot e=(wI&3) of chunk (wI>>2).
    if (!BOUNDS || (((wI >> 2) * 256) + ((wI & 3) * 64) < n)) w = mask[wI];
    lw[tid] = w;
  }
  __syncthreads();
  if (tid < 32) {
    ctot[tid] = (uint32_t)(__popcll(lw[4 * tid]) + __popcll(lw[4 * tid + 1]) +
                           __popcll(lw[4 * tid + 2]) + __popcll(lw[4 * tid + 3]));
  }
  __syncthreads();
  if (tid == 0) {
    uint32_t run = 0;
    for (int c = 0; c < 32; c++) { cpre[c] = run; run += ctot[c]; }
  }
  __syncthreads();
  uint32_t rbase = rsums[blockIdx.x];
  uint64_t lt = (1ull << lane) - 1ull;          // lane=0 -> 0 (1<<0=1, -1=0) OK
  for (int it = 0; it < ELEMS_G / 1024; it++) {
    int c = it * 4 + wid;
    uint64_t b0 = lw[c * 4 + 0], b1 = lw[c * 4 + 1],
             b2 = lw[c * 4 + 2], b3 = lw[c * 4 + 3];
    uint32_t running = rbase + cpre[c];
    int e0 = base + it * 1024 + wid * 256 + lane * 4;
    uint32_t below = (uint32_t)(__popcll(b0 & lt) + __popcll(b1 & lt) +
                                __popcll(b2 & lt) + __popcll(b3 & lt));
    uint32_t r0 = (uint32_t)((b0 >> lane) & 1ull), r1 = (uint32_t)((b1 >> lane) & 1ull);
    uint32_t r2 = (uint32_t)((b2 >> lane) & 1ull), r3 = (uint32_t)((b3 >> lane) & 1ull);
    uint32_t rk = running + below;
    float4 xv;
    if (!BOUNDS || e0 + 3 < n) {
      xv = *reinterpret_cast<const float4*>(x + e0);
    } else {
      xv.x = (e0 + 0 < n) ? x[e0 + 0] : 0.0f;
      xv.y = (e0 + 1 < n) ? x[e0 + 1] : 0.0f;
      xv.z = (e0 + 2 < n) ? x[e0 + 2] : 0.0f;
      xv.w = (e0 + 3 < n) ? x[e0 + 3] : 0.0f;
    }
    float4 ov;
    ov.x = r0 ? donors[rk] : xv.x;               rk += r0;
    ov.y = r1 ? donors[rk] : xv.y;               rk += r1;
    ov.z = r2 ? donors[rk] : xv.z;               rk += r2;
    ov.w = r3 ? donors[rk] : xv.w;
    if (!BOUNDS || e0 + 3 < n) {
      *reinterpret_cast<float4*>(out + e0) = ov;
    } else {
      if (e0 + 0 < n) out[e0 + 0] = ov.x;
      if (e0 + 1 < n) out[e0 + 1] = ov.y;
      if (e0 + 2 < n) out[e0 + 2] = ov.z;
      if (e0 + 3 < n) out[e0 + 3] = ov.w;
    }
  }
}

// ---------------------------------------------------------------------------
extern "C" void kernel_launch(void* const* d_in, const int* in_sizes, int n_in,
                              void* d_out, int out_size, void* d_ws, size_t ws_size,
                              hipStream_t stream) {
  const float* x = (const float*)d_in[0];
  float* out = (float*)d_out;
  int n = in_sizes[0];
  (void)n_in; (void)out_size; (void)ws_size;

  uint32_t bk0, bk1, sk0, sk1;
  tf2x32(0u, 42u, 0u, 0u, bk0, bk1);
  tf2x32(0u, 42u, 0u, 1u, sk0, sk1);

  int nBlkG = (n + ELEMS_G - 1) / ELEMS_G;     // 4096
  bool exact = ((n % ELEMS_G) == 0);

  size_t off = 0;
  auto alloc = [&](size_t bytes) -> void* {
    void* p = (uint8_t*)d_ws + off;
    off += (bytes + 255) & ~(size_t)255;
    return p;
  };
  uint32_t* dumpCursor = (uint32_t*)alloc(4);
  uint32_t* fineCursor = (uint32_t*)alloc((size_t)(NH + 1) * 4);
  uint32_t* rsums      = (uint32_t*)alloc((size_t)(nBlkG + 1) * 4);
  uint64_t* mask       = (uint64_t*)alloc((size_t)((n + 63) / 64 + 4) * 8); // 4 MB
  uint2*    dump       = (uint2*)alloc((size_t)CAPDUMP * 8);               // 31.5 MB
  uint2*    fine       = (uint2*)alloc((size_t)NBINS2 * STRIDE * 8);       // 33.0 MB
  float*    donors     = (float*)dump;   // alias: dump dead after k_regroup

  hipMemsetAsync(dumpCursor, 0, (size_t)(NH + 2) * 4 + 512, stream);

  if (exact)
    k_gen<false><<<nBlkG, 256, 0, stream>>>(x, mask, rsums, dumpCursor, dump,
                                            bk0, bk1, sk0, sk1, n);
  else
    k_gen<true><<<nBlkG, 256, 0, stream>>>(x, mask, rsums, dumpCursor, dump,
                                           bk0, bk1, sk0, sk1, n);
  k_scan_single<<<1, 256, 0, stream>>>(rsums, nBlkG);
  int nWin = (int)((CAPDUMP + WIN - 1) / WIN);    // 480
  k_regroup<<<nWin, 256, 0, stream>>>(dump, dumpCursor, fineCursor, fine);
  k_scan_single<<<1, 256, 0, stream>>>(fineCursor, (int)NBINS2);
  k_binsort<<<(int)NBINS2, 256, 0, stream>>>(fine, fineCursor, donors);
  if (exact)
    k_final<false><<<nBlkG, 256, 0, stream>>>(x, mask, rsums, donors, out, n);
  else
    k_final<true><<<nBlkG, 256, 0, stream>>>(x, mask, rsums, donors, out, n);
}

// Round 11
// 338.415 us; speedup vs baseline: 14.6890x; 1.0017x over previous
//
#include <hip/hip_runtime.h>
#include <stdint.h>

// ---------------------------------------------------------------------------
// JAX threefry2x32 (20 rounds), bit-exact port of jax/_src/prng.py
// Device rotates use v_alignbit (1 inst); host uses plain C.
// ---------------------------------------------------------------------------
static __host__ __device__ inline uint32_t rotl32(uint32_t x, int r) {
#if defined(__HIP_DEVICE_COMPILE__)
  return __builtin_amdgcn_alignbit(x, x, (uint32_t)(32 - r));
#else
  return (x << r) | (x >> (32 - r));
#endif
}

static __host__ __device__ inline void tf2x32(uint32_t k0, uint32_t k1,
                                              uint32_t x0, uint32_t x1,
                                              uint32_t& o0, uint32_t& o1) {
  uint32_t k2 = k0 ^ k1 ^ 0x1BD11BDAu;
#define TFR(a) { x0 += x1; x1 = rotl32(x1, a); x1 ^= x0; }
  x0 += k0; x1 += k1;
  TFR(13) TFR(15) TFR(26) TFR(6)
  x0 += k1; x1 += k2 + 1u;
  TFR(17) TFR(29) TFR(16) TFR(24)
  x0 += k2; x1 += k0 + 2u;
  TFR(13) TFR(15) TFR(26) TFR(6)
  x0 += k0; x1 += k1 + 3u;
  TFR(17) TFR(29) TFR(16) TFR(24)
  x0 += k1; x1 += k2 + 4u;
  TFR(13) TFR(15) TFR(26) TFR(6)
  x0 += k2; x1 += k0 + 5u;
#undef TFR
  o0 = x0; o1 = x1;
}

static __device__ inline uint32_t fold_bits(uint32_t k0, uint32_t k1, uint32_t ctr) {
  uint32_t a, b;
  tf2x32(k0, k1, 0u, ctr, a, b);
  return a ^ b;
}

// Candidates: m = bits>>9 < CUT2 (=7*2^17, 10.94%). E[C]=3.670M >= R~3.355M
// (+125 sigma). Fine bin = m>>10 in [0,896); within-bin bucket = m & 1023.
#define CUT2      917504u        // 7 << 17
#define NBINS2    896u           // used bins
#define NH        1024           // histogram array size (pow2 for scans)
#define ELEMS_G   8192           // k_gen / k_final block span
#define GPOOL     1216u          // k_gen LDS pool (mean 896, +11 sigma)
#define BSCAP     4608u          // binsort LDS buf (bin mean 4096, +8 sigma)
#define WIN       8192           // regroup window (entries)
#define CAPDUMP   3932160u       // dump capacity (mean 3.670M, +145 sigma)
#define STRIDE    4608u          // fine region stride
#define MASKI     0x07FFFFFFu
// bernoulli: u < 0.1f  <=>  mant < 838861  (exact; 0.1f = 0x3DCCCCCD)
#define BERN_THR  838861u

// pair packing: .x = (m<<12) | (value>>5)    [m:20 | v_hi:12]  (bin = .x>>22)
//               .y = ((value&31)<<27) | idx  [v_lo:5 | 00 | idx:25]

// MASK FORMAT (internal contract between k_gen and k_final):
// chunk = 256 consecutive elements handled by one wave-iteration; lane L holds
// elements chunkBase + 4L + e (e=0..3). mask[chunk*4 + e] = __ballot(repl_e)
// (bit L = element chunkBase+4L+e). Chunk index = blockIdx*32 + it*4 + wid.

// ---------------------------------------------------------------------------
// K1: threefry + ballot-mask/rsums + per-candidate LDS append + coalesced
// dump. float4 loads, 4 elems/lane. __launch_bounds__(256,6): ~84 VGPRs so
// the 8 threefry chains live in registers (R10 had VGPR=24 -> mov bloat).
// ---------------------------------------------------------------------------
template<bool BOUNDS>
__global__ __launch_bounds__(256, 6) void k_gen(const float* __restrict__ x,
                                                uint64_t* __restrict__ mask,
                                                uint32_t* __restrict__ rsums,
                                                uint32_t* __restrict__ dumpCursor,
                                                uint2* __restrict__ dump,
                                                uint32_t bk0, uint32_t bk1,
                                                uint32_t sk0, uint32_t sk1, int n) {
  __shared__ uint2 pool[GPOOL];          // 9.7 KB
  __shared__ uint32_t wcnt[4];
  __shared__ uint32_t lpoolCnt, lgbase;
  int tid = threadIdx.x, lane = tid & 63, wid = tid >> 6;
  int base = blockIdx.x * ELEMS_G;
  if (tid == 0) lpoolCnt = 0;
  __syncthreads();

  uint32_t cnt = 0;                      // wave-uniform (SALU popcounts)
  unsigned long long bball[4];
  for (int it = 0; it < ELEMS_G / 1024; it++) {        // 8 iterations x 1024 elems
    int e0 = base + it * 1024 + wid * 256 + lane * 4;  // 16B-aligned
    float4 xv;
    if (!BOUNDS || e0 + 3 < n) {
      xv = *reinterpret_cast<const float4*>(x + e0);
    } else {
      xv.x = (e0 + 0 < n) ? x[e0 + 0] : 0.0f;
      xv.y = (e0 + 1 < n) ? x[e0 + 1] : 0.0f;
      xv.z = (e0 + 2 < n) ? x[e0 + 2] : 0.0f;
      xv.w = (e0 + 3 < n) ? x[e0 + 3] : 0.0f;
    }
#define GENE(e, comp)                                                     \
    {                                                                     \
      uint32_t ii = (uint32_t)(e0 + e);                                   \
      bool np = (comp != 0.0f);                                           \
      uint32_t bb = fold_bits(bk0, bk1, ii);                              \
      bool rr = np && ((bb >> 9) < BERN_THR);                             \
      bball[e] = __ballot(rr);                                            \
      uint32_t mm = fold_bits(sk0, sk1, ii) >> 9;                         \
      if (np && mm < CUT2) {                                              \
        uint32_t slot = atomicAdd(&lpoolCnt, 1u);                         \
        uint32_t v = (uint32_t)comp;                                      \
        if (slot < GPOOL)                                                 \
          pool[slot] = make_uint2((mm << 12) | (v >> 5),                  \
                                  ((v & 31u) << 27) | ii);                \
      }                                                                   \
    }
    GENE(0, xv.x) GENE(1, xv.y) GENE(2, xv.z) GENE(3, xv.w)
#undef GENE
    // ballots are wave-uniform SGPRs -> s_bcnt1 on the scalar pipe (free)
    cnt += (uint32_t)(__popcll(bball[0]) + __popcll(bball[1]) +
                      __popcll(bball[2]) + __popcll(bball[3]));
    if (lane == 0) {
      uint32_t ci = (uint32_t)blockIdx.x * 32u + (uint32_t)it * 4u + (uint32_t)wid;
      if (!BOUNDS) {
        mask[ci * 4 + 0] = bball[0]; mask[ci * 4 + 1] = bball[1];
        mask[ci * 4 + 2] = bball[2]; mask[ci * 4 + 3] = bball[3];
      } else {
        for (int e = 0; e < 4; e++)
          if ((int)(ci * 256u + (uint32_t)e * 64u) < n) mask[ci * 4 + e] = bball[e];
      }
    }
  }
  if (lane == 0) wcnt[wid] = cnt;        // cnt already wave-total
  __syncthreads();
  if (tid == 0) {
    rsums[blockIdx.x] = wcnt[0] + wcnt[1] + wcnt[2] + wcnt[3];
    uint32_t pc = lpoolCnt; if (pc > GPOOL) pc = GPOOL;
    lgbase = atomicAdd((unsigned int*)dumpCursor, pc);   // ONE atomic per block
  }
  __syncthreads();
  uint32_t pc = lpoolCnt; if (pc > GPOOL) pc = GPOOL;
  uint32_t gb = lgbase;
  for (uint32_t j = tid; j < pc; j += 256) {
    uint32_t d = gb + j;
    if (d < CAPDUMP) dump[d] = pool[j];                  // coalesced stream
  }
}

// ---------------------------------------------------------------------------
// 2-target exclusive scan: block 0 scans data0[n0], block 1 scans data1[n1].
// In place; also writes data[n] = total (alloc n+1!)
// ---------------------------------------------------------------------------
__global__ void k_scan2(uint32_t* __restrict__ data0, int n0,
                        uint32_t* __restrict__ data1, int n1) {
  __shared__ uint32_t wsum[4];
  uint32_t* data = (blockIdx.x == 0) ? data0 : data1;
  int n = (blockIdx.x == 0) ? n0 : n1;
  int tid = threadIdx.x, lane = tid & 63, wid = tid >> 6;
  uint32_t running = 0;
  for (int base = 0; base < n; base += 256) {
    int i = base + tid;
    uint32_t v = (i < n) ? data[i] : 0u;
    uint32_t incl = v;
    for (int d = 1; d < 64; d <<= 1) {
      uint32_t t = __shfl_up(incl, (unsigned)d, 64);
      if (lane >= d) incl += t;
    }
    if (lane == 63) wsum[wid] = incl;
    __syncthreads();
    uint32_t woff = 0, tot = 0;
    for (int w = 0; w < 4; w++) { uint32_t s = wsum[w]; if (w < wid) woff += s; tot += s; }
    if (i < n) data[i] = running + woff + (incl - v);
    running += tot;
    __syncthreads();
  }
  if (tid == 0) data[n] = running;
}

// ---------------------------------------------------------------------------
// K2: regroup dense dump -> fixed-stride fine-bin regions (proven R7-R10).
// ---------------------------------------------------------------------------
__global__ __launch_bounds__(256) void k_regroup(const uint2* __restrict__ dump,
                                                 const uint32_t* __restrict__ dumpCursor,
                                                 uint32_t* __restrict__ fineCursor,
                                                 uint2* __restrict__ fine) {
  __shared__ uint2    pool2[WIN];        // 65.5 KB
  __shared__ uint32_t lhist[NH];         // 4 KB
  __shared__ uint32_t lgbase[NH];        // 4 KB
  __shared__ uint32_t wsums[4];
  int tid = threadIdx.x, lane = tid & 63, wid = tid >> 6;
  uint32_t total = dumpCursor[0];
  if (total > CAPDUMP) total = CAPDUMP;
  uint32_t wbase = blockIdx.x * (uint32_t)WIN;
  if (wbase >= total) return;
  uint32_t valid = total - wbase;
  if (valid > WIN) valid = WIN;

  for (int b = tid; b < NH; b += 256) lhist[b] = 0;
  __syncthreads();
  uint2 e[WIN / 256];
#pragma unroll
  for (int q = 0; q < WIN / 256; q++) {
    uint32_t j = (uint32_t)q * 256u + (uint32_t)tid;
    e[q] = (j < valid) ? dump[wbase + j] : make_uint2(0u, 0u);
    if (j < valid) atomicAdd(&lhist[e[q].x >> 22], 1u);
  }
  __syncthreads();
  for (int b = tid; b < NH; b += 256) {
    uint32_t h = lhist[b];
    lgbase[b] = h ? atomicAdd((unsigned int*)&fineCursor[b], h) : 0u;
  }
  __syncthreads();
  uint32_t h0 = lhist[4 * tid], h1 = lhist[4 * tid + 1],
           h2 = lhist[4 * tid + 2], h3 = lhist[4 * tid + 3];
  uint32_t tsum = h0 + h1 + h2 + h3;
  uint32_t incl = tsum;
  for (int d = 1; d < 64; d <<= 1) {
    uint32_t t = __shfl_up(incl, (unsigned)d, 64);
    if (lane >= d) incl += t;
  }
  if (lane == 63) wsums[wid] = incl;
  __syncthreads();
  if (wid == 0) {
    uint32_t v = (lane < 4) ? wsums[lane] : 0u;
    uint32_t in2 = v;
    for (int d = 1; d < 4; d <<= 1) {
      uint32_t t = __shfl_up(in2, (unsigned)d, 64);
      if (lane >= d) in2 += t;
    }
    if (lane < 4) wsums[lane] = in2 - v;
  }
  __syncthreads();
  uint32_t texcl = wsums[wid] + (incl - tsum);
  uint32_t e0 = texcl, e1 = e0 + h0, e2 = e1 + h1, e3 = e2 + h2;
  __syncthreads();
  lhist[4 * tid] = e0; lhist[4 * tid + 1] = e1;
  lhist[4 * tid + 2] = e2; lhist[4 * tid + 3] = e3;
  __syncthreads();
#pragma unroll
  for (int q = 0; q < WIN / 256; q++) {
    uint32_t j = (uint32_t)q * 256u + (uint32_t)tid;
    if (j < valid) {
      uint32_t b = e[q].x >> 22;
      uint32_t lpos = atomicAdd(&lhist[b], 1u);
      pool2[lpos] = e[q];
    }
  }
  __syncthreads();
  for (uint32_t j = tid; j < valid; j += 256) {
    uint2 p = pool2[j];
    uint32_t b = p.x >> 22;
    uint32_t st = (b == 0) ? 0u : lhist[b - 1];
    uint32_t dst = lgbase[b] + (j - st);
    if (dst < STRIDE) fine[(size_t)b * STRIDE + dst] = p;
  }
}

// ---------------------------------------------------------------------------
// K3: one 256-thread block per bin, fully LDS-resident sort (proven R6-R10).
// ---------------------------------------------------------------------------
__global__ __launch_bounds__(256) void k_binsort(const uint2* __restrict__ pairs,
                                                 const uint32_t* __restrict__ binPrefix,
                                                 float* __restrict__ donors) {
  __shared__ uint2    lbuf[BSCAP];      // 36.9 KB
  __shared__ uint32_t hist[NH];         // 4 KB
  __shared__ uint32_t wsums[4];
  int tid = threadIdx.x, lane = tid & 63, wid = tid >> 6;
  uint32_t bin = blockIdx.x;
  uint32_t gbase = binPrefix[bin];
  uint32_t cnt = binPrefix[bin + 1] - gbase;
  if (cnt > STRIDE) cnt = STRIDE;
  if (cnt > BSCAP) cnt = BSCAP;
  const uint2* src = pairs + (size_t)bin * STRIDE;

  for (int c = tid; c < 1024; c += 256) hist[c] = 0;
  __syncthreads();
  for (uint32_t j = tid; j < cnt; j += 256)
    atomicAdd(&hist[(src[j].x >> 12) & 1023u], 1u);
  __syncthreads();
  uint32_t h0 = hist[4 * tid], h1 = hist[4 * tid + 1],
           h2 = hist[4 * tid + 2], h3 = hist[4 * tid + 3];
  uint32_t tsum = h0 + h1 + h2 + h3;
  uint32_t incl = tsum;
  for (int d = 1; d < 64; d <<= 1) {
    uint32_t t = __shfl_up(incl, (unsigned)d, 64);
    if (lane >= d) incl += t;
  }
  if (lane == 63) wsums[wid] = incl;
  __syncthreads();
  if (wid == 0) {
    uint32_t v = (lane < 4) ? wsums[lane] : 0u;
    uint32_t in2 = v;
    for (int d = 1; d < 4; d <<= 1) {
      uint32_t t = __shfl_up(in2, (unsigned)d, 64);
      if (lane >= d) in2 += t;
    }
    if (lane < 4) wsums[lane] = in2 - v;
  }
  __syncthreads();
  uint32_t texcl = wsums[wid] + (incl - tsum);
  uint32_t e0 = texcl, e1 = e0 + h0, e2 = e1 + h1, e3 = e2 + h2;
  __syncthreads();
  hist[4 * tid] = e0; hist[4 * tid + 1] = e1;
  hist[4 * tid + 2] = e2; hist[4 * tid + 3] = e3;
  __syncthreads();
  for (uint32_t j = tid; j < cnt; j += 256) {
    uint2 p = src[j];
    uint32_t c = (p.x >> 12) & 1023u;
    uint32_t lpos = atomicAdd(&hist[c], 1u);
    lbuf[lpos] = p;
  }
  __syncthreads();
  for (int c = tid; c < 1024; c += 256) {
    uint32_t lo = (c == 0) ? 0u : hist[c - 1];
    uint32_t hi = hist[c];
    for (uint32_t u = lo + 1; u < hi; u++) {
      uint2 v = lbuf[u];
      uint32_t w = u;
      while (w > lo && (lbuf[w - 1].y & MASKI) > (v.y & MASKI)) {
        lbuf[w] = lbuf[w - 1];
        w--;
      }
      lbuf[w] = v;
    }
  }
  __syncthreads();
  for (uint32_t j = tid; j < cnt; j += 256) {
    uint2 p = lbuf[j];
    uint32_t v = ((p.x & 0xFFFu) << 5) | (p.y >> 27);
    donors[gbase + j] = (float)v;
  }
}

// ---------------------------------------------------------------------------
// K4: out[i] = repl ? donors[rank] : x[i].  Ballot-layout mask; float4 x-read
// and out-write; barrier-free per-wave walk after a one-shot chunk prefix.
// ---------------------------------------------------------------------------
template<bool BOUNDS>
__global__ __launch_bounds__(256) void k_final(const float* __restrict__ x,
                                               const uint64_t* __restrict__ mask,
                                               const uint32_t* __restrict__ rsums,
                                               const float* __restrict__ donors,
                                               float* __restrict__ out, int n) {
  __shared__ uint64_t lw[ELEMS_G / 64];       // 128 words, 1 KB
  __shared__ uint32_t ctot[32], cpre[32];
  int tid = threadIdx.x, lane = tid & 63, wid = tid >> 6;
  int base = blockIdx.x * ELEMS_G;
  int wordBase = blockIdx.x * (ELEMS_G / 64);
  if (tid < ELEMS_G / 64) {
    uint64_t w = 0ull;
    int wI = wordBase + tid;
    if (!BOUNDS || (((wI >> 2) * 256) + ((wI & 3) * 64) < n)) w = mask[wI];
    lw[tid] = w;
  }
  __syncthreads();
  if (tid < 32) {
    ctot[tid] = (uint32_t)(__popcll(lw[4 * tid]) + __popcll(lw[4 * tid + 1]) +
                           __popcll(lw[4 * tid + 2]) + __popcll(lw[4 * tid + 3]));
  }
  __syncthreads();
  if (tid == 0) {
    uint32_t run = 0;
    for (int c = 0; c < 32; c++) { cpre[c] = run; run += ctot[c]; }
  }
  __syncthreads();
  uint32_t rbase = rsums[blockIdx.x];
  uint64_t lt = (1ull << lane) - 1ull;
  for (int it = 0; it < ELEMS_G / 1024; it++) {
    int c = it * 4 + wid;
    uint64_t b0 = lw[c * 4 + 0], b1 = lw[c * 4 + 1],
             b2 = lw[c * 4 + 2], b3 = lw[c * 4 + 3];
    uint32_t running = rbase + cpre[c];
    int e0 = base + it * 1024 + wid * 256 + lane * 4;
    uint32_t below = (uint32_t)(__popcll(b0 & lt) + __popcll(b1 & lt) +
                                __popcll(b2 & lt) + __popcll(b3 & lt));
    uint32_t r0 = (uint32_t)((b0 >> lane) & 1ull), r1 = (uint32_t)((b1 >> lane) & 1ull);
    uint32_t r2 = (uint32_t)((b2 >> lane) & 1ull), r3 = (uint32_t)((b3 >> lane) & 1ull);
    uint32_t rk = running + below;
    float4 xv;
    if (!BOUNDS || e0 + 3 < n) {
      xv = *reinterpret_cast<const float4*>(x + e0);
    } else {
      xv.x = (e0 + 0 < n) ? x[e0 + 0] : 0.0f;
      xv.y = (e0 + 1 < n) ? x[e0 + 1] : 0.0f;
      xv.z = (e0 + 2 < n) ? x[e0 + 2] : 0.0f;
      xv.w = (e0 + 3 < n) ? x[e0 + 3] : 0.0f;
    }
    float4 ov;
    ov.x = r0 ? donors[rk] : xv.x;               rk += r0;
    ov.y = r1 ? donors[rk] : xv.y;               rk += r1;
    ov.z = r2 ? donors[rk] : xv.z;               rk += r2;
    ov.w = r3 ? donors[rk] : xv.w;
    if (!BOUNDS || e0 + 3 < n) {
      *reinterpret_cast<float4*>(out + e0) = ov;
    } else {
      if (e0 + 0 < n) out[e0 + 0] = ov.x;
      if (e0 + 1 < n) out[e0 + 1] = ov.y;
      if (e0 + 2 < n) out[e0 + 2] = ov.z;
      if (e0 + 3 < n) out[e0 + 3] = ov.w;
    }
  }
}

// ---------------------------------------------------------------------------
extern "C" void kernel_launch(void* const* d_in, const int* in_sizes, int n_in,
                              void* d_out, int out_size, void* d_ws, size_t ws_size,
                              hipStream_t stream) {
  const float* x = (const float*)d_in[0];
  float* out = (float*)d_out;
  int n = in_sizes[0];
  (void)n_in; (void)out_size; (void)ws_size;

  uint32_t bk0, bk1, sk0, sk1;
  tf2x32(0u, 42u, 0u, 0u, bk0, bk1);
  tf2x32(0u, 42u, 0u, 1u, sk0, sk1);

  int nBlkG = (n + ELEMS_G - 1) / ELEMS_G;     // 4096
  bool exact = ((n % ELEMS_G) == 0);

  size_t off = 0;
  auto alloc = [&](size_t bytes) -> void* {
    void* p = (uint8_t*)d_ws + off;
    off += (bytes + 255) & ~(size_t)255;
    return p;
  };
  uint32_t* dumpCursor = (uint32_t*)alloc(4);
  uint32_t* fineCursor = (uint32_t*)alloc((size_t)(NH + 1) * 4);
  uint32_t* rsums      = (uint32_t*)alloc((size_t)(nBlkG + 1) * 4);
  uint64_t* mask       = (uint64_t*)alloc((size_t)((n + 63) / 64 + 4) * 8); // 4 MB
  uint2*    dump       = (uint2*)alloc((size_t)CAPDUMP * 8);               // 31.5 MB
  uint2*    fine       = (uint2*)alloc((size_t)NBINS2 * STRIDE * 8);       // 33.0 MB
  float*    donors     = (float*)dump;   // alias: dump dead after k_regroup

  hipMemsetAsync(dumpCursor, 0, (size_t)(NH + 2) * 4 + 512, stream);

  if (exact)
    k_gen<false><<<nBlkG, 256, 0, stream>>>(x, mask, rsums, dumpCursor, dump,
                                            bk0, bk1, sk0, sk1, n);
  else
    k_gen<true><<<nBlkG, 256, 0, stream>>>(x, mask, rsums, dumpCursor, dump,
                                           bk0, bk1, sk0, sk1, n);
  int nWin = (int)((CAPDUMP + WIN - 1) / WIN);    // 480
  k_regroup<<<nWin, 256, 0, stream>>>(dump, dumpCursor, fineCursor, fine);
  k_scan2<<<2, 256, 0, stream>>>(rsums, nBlkG, fineCursor, (int)NBINS2);
  k_binsort<<<(int)NBINS2, 256, 0, stream>>>(fine, fineCursor, donors);
  if (exact)
    k_final<false><<<nBlkG, 256, 0, stream>>>(x, mask, rsums, donors, out, n);
  else
    k_final<true><<<nBlkG, 256, 0, stream>>>(x, mask, rsums, donors, out, n);
}

// Round 12
// 334.938 us; speedup vs baseline: 14.8415x; 1.0104x over previous
//
#include <hip/hip_runtime.h>
#include <stdint.h>

// ---------------------------------------------------------------------------
// JAX threefry2x32 (20 rounds), bit-exact port of jax/_src/prng.py
// ---------------------------------------------------------------------------
static __host__ __device__ inline uint32_t rotl32(uint32_t x, int r) {
#if defined(__HIP_DEVICE_COMPILE__)
  return __builtin_amdgcn_alignbit(x, x, (uint32_t)(32 - r));
#else
  return (x << r) | (x >> (32 - r));
#endif
}

static __host__ __device__ inline void tf2x32(uint32_t k0, uint32_t k1,
                                              uint32_t x0, uint32_t x1,
                                              uint32_t& o0, uint32_t& o1) {
  uint32_t k2 = k0 ^ k1 ^ 0x1BD11BDAu;
#define TFR(a) { x0 += x1; x1 = rotl32(x1, a); x1 ^= x0; }
  x0 += k0; x1 += k1;
  TFR(13) TFR(15) TFR(26) TFR(6)
  x0 += k1; x1 += k2 + 1u;
  TFR(17) TFR(29) TFR(16) TFR(24)
  x0 += k2; x1 += k0 + 2u;
  TFR(13) TFR(15) TFR(26) TFR(6)
  x0 += k0; x1 += k1 + 3u;
  TFR(17) TFR(29) TFR(16) TFR(24)
  x0 += k1; x1 += k2 + 4u;
  TFR(13) TFR(15) TFR(26) TFR(6)
  x0 += k2; x1 += k0 + 5u;
#undef TFR
  o0 = x0; o1 = x1;
}

static __device__ inline uint32_t fold_bits(uint32_t k0, uint32_t k1, uint32_t ctr) {
  uint32_t a, b;
  tf2x32(k0, k1, 0u, ctr, a, b);
  return a ^ b;
}

// Candidates: m = bits>>9 < CUT2 (=7*2^17, 10.94%). E[C]=3.670M >= R~3.355M
// (+125 sigma). Bin = m>>9 in [0,1792); within-bin bucket = m & 511.
#define CUT2      917504u        // 7 << 17
#define NBINS2    1792u          // bins (mean 2048/bin, sd 45)
#define NH        2048           // regroup hist array size (pow2)
#define ELEMS_G   8192           // k_gen / k_final block span
#define GPOOL     1216u          // k_gen LDS pool (mean 896, +11 sigma)
#define BSCAP     2432u          // binsort LDS buf (mean 2048, +8.5 sigma)
#define WIN       4096           // regroup window (entries)
#define CAPDUMP   3932160u       // dump capacity (mean 3.670M, +145 sigma)
#define STRIDE    2432u          // fine region stride
#define MASKI     0x07FFFFFFu
// bernoulli: u < 0.1f  <=>  mant < 838861  (exact; 0.1f = 0x3DCCCCCD)
#define BERN_THR  838861u

// pair packing: .x = (m<<12) | (value>>5)    [m:20 | v_hi:12]
//               .y = ((value&31)<<27) | idx  [v_lo:5 | 00 | idx:25]
// bin = .x>>21 (m>>9);  fine bucket c = (.x>>12)&511 (m&511)

// MASK FORMAT: chunk = 256 elems per wave-iter; lane L holds elems
// chunkBase+4L+e; mask[chunk*4+e] = ballot(repl_e). chunk = blk*32+it*4+wid.

// ---------------------------------------------------------------------------
// K1: threefry + ballot-mask/rsums + wave-aggregated LDS pool append +
// coalesced dense dump. One global atomic per block.
// ---------------------------------------------------------------------------
template<bool BOUNDS>
__global__ __launch_bounds__(256) void k_gen(const float* __restrict__ x,
                                             uint64_t* __restrict__ mask,
                                             uint32_t* __restrict__ rsums,
                                             uint32_t* __restrict__ dumpCursor,
                                             uint2* __restrict__ dump,
                                             uint32_t bk0, uint32_t bk1,
                                             uint32_t sk0, uint32_t sk1, int n) {
  __shared__ uint2 pool[GPOOL];          // 9.7 KB
  __shared__ uint32_t wcnt[4];
  __shared__ uint32_t lpoolCnt, lgbase;
  int tid = threadIdx.x, lane = tid & 63, wid = tid >> 6;
  int base = blockIdx.x * ELEMS_G;
  if (tid == 0) lpoolCnt = 0;
  __syncthreads();

  uint32_t cnt = 0;                      // wave-uniform (SALU popcounts)
  uint64_t lt = (1ull << lane) - 1ull;
  unsigned long long bball[4];
  for (int it = 0; it < ELEMS_G / 1024; it++) {        // 8 iterations x 1024 elems
    int e0 = base + it * 1024 + wid * 256 + lane * 4;  // 16B-aligned
    float4 xv;
    if (!BOUNDS || e0 + 3 < n) {
      xv = *reinterpret_cast<const float4*>(x + e0);
    } else {
      xv.x = (e0 + 0 < n) ? x[e0 + 0] : 0.0f;
      xv.y = (e0 + 1 < n) ? x[e0 + 1] : 0.0f;
      xv.z = (e0 + 2 < n) ? x[e0 + 2] : 0.0f;
      xv.w = (e0 + 3 < n) ? x[e0 + 3] : 0.0f;
    }
#define GENE(e, comp)                                                     \
    {                                                                     \
      uint32_t ii = (uint32_t)(e0 + e);                                   \
      bool np = (comp != 0.0f);                                           \
      uint32_t bb = fold_bits(bk0, bk1, ii);                              \
      bool rr = np && ((bb >> 9) < BERN_THR);                             \
      bball[e] = __ballot(rr);                                            \
      uint32_t mm = fold_bits(sk0, sk1, ii) >> 9;                         \
      bool cand = np && (mm < CUT2);                                      \
      unsigned long long cb = __ballot(cand);                             \
      uint32_t pb = 0;                                                    \
      if (lane == 0 && cb) pb = atomicAdd(&lpoolCnt, (uint32_t)__popcll(cb)); \
      pb = __builtin_amdgcn_readfirstlane(pb);                            \
      if (cand) {                                                         \
        uint32_t slot = pb + (uint32_t)__popcll(cb & lt);                 \
        if (slot < GPOOL) {                                               \
          uint32_t v = (uint32_t)comp;                                    \
          pool[slot] = make_uint2((mm << 12) | (v >> 5),                  \
                                  ((v & 31u) << 27) | ii);                \
        }                                                                 \
      }                                                                   \
    }
    GENE(0, xv.x) GENE(1, xv.y) GENE(2, xv.z) GENE(3, xv.w)
#undef GENE
    cnt += (uint32_t)(__popcll(bball[0]) + __popcll(bball[1]) +
                      __popcll(bball[2]) + __popcll(bball[3]));
    if (lane == 0) {
      uint32_t ci = (uint32_t)blockIdx.x * 32u + (uint32_t)it * 4u + (uint32_t)wid;
      if (!BOUNDS) {
        mask[ci * 4 + 0] = bball[0]; mask[ci * 4 + 1] = bball[1];
        mask[ci * 4 + 2] = bball[2]; mask[ci * 4 + 3] = bball[3];
      } else {
        for (int e = 0; e < 4; e++)
          if ((int)(ci * 256u + (uint32_t)e * 64u) < n) mask[ci * 4 + e] = bball[e];
      }
    }
  }
  if (lane == 0) wcnt[wid] = cnt;
  __syncthreads();
  if (tid == 0) {
    rsums[blockIdx.x] = wcnt[0] + wcnt[1] + wcnt[2] + wcnt[3];
    uint32_t pc = lpoolCnt; if (pc > GPOOL) pc = GPOOL;
    lgbase = atomicAdd((unsigned int*)dumpCursor, pc);   // ONE atomic per block
  }
  __syncthreads();
  uint32_t pc = lpoolCnt; if (pc > GPOOL) pc = GPOOL;
  uint32_t gb = lgbase;
  for (uint32_t j = tid; j < pc; j += 256) {
    uint32_t d = gb + j;
    if (d < CAPDUMP) dump[d] = pool[j];                  // coalesced stream
  }
}

// ---------------------------------------------------------------------------
// 2-target exclusive scan: block 0 scans data0[n0], block 1 scans data1[n1].
// In place; writes data[n] = total (alloc n+1!)
// ---------------------------------------------------------------------------
__global__ void k_scan2(uint32_t* __restrict__ data0, int n0,
                        uint32_t* __restrict__ data1, int n1) {
  __shared__ uint32_t wsum[4];
  uint32_t* data = (blockIdx.x == 0) ? data0 : data1;
  int n = (blockIdx.x == 0) ? n0 : n1;
  int tid = threadIdx.x, lane = tid & 63, wid = tid >> 6;
  uint32_t running = 0;
  for (int base = 0; base < n; base += 256) {
    int i = base + tid;
    uint32_t v = (i < n) ? data[i] : 0u;
    uint32_t incl = v;
    for (int d = 1; d < 64; d <<= 1) {
      uint32_t t = __shfl_up(incl, (unsigned)d, 64);
      if (lane >= d) incl += t;
    }
    if (lane == 63) wsum[wid] = incl;
    __syncthreads();
    uint32_t woff = 0, tot = 0;
    for (int w = 0; w < 4; w++) { uint32_t s = wsum[w]; if (w < wid) woff += s; tot += s; }
    if (i < n) data[i] = running + woff + (incl - v);
    running += tot;
    __syncthreads();
  }
  if (tid == 0) data[n] = running;
}

// ---------------------------------------------------------------------------
// K2: regroup dense dump -> 1792 fixed-stride bin regions.
// WIN=4096, NH=2048 -> ~49 KB LDS -> 3 blocks/CU; 960 blocks.
// ---------------------------------------------------------------------------
__global__ __launch_bounds__(256) void k_regroup(const uint2* __restrict__ dump,
                                                 const uint32_t* __restrict__ dumpCursor,
                                                 uint32_t* __restrict__ fineCursor,
                                                 uint2* __restrict__ fine) {
  __shared__ uint2    pool2[WIN];        // 32 KB
  __shared__ uint32_t lhist[NH];         // 8 KB
  __shared__ uint32_t lgbase[NH];        // 8 KB
  __shared__ uint32_t wsums[4];
  int tid = threadIdx.x, lane = tid & 63, wid = tid >> 6;
  uint32_t total = dumpCursor[0];
  if (total > CAPDUMP) total = CAPDUMP;
  uint32_t wbase = blockIdx.x * (uint32_t)WIN;
  if (wbase >= total) return;
  uint32_t valid = total - wbase;
  if (valid > WIN) valid = WIN;

  for (int b = tid; b < NH; b += 256) lhist[b] = 0;
  __syncthreads();
  uint2 e[WIN / 256];                    // 16 regs-pairs, static indexed
#pragma unroll
  for (int q = 0; q < WIN / 256; q++) {
    uint32_t j = (uint32_t)q * 256u + (uint32_t)tid;
    e[q] = (j < valid) ? dump[wbase + j] : make_uint2(0u, 0u);
    if (j < valid) atomicAdd(&lhist[e[q].x >> 21], 1u);
  }
  __syncthreads();
  for (int b = tid; b < NH; b += 256) {
    uint32_t h = lhist[b];
    lgbase[b] = h ? atomicAdd((unsigned int*)&fineCursor[b], h) : 0u;
  }
  __syncthreads();
  // block exclusive scan of lhist[2048]; thread owns entries [8t, 8t+8)
  uint32_t hv[8], tsum = 0;
#pragma unroll
  for (int j = 0; j < 8; j++) { hv[j] = lhist[8 * tid + j]; tsum += hv[j]; }
  uint32_t incl = tsum;
  for (int d = 1; d < 64; d <<= 1) {
    uint32_t t = __shfl_up(incl, (unsigned)d, 64);
    if (lane >= d) incl += t;
  }
  if (lane == 63) wsums[wid] = incl;
  __syncthreads();
  if (wid == 0) {
    uint32_t v = (lane < 4) ? wsums[lane] : 0u;
    uint32_t in2 = v;
    for (int d = 1; d < 4; d <<= 1) {
      uint32_t t = __shfl_up(in2, (unsigned)d, 64);
      if (lane >= d) in2 += t;
    }
    if (lane < 4) wsums[lane] = in2 - v;   // exclusive wave base
  }
  __syncthreads();
  uint32_t run = wsums[wid] + (incl - tsum);
#pragma unroll
  for (int j = 0; j < 8; j++) { uint32_t h = hv[j]; lhist[8 * tid + j] = run; run += h; }
  __syncthreads();
  // scatter registers -> pool2 grouped by bin
#pragma unroll
  for (int q = 0; q < WIN / 256; q++) {
    uint32_t j = (uint32_t)q * 256u + (uint32_t)tid;
    if (j < valid) {
      uint32_t b = e[q].x >> 21;
      uint32_t lpos = atomicAdd(&lhist[b], 1u);
      pool2[lpos] = e[q];
    }
  }
  __syncthreads();
  // bin-grouped global writes; start[b] = (b==0)?0:lhist[b-1] (= end[b-1])
  for (uint32_t j = tid; j < valid; j += 256) {
    uint2 p = pool2[j];
    uint32_t b = p.x >> 21;
    uint32_t st = (b == 0) ? 0u : lhist[b - 1];
    uint32_t dst = lgbase[b] + (j - st);
    if (dst < STRIDE) fine[(size_t)b * STRIDE + dst] = p;
  }
}

// ---------------------------------------------------------------------------
// K3: one 256-thread block per bin, LDS-resident sort. ~21.5 KB -> 7 blk/CU.
// ---------------------------------------------------------------------------
__global__ __launch_bounds__(256) void k_binsort(const uint2* __restrict__ pairs,
                                                 const uint32_t* __restrict__ binPrefix,
                                                 float* __restrict__ donors) {
  __shared__ uint2    lbuf[BSCAP];      // 19.5 KB
  __shared__ uint32_t hist[512];        // 2 KB (fine buckets m & 511)
  __shared__ uint32_t wsums[4];
  int tid = threadIdx.x, lane = tid & 63, wid = tid >> 6;
  uint32_t bin = blockIdx.x;
  uint32_t gbase = binPrefix[bin];
  uint32_t cnt = binPrefix[bin + 1] - gbase;
  if (cnt > STRIDE) cnt = STRIDE;
  if (cnt > BSCAP) cnt = BSCAP;
  const uint2* src = pairs + (size_t)bin * STRIDE;

  for (int c = tid; c < 512; c += 256) hist[c] = 0;
  __syncthreads();
  for (uint32_t j = tid; j < cnt; j += 256)
    atomicAdd(&hist[(src[j].x >> 12) & 511u], 1u);
  __syncthreads();
  // block exclusive scan of hist[512]; thread owns [2t, 2t+2)
  uint32_t h0 = hist[2 * tid], h1 = hist[2 * tid + 1];
  uint32_t tsum = h0 + h1;
  uint32_t incl = tsum;
  for (int d = 1; d < 64; d <<= 1) {
    uint32_t t = __shfl_up(incl, (unsigned)d, 64);
    if (lane >= d) incl += t;
  }
  if (lane == 63) wsums[wid] = incl;
  __syncthreads();
  if (wid == 0) {
    uint32_t v = (lane < 4) ? wsums[lane] : 0u;
    uint32_t in2 = v;
    for (int d = 1; d < 4; d <<= 1) {
      uint32_t t = __shfl_up(in2, (unsigned)d, 64);
      if (lane >= d) in2 += t;
    }
    if (lane < 4) wsums[lane] = in2 - v;
  }
  __syncthreads();
  uint32_t texcl = wsums[wid] + (incl - tsum);
  uint32_t e0 = texcl, e1 = e0 + h0;
  __syncthreads();   // all hist reads done before overwrite
  hist[2 * tid] = e0; hist[2 * tid + 1] = e1;
  __syncthreads();
  // counting-scatter into LDS at exact slots
  for (uint32_t j = tid; j < cnt; j += 256) {
    uint2 p = src[j];
    uint32_t c = (p.x >> 12) & 511u;
    uint32_t lpos = atomicAdd(&hist[c], 1u);
    lbuf[lpos] = p;
  }
  __syncthreads();
  // stabilize ties by idx (avg 4/bucket)
  for (int c = tid; c < 512; c += 256) {
    uint32_t lo = (c == 0) ? 0u : hist[c - 1];
    uint32_t hi = hist[c];
    for (uint32_t u = lo + 1; u < hi; u++) {
      uint2 v = lbuf[u];
      uint32_t w = u;
      while (w > lo && (lbuf[w - 1].y & MASKI) > (v.y & MASKI)) {
        lbuf[w] = lbuf[w - 1];
        w--;
      }
      lbuf[w] = v;
    }
  }
  __syncthreads();
  // coalesced donor-value stream
  for (uint32_t j = tid; j < cnt; j += 256) {
    uint2 p = lbuf[j];
    uint32_t v = ((p.x & 0xFFFu) << 5) | (p.y >> 27);
    donors[gbase + j] = (float)v;
  }
}

// ---------------------------------------------------------------------------
// K4: out[i] = repl ? donors[rank] : x[i]. Ballot-layout mask; float4 I/O;
// barrier-free per-wave walk after a one-shot chunk prefix.
// ---------------------------------------------------------------------------
template<bool BOUNDS>
__global__ __launch_bounds__(256) void k_final(const float* __restrict__ x,
                                               const uint64_t* __restrict__ mask,
                                               const uint32_t* __restrict__ rsums,
                                               const float* __restrict__ donors,
                                               float* __restrict__ out, int n) {
  __shared__ uint64_t lw[ELEMS_G / 64];       // 128 words, 1 KB
  __shared__ uint32_t ctot[32], cpre[32];
  int tid = threadIdx.x, lane = tid & 63, wid = tid >> 6;
  int base = blockIdx.x * ELEMS_G;
  int wordBase = blockIdx.x * (ELEMS_G / 64);
  if (tid < ELEMS_G / 64) {
    uint64_t w = 0ull;
    int wI = wordBase + tid;
    if (!BOUNDS || (((wI >> 2) * 256) + ((wI & 3) * 64) < n)) w = mask[wI];
    lw[tid] = w;
  }
  __syncthreads();
  if (tid < 32) {
    ctot[tid] = (uint32_t)(__popcll(lw[4 * tid]) + __popcll(lw[4 * tid + 1]) +
                           __popcll(lw[4 * tid + 2]) + __popcll(lw[4 * tid + 3]));
  }
  __syncthreads();
  if (tid == 0) {
    uint32_t run = 0;
    for (int c = 0; c < 32; c++) { cpre[c] = run; run += ctot[c]; }
  }
  __syncthreads();
  uint32_t rbase = rsums[blockIdx.x];
  uint64_t lt = (1ull << lane) - 1ull;
  for (int it = 0; it < ELEMS_G / 1024; it++) {
    int c = it * 4 + wid;
    uint64_t b0 = lw[c * 4 + 0], b1 = lw[c * 4 + 1],
             b2 = lw[c * 4 + 2], b3 = lw[c * 4 + 3];
    uint32_t running = rbase + cpre[c];
    int e0 = base + it * 1024 + wid * 256 + lane * 4;
    uint32_t below = (uint32_t)(__popcll(b0 & lt) + __popcll(b1 & lt) +
                                __popcll(b2 & lt) + __popcll(b3 & lt));
    uint32_t r0 = (uint32_t)((b0 >> lane) & 1ull), r1 = (uint32_t)((b1 >> lane) & 1ull);
    uint32_t r2 = (uint32_t)((b2 >> lane) & 1ull), r3 = (uint32_t)((b3 >> lane) & 1ull);
    uint32_t rk = running + below;
    float4 xv;
    if (!BOUNDS || e0 + 3 < n) {
      xv = *reinterpret_cast<const float4*>(x + e0);
    } else {
      xv.x = (e0 + 0 < n) ? x[e0 + 0] : 0.0f;
      xv.y = (e0 + 1 < n) ? x[e0 + 1] : 0.0f;
      xv.z = (e0 + 2 < n) ? x[e0 + 2] : 0.0f;
      xv.w = (e0 + 3 < n) ? x[e0 + 3] : 0.0f;
    }
    float4 ov;
    ov.x = r0 ? donors[rk] : xv.x;               rk += r0;
    ov.y = r1 ? donors[rk] : xv.y;               rk += r1;
    ov.z = r2 ? donors[rk] : xv.z;               rk += r2;
    ov.w = r3 ? donors[rk] : xv.w;
    if (!BOUNDS || e0 + 3 < n) {
      *reinterpret_cast<float4*>(out + e0) = ov;
    } else {
      if (e0 + 0 < n) out[e0 + 0] = ov.x;
      if (e0 + 1 < n) out[e0 + 1] = ov.y;
      if (e0 + 2 < n) out[e0 + 2] = ov.z;
      if (e0 + 3 < n) out[e0 + 3] = ov.w;
    }
  }
}

// ---------------------------------------------------------------------------
extern "C" void kernel_launch(void* const* d_in, const int* in_sizes, int n_in,
                              void* d_out, int out_size, void* d_ws, size_t ws_size,
                              hipStream_t stream) {
  const float* x = (const float*)d_in[0];
  float* out = (float*)d_out;
  int n = in_sizes[0];
  (void)n_in; (void)out_size; (void)ws_size;

  uint32_t bk0, bk1, sk0, sk1;
  tf2x32(0u, 42u, 0u, 0u, bk0, bk1);
  tf2x32(0u, 42u, 0u, 1u, sk0, sk1);

  int nBlkG = (n + ELEMS_G - 1) / ELEMS_G;     // 4096
  bool exact = ((n % ELEMS_G) == 0);

  size_t off = 0;
  auto alloc = [&](size_t bytes) -> void* {
    void* p = (uint8_t*)d_ws + off;
    off += (bytes + 255) & ~(size_t)255;
    return p;
  };
  uint32_t* dumpCursor = (uint32_t*)alloc(4);
  uint32_t* fineCursor = (uint32_t*)alloc((size_t)(NH + 1) * 4);
  size_t zeroBytes = off;                       // zero both cursor blocks
  uint32_t* rsums      = (uint32_t*)alloc((size_t)(nBlkG + 1) * 4);
  uint64_t* mask       = (uint64_t*)alloc((size_t)((n + 63) / 64 + 4) * 8); // 4 MB
  uint2*    dump       = (uint2*)alloc((size_t)CAPDUMP * 8);               // 31.5 MB
  uint2*    fine       = (uint2*)alloc((size_t)NBINS2 * STRIDE * 8);       // 34.9 MB
  float*    donors     = (float*)dump;   // alias: dump dead after k_regroup

  hipMemsetAsync(d_ws, 0, zeroBytes, stream);

  if (exact)
    k_gen<false><<<nBlkG, 256, 0, stream>>>(x, mask, rsums, dumpCursor, dump,
                                            bk0, bk1, sk0, sk1, n);
  else
    k_gen<true><<<nBlkG, 256, 0, stream>>>(x, mask, rsums, dumpCursor, dump,
                                           bk0, bk1, sk0, sk1, n);
  int nWin = (int)((CAPDUMP + WIN - 1) / WIN);    // 960
  k_regroup<<<nWin, 256, 0, stream>>>(dump, dumpCursor, fineCursor, fine);
  k_scan2<<<2, 256, 0, stream>>>(rsums, nBlkG, fineCursor, (int)NBINS2);
  k_binsort<<<(int)NBINS2, 256, 0, stream>>>(fine, fineCursor, donors);
  if (exact)
    k_final<false><<<nBlkG, 256, 0, stream>>>(x, mask, rsums, donors, out, n);
  else
    k_final<true><<<nBlkG, 256, 0, stream>>>(x, mask, rsums, donors, out, n);
}

// Round 13
// 330.029 us; speedup vs baseline: 15.0622x; 1.0149x over previous
//
#include <hip/hip_runtime.h>
#include <stdint.h>

// ---------------------------------------------------------------------------
// JAX threefry2x32 (20 rounds), bit-exact port of jax/_src/prng.py
// ---------------------------------------------------------------------------
static __host__ __device__ inline uint32_t rotl32(uint32_t x, int r) {
#if defined(__HIP_DEVICE_COMPILE__)
  return __builtin_amdgcn_alignbit(x, x, (uint32_t)(32 - r));
#else
  return (x << r) | (x >> (32 - r));
#endif
}

static __host__ __device__ inline void tf2x32(uint32_t k0, uint32_t k1,
                                              uint32_t x0, uint32_t x1,
                                              uint32_t& o0, uint32_t& o1) {
  uint32_t k2 = k0 ^ k1 ^ 0x1BD11BDAu;
#define TFR(a) { x0 += x1; x1 = rotl32(x1, a); x1 ^= x0; }
  x0 += k0; x1 += k1;
  TFR(13) TFR(15) TFR(26) TFR(6)
  x0 += k1; x1 += k2 + 1u;
  TFR(17) TFR(29) TFR(16) TFR(24)
  x0 += k2; x1 += k0 + 2u;
  TFR(13) TFR(15) TFR(26) TFR(6)
  x0 += k0; x1 += k1 + 3u;
  TFR(17) TFR(29) TFR(16) TFR(24)
  x0 += k1; x1 += k2 + 4u;
  TFR(13) TFR(15) TFR(26) TFR(6)
  x0 += k2; x1 += k0 + 5u;
#undef TFR
  o0 = x0; o1 = x1;
}

static __device__ inline uint32_t fold_bits(uint32_t k0, uint32_t k1, uint32_t ctr) {
  uint32_t a, b;
  tf2x32(k0, k1, 0u, ctr, a, b);
  return a ^ b;
}

// Candidates: m = bits>>9 < CUT2 (=7*2^17, 10.94%). E[C]=3.670M >= R~3.355M.
// coarse bin = m>>14 in [0,56); fine bin = m>>9 in [0,1792); bucket = m&511.
#define CUT2      917504u        // 7 << 17
#define NCOARSE   56u
#define CSTRIDE   69632u         // per-coarse region (mean 65536, +16 sigma)
#define WPC       17u            // windows per coarse region (69632/4096)
#define NFINE     1792u
#define STRIDE    2432u          // fine region stride (mean 2048, +8.5 sigma)
#define BSCAP     2432u
#define ELEMS_G   8192           // gen/final block span
#define GPOOL     1216u          // k_cand LDS pool (mean 896, +11 sigma)
#define WIN       4096           // regroup window (entries)
#define CAPDUMP   3932160u       // dump capacity (mean 3.670M, +145 sigma)
#define MASKI     0x07FFFFFFu
#define BERN_THR  838861u        // u < 0.1f <=> mant < 838861 (exact)

// pair packing: .x = (m<<12) | (value>>5)    [m:20 | v_hi:12]
//               .y = ((value&31)<<27) | idx  [v_lo:5 | 00 | idx:25]
// coarse = .x>>26; fine-in-coarse = (.x>>21)&31; bucket = (.x>>12)&511

// MASK FORMAT: chunk = 256 elems per wave-iter; lane L holds elems
// chunkBase+4L+e; mask[chunk*4+e] = ballot(repl_e). chunk = blk*32+it*4+wid.

// ---------------------------------------------------------------------------
// K1a: bernoulli fold ONLY -> ballot mask + rsums. Branchless, no LDS pool,
// no atomics. Isolates the cost of one full threefry pass over N.
// ---------------------------------------------------------------------------
template<bool BOUNDS>
__global__ __launch_bounds__(256) void k_bern(const float* __restrict__ x,
                                              uint64_t* __restrict__ mask,
                                              uint32_t* __restrict__ rsums,
                                              uint32_t bk0, uint32_t bk1, int n) {
  __shared__ uint32_t wcnt[4];
  int tid = threadIdx.x, lane = tid & 63, wid = tid >> 6;
  int base = blockIdx.x * ELEMS_G;
  uint32_t cnt = 0;
  unsigned long long bball[4];
  for (int it = 0; it < ELEMS_G / 1024; it++) {
    int e0 = base + it * 1024 + wid * 256 + lane * 4;
    float4 xv;
    if (!BOUNDS || e0 + 3 < n) {
      xv = *reinterpret_cast<const float4*>(x + e0);
    } else {
      xv.x = (e0 + 0 < n) ? x[e0 + 0] : 0.0f;
      xv.y = (e0 + 1 < n) ? x[e0 + 1] : 0.0f;
      xv.z = (e0 + 2 < n) ? x[e0 + 2] : 0.0f;
      xv.w = (e0 + 3 < n) ? x[e0 + 3] : 0.0f;
    }
#define BERNE(e, comp)                                                    \
    {                                                                     \
      uint32_t ii = (uint32_t)(e0 + e);                                   \
      uint32_t bb = fold_bits(bk0, bk1, ii);                              \
      bool rr = (comp != 0.0f) && ((bb >> 9) < BERN_THR);                 \
      bball[e] = __ballot(rr);                                            \
    }
    BERNE(0, xv.x) BERNE(1, xv.y) BERNE(2, xv.z) BERNE(3, xv.w)
#undef BERNE
    cnt += (uint32_t)(__popcll(bball[0]) + __popcll(bball[1]) +
                      __popcll(bball[2]) + __popcll(bball[3]));
    if (lane == 0) {
      uint32_t ci = (uint32_t)blockIdx.x * 32u + (uint32_t)it * 4u + (uint32_t)wid;
      if (!BOUNDS) {
        mask[ci * 4 + 0] = bball[0]; mask[ci * 4 + 1] = bball[1];
        mask[ci * 4 + 2] = bball[2]; mask[ci * 4 + 3] = bball[3];
      } else {
        for (int e = 0; e < 4; e++)
          if ((int)(ci * 256u + (uint32_t)e * 64u) < n) mask[ci * 4 + e] = bball[e];
      }
    }
  }
  if (lane == 0) wcnt[wid] = cnt;
  __syncthreads();
  if (tid == 0) rsums[blockIdx.x] = wcnt[0] + wcnt[1] + wcnt[2] + wcnt[3];
}

// ---------------------------------------------------------------------------
// K1b: shuffle fold + wave-aggregated LDS pool + coalesced dense dump.
// ---------------------------------------------------------------------------
template<bool BOUNDS>
__global__ __launch_bounds__(256) void k_cand(const float* __restrict__ x,
                                              uint32_t* __restrict__ dumpCursor,
                                              uint2* __restrict__ dump,
                                              uint32_t sk0, uint32_t sk1, int n) {
  __shared__ uint2 pool[GPOOL];          // 9.7 KB
  __shared__ uint32_t lpoolCnt, lgbase;
  int tid = threadIdx.x, lane = tid & 63, wid = tid >> 6;
  int base = blockIdx.x * ELEMS_G;
  if (tid == 0) lpoolCnt = 0;
  __syncthreads();
  uint64_t lt = (1ull << lane) - 1ull;
  for (int it = 0; it < ELEMS_G / 1024; it++) {
    int e0 = base + it * 1024 + wid * 256 + lane * 4;
    float4 xv;
    if (!BOUNDS || e0 + 3 < n) {
      xv = *reinterpret_cast<const float4*>(x + e0);
    } else {
      xv.x = (e0 + 0 < n) ? x[e0 + 0] : 0.0f;
      xv.y = (e0 + 1 < n) ? x[e0 + 1] : 0.0f;
      xv.z = (e0 + 2 < n) ? x[e0 + 2] : 0.0f;
      xv.w = (e0 + 3 < n) ? x[e0 + 3] : 0.0f;
    }
#define CANDE(e, comp)                                                    \
    {                                                                     \
      uint32_t ii = (uint32_t)(e0 + e);                                   \
      uint32_t mm = fold_bits(sk0, sk1, ii) >> 9;                         \
      bool cand = (comp != 0.0f) && (mm < CUT2);                          \
      unsigned long long cb = __ballot(cand);                             \
      uint32_t pb = 0;                                                    \
      if (lane == 0 && cb) pb = atomicAdd(&lpoolCnt, (uint32_t)__popcll(cb)); \
      pb = __builtin_amdgcn_readfirstlane(pb);                            \
      if (cand) {                                                         \
        uint32_t slot = pb + (uint32_t)__popcll(cb & lt);                 \
        if (slot < GPOOL) {                                               \
          uint32_t v = (uint32_t)comp;                                    \
          pool[slot] = make_uint2((mm << 12) | (v >> 5),                  \
                                  ((v & 31u) << 27) | ii);                \
        }                                                                 \
      }                                                                   \
    }
    CANDE(0, xv.x) CANDE(1, xv.y) CANDE(2, xv.z) CANDE(3, xv.w)
#undef CANDE
  }
  __syncthreads();
  if (tid == 0) {
    uint32_t pc = lpoolCnt; if (pc > GPOOL) pc = GPOOL;
    lgbase = atomicAdd((unsigned int*)dumpCursor, pc);
  }
  __syncthreads();
  uint32_t pc = lpoolCnt; if (pc > GPOOL) pc = GPOOL;
  uint32_t gb = lgbase;
  for (uint32_t j = tid; j < pc; j += 256) {
    uint32_t d = gb + j;
    if (d < CAPDUMP) dump[d] = pool[j];
  }
}

// ---------------------------------------------------------------------------
// 2-target exclusive scan (in place; writes data[n] = total, alloc n+1)
// ---------------------------------------------------------------------------
__global__ void k_scan2(uint32_t* __restrict__ data0, int n0,
                        uint32_t* __restrict__ data1, int n1) {
  __shared__ uint32_t wsum[4];
  uint32_t* data = (blockIdx.x == 0) ? data0 : data1;
  int n = (blockIdx.x == 0) ? n0 : n1;
  int tid = threadIdx.x, lane = tid & 63, wid = tid >> 6;
  uint32_t running = 0;
  for (int base = 0; base < n; base += 256) {
    int i = base + tid;
    uint32_t v = (i < n) ? data[i] : 0u;
    uint32_t incl = v;
    for (int d = 1; d < 64; d <<= 1) {
      uint32_t t = __shfl_up(incl, (unsigned)d, 64);
      if (lane >= d) incl += t;
    }
    if (lane == 63) wsum[wid] = incl;
    __syncthreads();
    uint32_t woff = 0, tot = 0;
    for (int w = 0; w < 4; w++) { uint32_t s = wsum[w]; if (w < wid) woff += s; tot += s; }
    if (i < n) data[i] = running + woff + (incl - v);
    running += tot;
    __syncthreads();
  }
  if (tid == 0) data[n] = running;
}

// ---------------------------------------------------------------------------
// K2a: dense dump -> 56 coarse regions (runs ~73 entries, coalesced).
// ---------------------------------------------------------------------------
__global__ __launch_bounds__(256) void k_regA(const uint2* __restrict__ dump,
                                              const uint32_t* __restrict__ dumpCursor,
                                              uint32_t* __restrict__ coarseCursor,
                                              uint2* __restrict__ coarse) {
  __shared__ uint2 pool2[WIN];          // 32 KB
  __shared__ uint32_t lh[4][64];        // per-wave hists
  __shared__ uint32_t hbase[64], lgb[64], lcur[64];
  int tid = threadIdx.x, lane = tid & 63, wid = tid >> 6;
  uint32_t total = dumpCursor[0]; if (total > CAPDUMP) total = CAPDUMP;
  uint32_t wbase = blockIdx.x * (uint32_t)WIN;
  if (wbase >= total) return;
  uint32_t valid = total - wbase; if (valid > WIN) valid = WIN;
  lh[wid][lane] = 0;
  __syncthreads();
  uint2 e[WIN / 256];
#pragma unroll
  for (int q = 0; q < WIN / 256; q++) {
    uint32_t j = (uint32_t)q * 256u + (uint32_t)tid;
    e[q] = (j < valid) ? dump[wbase + j] : make_uint2(0u, 0u);
    if (j < valid) atomicAdd(&lh[wid][e[q].x >> 26], 1u);
  }
  __syncthreads();
  if (tid < 64) {
    uint32_t h = lh[0][tid] + lh[1][tid] + lh[2][tid] + lh[3][tid];
    lgb[tid] = (h && tid < NCOARSE) ? atomicAdd((unsigned int*)&coarseCursor[tid], h) : 0u;
    lcur[tid] = h;
  }
  __syncthreads();
  if (wid == 0) {
    uint32_t v = lcur[lane];
    uint32_t incl = v;
    for (int d = 1; d < 64; d <<= 1) {
      uint32_t t = __shfl_up(incl, (unsigned)d, 64);
      if (lane >= d) incl += t;
    }
    hbase[lane] = incl - v;
    lcur[lane] = incl - v;
  }
  __syncthreads();
#pragma unroll
  for (int q = 0; q < WIN / 256; q++) {
    uint32_t j = (uint32_t)q * 256u + (uint32_t)tid;
    if (j < valid) {
      uint32_t c = e[q].x >> 26;
      uint32_t lpos = atomicAdd(&lcur[c], 1u);
      pool2[lpos] = e[q];
    }
  }
  __syncthreads();
  for (uint32_t j = tid; j < valid; j += 256) {
    uint2 p = pool2[j];
    uint32_t c = p.x >> 26;
    uint32_t dst = lgb[c] + (j - hbase[c]);
    if (dst < CSTRIDE) coarse[(size_t)c * CSTRIDE + dst] = p;
  }
}

// ---------------------------------------------------------------------------
// K2b: coarse region -> 32 fine regions per coarse (runs ~128, coalesced).
// Grid = NCOARSE * WPC.
// ---------------------------------------------------------------------------
__global__ __launch_bounds__(256) void k_regB(const uint2* __restrict__ coarse,
                                              const uint32_t* __restrict__ coarseCursor,
                                              uint32_t* __restrict__ fineCursor,
                                              uint2* __restrict__ fine) {
  __shared__ uint2 pool2[WIN];          // 32 KB
  __shared__ uint32_t lh[4][32];
  __shared__ uint32_t hbase[32], lgb[32], lcur[32];
  int tid = threadIdx.x, lane = tid & 63, wid = tid >> 6;
  uint32_t c = blockIdx.x / WPC, w = blockIdx.x % WPC;
  uint32_t ccnt = coarseCursor[c]; if (ccnt > CSTRIDE) ccnt = CSTRIDE;
  uint32_t wbase = w * (uint32_t)WIN;
  if (wbase >= ccnt) return;
  uint32_t valid = ccnt - wbase; if (valid > WIN) valid = WIN;
  const uint2* src = coarse + (size_t)c * CSTRIDE + wbase;
  if (tid < 128) lh[tid >> 5][tid & 31] = 0;
  __syncthreads();
  uint2 e[WIN / 256];
#pragma unroll
  for (int q = 0; q < WIN / 256; q++) {
    uint32_t j = (uint32_t)q * 256u + (uint32_t)tid;
    e[q] = (j < valid) ? src[j] : make_uint2(0u, 0u);
    if (j < valid) atomicAdd(&lh[wid][(e[q].x >> 21) & 31u], 1u);
  }
  __syncthreads();
  if (tid < 32) {
    uint32_t h = lh[0][tid] + lh[1][tid] + lh[2][tid] + lh[3][tid];
    lgb[tid] = h ? atomicAdd((unsigned int*)&fineCursor[c * 32u + tid], h) : 0u;
    lcur[tid] = h;
  }
  __syncthreads();
  if (wid == 0) {
    uint32_t v = (lane < 32) ? lcur[lane] : 0u;
    uint32_t incl = v;
    for (int d = 1; d < 32; d <<= 1) {
      uint32_t t = __shfl_up(incl, (unsigned)d, 64);
      if (lane >= d) incl += t;
    }
    if (lane < 32) { hbase[lane] = incl - v; lcur[lane] = incl - v; }
  }
  __syncthreads();
#pragma unroll
  for (int q = 0; q < WIN / 256; q++) {
    uint32_t j = (uint32_t)q * 256u + (uint32_t)tid;
    if (j < valid) {
      uint32_t f = (e[q].x >> 21) & 31u;
      uint32_t lpos = atomicAdd(&lcur[f], 1u);
      pool2[lpos] = e[q];
    }
  }
  __syncthreads();
  for (uint32_t j = tid; j < valid; j += 256) {
    uint2 p = pool2[j];
    uint32_t f = (p.x >> 21) & 31u;
    uint32_t dst = lgb[f] + (j - hbase[f]);
    if (dst < STRIDE) fine[(size_t)(c * 32u + f) * STRIDE + dst] = p;
  }
}

// ---------------------------------------------------------------------------
// K3: one block per fine bin, LDS-resident sort (proven R6-R12).
// ---------------------------------------------------------------------------
__global__ __launch_bounds__(256) void k_binsort(const uint2* __restrict__ pairs,
                                                 const uint32_t* __restrict__ binPrefix,
                                                 float* __restrict__ donors) {
  __shared__ uint2    lbuf[BSCAP];      // 19.5 KB
  __shared__ uint32_t hist[512];        // 2 KB
  __shared__ uint32_t wsums[4];
  int tid = threadIdx.x, lane = tid & 63, wid = tid >> 6;
  uint32_t bin = blockIdx.x;
  uint32_t gbase = binPrefix[bin];
  uint32_t cnt = binPrefix[bin + 1] - gbase;
  if (cnt > STRIDE) cnt = STRIDE;
  if (cnt > BSCAP) cnt = BSCAP;
  const uint2* src = pairs + (size_t)bin * STRIDE;

  for (int c = tid; c < 512; c += 256) hist[c] = 0;
  __syncthreads();
  for (uint32_t j = tid; j < cnt; j += 256)
    atomicAdd(&hist[(src[j].x >> 12) & 511u], 1u);
  __syncthreads();
  uint32_t h0 = hist[2 * tid], h1 = hist[2 * tid + 1];
  uint32_t tsum = h0 + h1;
  uint32_t incl = tsum;
  for (int d = 1; d < 64; d <<= 1) {
    uint32_t t = __shfl_up(incl, (unsigned)d, 64);
    if (lane >= d) incl += t;
  }
  if (lane == 63) wsums[wid] = incl;
  __syncthreads();
  if (wid == 0) {
    uint32_t v = (lane < 4) ? wsums[lane] : 0u;
    uint32_t in2 = v;
    for (int d = 1; d < 4; d <<= 1) {
      uint32_t t = __shfl_up(in2, (unsigned)d, 64);
      if (lane >= d) in2 += t;
    }
    if (lane < 4) wsums[lane] = in2 - v;
  }
  __syncthreads();
  uint32_t texcl = wsums[wid] + (incl - tsum);
  uint32_t e0 = texcl, e1 = e0 + h0;
  __syncthreads();
  hist[2 * tid] = e0; hist[2 * tid + 1] = e1;
  __syncthreads();
  for (uint32_t j = tid; j < cnt; j += 256) {
    uint2 p = src[j];
    uint32_t c = (p.x >> 12) & 511u;
    uint32_t lpos = atomicAdd(&hist[c], 1u);
    lbuf[lpos] = p;
  }
  __syncthreads();
  for (int c = tid; c < 512; c += 256) {
    uint32_t lo = (c == 0) ? 0u : hist[c - 1];
    uint32_t hi = hist[c];
    for (uint32_t u = lo + 1; u < hi; u++) {
      uint2 v = lbuf[u];
      uint32_t w = u;
      while (w > lo && (lbuf[w - 1].y & MASKI) > (v.y & MASKI)) {
        lbuf[w] = lbuf[w - 1];
        w--;
      }
      lbuf[w] = v;
    }
  }
  __syncthreads();
  for (uint32_t j = tid; j < cnt; j += 256) {
    uint2 p = lbuf[j];
    uint32_t v = ((p.x & 0xFFFu) << 5) | (p.y >> 27);
    donors[gbase + j] = (float)v;
  }
}

// ---------------------------------------------------------------------------
// K4: out[i] = repl ? donors[rank] : x[i] (proven R10-R12).
// ---------------------------------------------------------------------------
template<bool BOUNDS>
__global__ __launch_bounds__(256) void k_final(const float* __restrict__ x,
                                               const uint64_t* __restrict__ mask,
                                               const uint32_t* __restrict__ rsums,
                                               const float* __restrict__ donors,
                                               float* __restrict__ out, int n) {
  __shared__ uint64_t lw[ELEMS_G / 64];
  __shared__ uint32_t ctot[32], cpre[32];
  int tid = threadIdx.x, lane = tid & 63, wid = tid >> 6;
  int base = blockIdx.x * ELEMS_G;
  int wordBase = blockIdx.x * (ELEMS_G / 64);
  if (tid < ELEMS_G / 64) {
    uint64_t w = 0ull;
    int wI = wordBase + tid;
    if (!BOUNDS || (((wI >> 2) * 256) + ((wI & 3) * 64) < n)) w = mask[wI];
    lw[tid] = w;
  }
  __syncthreads();
  if (tid < 32) {
    ctot[tid] = (uint32_t)(__popcll(lw[4 * tid]) + __popcll(lw[4 * tid + 1]) +
                           __popcll(lw[4 * tid + 2]) + __popcll(lw[4 * tid + 3]));
  }
  __syncthreads();
  if (tid == 0) {
    uint32_t run = 0;
    for (int c = 0; c < 32; c++) { cpre[c] = run; run += ctot[c]; }
  }
  __syncthreads();
  uint32_t rbase = rsums[blockIdx.x];
  uint64_t lt = (1ull << lane) - 1ull;
  for (int it = 0; it < ELEMS_G / 1024; it++) {
    int c = it * 4 + wid;
    uint64_t b0 = lw[c * 4 + 0], b1 = lw[c * 4 + 1],
             b2 = lw[c * 4 + 2], b3 = lw[c * 4 + 3];
    uint32_t running = rbase + cpre[c];
    int e0 = base + it * 1024 + wid * 256 + lane * 4;
    uint32_t below = (uint32_t)(__popcll(b0 & lt) + __popcll(b1 & lt) +
                                __popcll(b2 & lt) + __popcll(b3 & lt));
    uint32_t r0 = (uint32_t)((b0 >> lane) & 1ull), r1 = (uint32_t)((b1 >> lane) & 1ull);
    uint32_t r2 = (uint32_t)((b2 >> lane) & 1ull), r3 = (uint32_t)((b3 >> lane) & 1ull);
    uint32_t rk = running + below;
    float4 xv;
    if (!BOUNDS || e0 + 3 < n) {
      xv = *reinterpret_cast<const float4*>(x + e0);
    } else {
      xv.x = (e0 + 0 < n) ? x[e0 + 0] : 0.0f;
      xv.y = (e0 + 1 < n) ? x[e0 + 1] : 0.0f;
      xv.z = (e0 + 2 < n) ? x[e0 + 2] : 0.0f;
      xv.w = (e0 + 3 < n) ? x[e0 + 3] : 0.0f;
    }
    float4 ov;
    ov.x = r0 ? donors[rk] : xv.x;               rk += r0;
    ov.y = r1 ? donors[rk] : xv.y;               rk += r1;
    ov.z = r2 ? donors[rk] : xv.z;               rk += r2;
    ov.w = r3 ? donors[rk] : xv.w;
    if (!BOUNDS || e0 + 3 < n) {
      *reinterpret_cast<float4*>(out + e0) = ov;
    } else {
      if (e0 + 0 < n) out[e0 + 0] = ov.x;
      if (e0 + 1 < n) out[e0 + 1] = ov.y;
      if (e0 + 2 < n) out[e0 + 2] = ov.z;
      if (e0 + 3 < n) out[e0 + 3] = ov.w;
    }
  }
}

// ---------------------------------------------------------------------------
extern "C" void kernel_launch(void* const* d_in, const int* in_sizes, int n_in,
                              void* d_out, int out_size, void* d_ws, size_t ws_size,
                              hipStream_t stream) {
  const float* x = (const float*)d_in[0];
  float* out = (float*)d_out;
  int n = in_sizes[0];
  (void)n_in; (void)out_size; (void)ws_size;

  uint32_t bk0, bk1, sk0, sk1;
  tf2x32(0u, 42u, 0u, 0u, bk0, bk1);
  tf2x32(0u, 42u, 0u, 1u, sk0, sk1);

  int nBlkG = (n + ELEMS_G - 1) / ELEMS_G;     // 4096
  bool exact = ((n % ELEMS_G) == 0);

  size_t off = 0;
  auto alloc = [&](size_t bytes) -> void* {
    void* p = (uint8_t*)d_ws + off;
    off += (bytes + 255) & ~(size_t)255;
    return p;
  };
  uint32_t* dumpCursor   = (uint32_t*)alloc(4);
  uint32_t* coarseCursor = (uint32_t*)alloc((size_t)64 * 4);
  uint32_t* fineCursor   = (uint32_t*)alloc((size_t)(NFINE + 1) * 4);
  size_t zeroBytes = off;                      // all cursors zeroed
  uint32_t* rsums = (uint32_t*)alloc((size_t)(nBlkG + 1) * 4);
  uint64_t* mask  = (uint64_t*)alloc((size_t)((n + 63) / 64 + 4) * 8);     // 4 MB
  // bufA: dump (31.5 MB) then reused as fine (34.9 MB)
  uint2* bufA = (uint2*)alloc((size_t)NFINE * STRIDE * 8);                 // 34.9 MB
  // bufB: coarse (31.2 MB) then reused as donors (<=15.7 MB)
  uint2* bufB = (uint2*)alloc((size_t)NCOARSE * CSTRIDE * 8);              // 31.2 MB
  uint2* dump = bufA;
  uint2* coarse = bufB;
  uint2* fine = bufA;
  float* donors = (float*)bufB;

  hipMemsetAsync(d_ws, 0, zeroBytes, stream);

  if (exact) {
    k_bern<false><<<nBlkG, 256, 0, stream>>>(x, mask, rsums, bk0, bk1, n);
    k_cand<false><<<nBlkG, 256, 0, stream>>>(x, dumpCursor, dump, sk0, sk1, n);
  } else {
    k_bern<true><<<nBlkG, 256, 0, stream>>>(x, mask, rsums, bk0, bk1, n);
    k_cand<true><<<nBlkG, 256, 0, stream>>>(x, dumpCursor, dump, sk0, sk1, n);
  }
  int nWinA = (int)(CAPDUMP / WIN);            // 960
  k_regA<<<nWinA, 256, 0, stream>>>(dump, dumpCursor, coarseCursor, coarse);
  k_regB<<<(int)(NCOARSE * WPC), 256, 0, stream>>>(coarse, coarseCursor, fineCursor, fine);
  k_scan2<<<2, 256, 0, stream>>>(rsums, nBlkG, fineCursor, (int)NFINE);
  k_binsort<<<(int)NFINE, 256, 0, stream>>>(fine, fineCursor, donors);
  if (exact)
    k_final<false><<<nBlkG, 256, 0, stream>>>(x, mask, rsums, donors, out, n);
  else
    k_final<true><<<nBlkG, 256, 0, stream>>>(x, mask, rsums, donors, out, n);
}

// Round 16
// 303.073 us; speedup vs baseline: 16.4019x; 1.0889x over previous
//
#include <hip/hip_runtime.h>
#include <stdint.h>

// ---------------------------------------------------------------------------
// JAX threefry2x32 (20 rounds), bit-exact port of jax/_src/prng.py
// ---------------------------------------------------------------------------
static __host__ __device__ inline uint32_t rotl32(uint32_t x, int r) {
#if defined(__HIP_DEVICE_COMPILE__)
  return __builtin_amdgcn_alignbit(x, x, (uint32_t)(32 - r));
#else
  return (x << r) | (x >> (32 - r));
#endif
}

static __host__ __device__ inline void tf2x32(uint32_t k0, uint32_t k1,
                                              uint32_t x0, uint32_t x1,
                                              uint32_t& o0, uint32_t& o1) {
  uint32_t k2 = k0 ^ k1 ^ 0x1BD11BDAu;
#define TFR(a) { x0 += x1; x1 = rotl32(x1, a); x1 ^= x0; }
  x0 += k0; x1 += k1;
  TFR(13) TFR(15) TFR(26) TFR(6)
  x0 += k1; x1 += k2 + 1u;
  TFR(17) TFR(29) TFR(16) TFR(24)
  x0 += k2; x1 += k0 + 2u;
  TFR(13) TFR(15) TFR(26) TFR(6)
  x0 += k0; x1 += k1 + 3u;
  TFR(17) TFR(29) TFR(16) TFR(24)
  x0 += k1; x1 += k2 + 4u;
  TFR(13) TFR(15) TFR(26) TFR(6)
  x0 += k2; x1 += k0 + 5u;
#undef TFR
  o0 = x0; o1 = x1;
}

static __device__ inline uint32_t fold_bits(uint32_t k0, uint32_t k1, uint32_t ctr) {
  uint32_t a, b;
  tf2x32(k0, k1, 0u, ctr, a, b);
  return a ^ b;
}

// Candidates: m = bits>>9 < CUT2 (=7*2^17, 10.94%). E[C]=3.670M >= R~3.355M.
// coarse bin = m>>14 in [0,56); fine bin = m>>9 in [0,1792); bucket = m&511.
#define CUT2      917504u        // 7 << 17
#define NCOARSE   56u
#define CSTRIDE   69632u         // per-coarse region (mean 65536, +16 sigma)
#define WPC       17u            // windows per coarse region (69632/4096)
#define NFINE     1792u
#define STRIDE    2432u          // fine region stride (mean 2048, +8.5 sigma)
#define BSCAP     2432u
#define ELEMS_G   8192           // gen/final block span
#define GPOOL     1216u          // k_gen LDS pool (mean 896, +11 sigma)
#define WIN       4096           // regroup window (entries)
#define MASKI     0x07FFFFFFu
#define BERN_THR  838861u        // u < 0.1f <=> mant < 838861 (exact)

// pair packing: .x = (m<<12) | (value>>5)    [m:20 | v_hi:12]
//               .y = ((value&31)<<27) | idx  [v_lo:5 | 00 | idx:25]
// coarse = .x>>26; fine-in-coarse = (.x>>21)&31; bucket = (.x>>12)&511

// MASK FORMAT: chunk = 256 elems per wave-iter; lane L holds elems
// chunkBase+4L+e; mask[chunk*4+e] = ballot(repl_e). chunk = blk*32+it*4+wid.

// ---------------------------------------------------------------------------
// K1 (fused): both threefry folds per element + ballot mask + rsums +
// wave-aggregated LDS pool; epilogue groups pool by 56 coarse bins in LDS
// and writes ~16-entry runs directly to coarse regions (replaces dump+regA).
// ---------------------------------------------------------------------------
template<bool BOUNDS>
__global__ __launch_bounds__(256) void k_gen(const float* __restrict__ x,
                                             uint64_t* __restrict__ mask,
                                             uint32_t* __restrict__ rsums,
                                             uint32_t* __restrict__ coarseCursor,
                                             uint2* __restrict__ coarse,
                                             uint32_t bk0, uint32_t bk1,
                                             uint32_t sk0, uint32_t sk1, int n) {
  __shared__ uint2 pool[GPOOL];          // 9.7 KB
  __shared__ uint2 pool2[GPOOL];         // 9.7 KB
  __shared__ uint32_t lh[64], hbase[64], lgb[64], lcur[64];
  __shared__ uint32_t wcnt[4];
  __shared__ uint32_t lpoolCnt;
  int tid = threadIdx.x, lane = tid & 63, wid = tid >> 6;
  int base = blockIdx.x * ELEMS_G;
  if (tid == 0) lpoolCnt = 0;
  __syncthreads();

  uint32_t cnt = 0;
  uint64_t lt = (1ull << lane) - 1ull;
  unsigned long long bball[4];
  for (int it = 0; it < ELEMS_G / 1024; it++) {
    int e0 = base + it * 1024 + wid * 256 + lane * 4;
    float4 xv;
    if (!BOUNDS || e0 + 3 < n) {
      xv = *reinterpret_cast<const float4*>(x + e0);
    } else {
      xv.x = (e0 + 0 < n) ? x[e0 + 0] : 0.0f;
      xv.y = (e0 + 1 < n) ? x[e0 + 1] : 0.0f;
      xv.z = (e0 + 2 < n) ? x[e0 + 2] : 0.0f;
      xv.w = (e0 + 3 < n) ? x[e0 + 3] : 0.0f;
    }
#define GENE(e, comp)                                                     \
    {                                                                     \
      uint32_t ii = (uint32_t)(e0 + e);                                   \
      bool np = (comp != 0.0f);                                           \
      uint32_t bb = fold_bits(bk0, bk1, ii);                              \
      bool rr = np && ((bb >> 9) < BERN_THR);                             \
      bball[e] = __ballot(rr);                                            \
      uint32_t mm = fold_bits(sk0, sk1, ii) >> 9;                         \
      bool cand = np && (mm < CUT2);                                      \
      unsigned long long cb = __ballot(cand);                             \
      uint32_t pb = 0;                                                    \
      if (lane == 0 && cb) pb = atomicAdd(&lpoolCnt, (uint32_t)__popcll(cb)); \
      pb = __builtin_amdgcn_readfirstlane(pb);                            \
      if (cand) {                                                         \
        uint32_t slot = pb + (uint32_t)__popcll(cb & lt);                 \
        if (slot < GPOOL) {                                               \
          uint32_t v = (uint32_t)comp;                                    \
          pool[slot] = make_uint2((mm << 12) | (v >> 5),                  \
                                  ((v & 31u) << 27) | ii);                \
        }                                                                 \
      }                                                                   \
    }
    GENE(0, xv.x) GENE(1, xv.y) GENE(2, xv.z) GENE(3, xv.w)
#undef GENE
    cnt += (uint32_t)(__popcll(bball[0]) + __popcll(bball[1]) +
                      __popcll(bball[2]) + __popcll(bball[3]));
    if (lane == 0) {
      uint32_t ci = (uint32_t)blockIdx.x * 32u + (uint32_t)it * 4u + (uint32_t)wid;
      if (!BOUNDS) {
        mask[ci * 4 + 0] = bball[0]; mask[ci * 4 + 1] = bball[1];
        mask[ci * 4 + 2] = bball[2]; mask[ci * 4 + 3] = bball[3];
      } else {
        for (int e = 0; e < 4; e++)
          if ((int)(ci * 256u + (uint32_t)e * 64u) < n) mask[ci * 4 + e] = bball[e];
      }
    }
  }
  if (lane == 0) wcnt[wid] = cnt;
  if (tid < 64) lh[tid] = 0;
  __syncthreads();
  if (tid == 0) rsums[blockIdx.x] = wcnt[0] + wcnt[1] + wcnt[2] + wcnt[3];
  // ---- epilogue: group pool by coarse bin (LDS) -> run-grouped writes ----
  uint32_t pc = lpoolCnt; if (pc > GPOOL) pc = GPOOL;
  for (uint32_t j = tid; j < pc; j += 256) atomicAdd(&lh[pool[j].x >> 26], 1u);
  __syncthreads();
  if (tid < 64) {
    uint32_t h = lh[tid];
    lgb[tid] = (h && tid < NCOARSE) ? atomicAdd((unsigned int*)&coarseCursor[tid], h) : 0u;
  }
  __syncthreads();
  if (wid == 0) {
    uint32_t v = lh[lane];
    uint32_t incl = v;
    for (int d = 1; d < 64; d <<= 1) {
      uint32_t t = __shfl_up(incl, (unsigned)d, 64);
      if (lane >= d) incl += t;
    }
    hbase[lane] = incl - v;
    lcur[lane] = incl - v;
  }
  __syncthreads();
  for (uint32_t j = tid; j < pc; j += 256) {
    uint2 p = pool[j];
    uint32_t c = p.x >> 26;
    uint32_t lpos = atomicAdd(&lcur[c], 1u);
    pool2[lpos] = p;
  }
  __syncthreads();
  for (uint32_t j = tid; j < pc; j += 256) {
    uint2 p = pool2[j];
    uint32_t c = p.x >> 26;
    uint32_t dst = lgb[c] + (j - hbase[c]);
    if (dst < CSTRIDE) coarse[(size_t)c * CSTRIDE + dst] = p;
  }
}

// ---------------------------------------------------------------------------
// 2-target exclusive scan (in place; writes data[n] = total, alloc n+1)
// ---------------------------------------------------------------------------
__global__ void k_scan2(uint32_t* __restrict__ data0, int n0,
                        uint32_t* __restrict__ data1, int n1) {
  __shared__ uint32_t wsum[4];
  uint32_t* data = (blockIdx.x == 0) ? data0 : data1;
  int n = (blockIdx.x == 0) ? n0 : n1;
  int tid = threadIdx.x, lane = tid & 63, wid = tid >> 6;
  uint32_t running = 0;
  for (int base = 0; base < n; base += 256) {
    int i = base + tid;
    uint32_t v = (i < n) ? data[i] : 0u;
    uint32_t incl = v;
    for (int d = 1; d < 64; d <<= 1) {
      uint32_t t = __shfl_up(incl, (unsigned)d, 64);
      if (lane >= d) incl += t;
    }
    if (lane == 63) wsum[wid] = incl;
    __syncthreads();
    uint32_t woff = 0, tot = 0;
    for (int w = 0; w < 4; w++) { uint32_t s = wsum[w]; if (w < wid) woff += s; tot += s; }
    if (i < n) data[i] = running + woff + (incl - v);
    running += tot;
    __syncthreads();
  }
  if (tid == 0) data[n] = running;
}

// ---------------------------------------------------------------------------
// K2b: coarse region -> 32 fine regions per coarse (runs ~128, coalesced).
// Grid = NCOARSE * WPC.
// ---------------------------------------------------------------------------
__global__ __launch_bounds__(256) void k_regB(const uint2* __restrict__ coarse,
                                              const uint32_t* __restrict__ coarseCursor,
                                              uint32_t* __restrict__ fineCursor,
                                              uint2* __restrict__ fine) {
  __shared__ uint2 pool2[WIN];          // 32 KB
  __shared__ uint32_t lh[4][32];
  __shared__ uint32_t hbase[32], lgb[32], lcur[32];
  int tid = threadIdx.x, lane = tid & 63, wid = tid >> 6;
  uint32_t c = blockIdx.x / WPC, w = blockIdx.x % WPC;
  uint32_t ccnt = coarseCursor[c]; if (ccnt > CSTRIDE) ccnt = CSTRIDE;
  uint32_t wbase = w * (uint32_t)WIN;
  if (wbase >= ccnt) return;
  uint32_t valid = ccnt - wbase; if (valid > WIN) valid = WIN;
  const uint2* src = coarse + (size_t)c * CSTRIDE + wbase;
  if (tid < 128) lh[tid >> 5][tid & 31] = 0;
  __syncthreads();
  uint2 e[WIN / 256];
#pragma unroll
  for (int q = 0; q < WIN / 256; q++) {
    uint32_t j = (uint32_t)q * 256u + (uint32_t)tid;
    e[q] = (j < valid) ? src[j] : make_uint2(0u, 0u);
    if (j < valid) atomicAdd(&lh[wid][(e[q].x >> 21) & 31u], 1u);
  }
  __syncthreads();
  if (tid < 32) {
    uint32_t h = lh[0][tid] + lh[1][tid] + lh[2][tid] + lh[3][tid];
    lgb[tid] = h ? atomicAdd((unsigned int*)&fineCursor[c * 32u + tid], h) : 0u;
    lcur[tid] = h;
  }
  __syncthreads();
  if (wid == 0) {
    uint32_t v = (lane < 32) ? lcur[lane] : 0u;
    uint32_t incl = v;
    for (int d = 1; d < 32; d <<= 1) {
      uint32_t t = __shfl_up(incl, (unsigned)d, 64);
      if (lane >= d) incl += t;
    }
    if (lane < 32) { hbase[lane] = incl - v; lcur[lane] = incl - v; }
  }
  __syncthreads();
#pragma unroll
  for (int q = 0; q < WIN / 256; q++) {
    uint32_t j = (uint32_t)q * 256u + (uint32_t)tid;
    if (j < valid) {
      uint32_t f = (e[q].x >> 21) & 31u;
      uint32_t lpos = atomicAdd(&lcur[f], 1u);
      pool2[lpos] = e[q];
    }
  }
  __syncthreads();
  for (uint32_t j = tid; j < valid; j += 256) {
    uint2 p = pool2[j];
    uint32_t f = (p.x >> 21) & 31u;
    uint32_t dst = lgb[f] + (j - hbase[f]);
    if (dst < STRIDE) fine[(size_t)(c * 32u + f) * STRIDE + dst] = p;
  }
}

// ---------------------------------------------------------------------------
// K3: one block per fine bin, LDS-resident sort (proven R6-R13).
// ---------------------------------------------------------------------------
__global__ __launch_bounds__(256) void k_binsort(const uint2* __restrict__ pairs,
                                                 const uint32_t* __restrict__ binPrefix,
                                                 float* __restrict__ donors) {
  __shared__ uint2    lbuf[BSCAP];      // 19.5 KB
  __shared__ uint32_t hist[512];        // 2 KB
  __shared__ uint32_t wsums[4];
  int tid = threadIdx.x, lane = tid & 63, wid = tid >> 6;
  uint32_t bin = blockIdx.x;
  uint32_t gbase = binPrefix[bin];
  uint32_t cnt = binPrefix[bin + 1] - gbase;
  if (cnt > STRIDE) cnt = STRIDE;
  if (cnt > BSCAP) cnt = BSCAP;
  const uint2* src = pairs + (size_t)bin * STRIDE;

  for (int c = tid; c < 512; c += 256) hist[c] = 0;
  __syncthreads();
  for (uint32_t j = tid; j < cnt; j += 256)
    atomicAdd(&hist[(src[j].x >> 12) & 511u], 1u);
  __syncthreads();
  uint32_t h0 = hist[2 * tid], h1 = hist[2 * tid + 1];
  uint32_t tsum = h0 + h1;
  uint32_t incl = tsum;
  for (int d = 1; d < 64; d <<= 1) {
    uint32_t t = __shfl_up(incl, (unsigned)d, 64);
    if (lane >= d) incl += t;
  }
  if (lane == 63) wsums[wid] = incl;
  __syncthreads();
  if (wid == 0) {
    uint32_t v = (lane < 4) ? wsums[lane] : 0u;
    uint32_t in2 = v;
    for (int d = 1; d < 4; d <<= 1) {
      uint32_t t = __shfl_up(in2, (unsigned)d, 64);
      if (lane >= d) in2 += t;
    }
    if (lane < 4) wsums[lane] = in2 - v;
  }
  __syncthreads();
  uint32_t texcl = wsums[wid] + (incl - tsum);
  uint32_t e0 = texcl, e1 = e0 + h0;
  __syncthreads();
  hist[2 * tid] = e0; hist[2 * tid + 1] = e1;
  __syncthreads();
  for (uint32_t j = tid; j < cnt; j += 256) {
    uint2 p = src[j];
    uint32_t c = (p.x >> 12) & 511u;
    uint32_t lpos = atomicAdd(&hist[c], 1u);
    lbuf[lpos] = p;
  }
  __syncthreads();
  for (int c = tid; c < 512; c += 256) {
    uint32_t lo = (c == 0) ? 0u : hist[c - 1];
    uint32_t hi = hist[c];
    for (uint32_t u = lo + 1; u < hi; u++) {
      uint2 v = lbuf[u];
      uint32_t w = u;
      while (w > lo && (lbuf[w - 1].y & MASKI) > (v.y & MASKI)) {
        lbuf[w] = lbuf[w - 1];
        w--;
      }
      lbuf[w] = v;
    }
  }
  __syncthreads();
  for (uint32_t j = tid; j < cnt; j += 256) {
    uint2 p = lbuf[j];
    uint32_t v = ((p.x & 0xFFFu) << 5) | (p.y >> 27);
    donors[gbase + j] = (float)v;
  }
}

// ---------------------------------------------------------------------------
// K4: out[i] = repl ? donors[rank] : x[i] (proven R10-R13).
// ---------------------------------------------------------------------------
template<bool BOUNDS>
__global__ __launch_bounds__(256) void k_final(const float* __restrict__ x,
                                               const uint64_t* __restrict__ mask,
                                               const uint32_t* __restrict__ rsums,
                                               const float* __restrict__ donors,
                                               float* __restrict__ out, int n) {
  __shared__ uint64_t lw[ELEMS_G / 64];
  __shared__ uint32_t ctot[32], cpre[32];
  int tid = threadIdx.x, lane = tid & 63, wid = tid >> 6;
  int base = blockIdx.x * ELEMS_G;
  int wordBase = blockIdx.x * (ELEMS_G / 64);
  if (tid < ELEMS_G / 64) {
    uint64_t w = 0ull;
    int wI = wordBase + tid;
    if (!BOUNDS || (((wI >> 2) * 256) + ((wI & 3) * 64) < n)) w = mask[wI];
    lw[tid] = w;
  }
  __syncthreads();
  if (tid < 32) {
    ctot[tid] = (uint32_t)(__popcll(lw[4 * tid]) + __popcll(lw[4 * tid + 1]) +
                           __popcll(lw[4 * tid + 2]) + __popcll(lw[4 * tid + 3]));
  }
  __syncthreads();
  if (tid == 0) {
    uint32_t run = 0;
    for (int c = 0; c < 32; c++) { cpre[c] = run; run += ctot[c]; }
  }
  __syncthreads();
  uint32_t rbase = rsums[blockIdx.x];
  uint64_t lt = (1ull << lane) - 1ull;
  for (int it = 0; it < ELEMS_G / 1024; it++) {
    int c = it * 4 + wid;
    uint64_t b0 = lw[c * 4 + 0], b1 = lw[c * 4 + 1],
             b2 = lw[c * 4 + 2], b3 = lw[c * 4 + 3];
    uint32_t running = rbase + cpre[c];
    int e0 = base + it * 1024 + wid * 256 + lane * 4;
    uint32_t below = (uint32_t)(__popcll(b0 & lt) + __popcll(b1 & lt) +
                                __popcll(b2 & lt) + __popcll(b3 & lt));
    uint32_t r0 = (uint32_t)((b0 >> lane) & 1ull), r1 = (uint32_t)((b1 >> lane) & 1ull);
    uint32_t r2 = (uint32_t)((b2 >> lane) & 1ull), r3 = (uint32_t)((b3 >> lane) & 1ull);
    uint32_t rk = running + below;
    float4 xv;
    if (!BOUNDS || e0 + 3 < n) {
      xv = *reinterpret_cast<const float4*>(x + e0);
    } else {
      xv.x = (e0 + 0 < n) ? x[e0 + 0] : 0.0f;
      xv.y = (e0 + 1 < n) ? x[e0 + 1] : 0.0f;
      xv.z = (e0 + 2 < n) ? x[e0 + 2] : 0.0f;
      xv.w = (e0 + 3 < n) ? x[e0 + 3] : 0.0f;
    }
    float4 ov;
    ov.x = r0 ? donors[rk] : xv.x;               rk += r0;
    ov.y = r1 ? donors[rk] : xv.y;               rk += r1;
    ov.z = r2 ? donors[rk] : xv.z;               rk += r2;
    ov.w = r3 ? donors[rk] : xv.w;
    if (!BOUNDS || e0 + 3 < n) {
      *reinterpret_cast<float4*>(out + e0) = ov;
    } else {
      if (e0 + 0 < n) out[e0 + 0] = ov.x;
      if (e0 + 1 < n) out[e0 + 1] = ov.y;
      if (e0 + 2 < n) out[e0 + 2] = ov.z;
      if (e0 + 3 < n) out[e0 + 3] = ov.w;
    }
  }
}

// ---------------------------------------------------------------------------
extern "C" void kernel_launch(void* const* d_in, const int* in_sizes, int n_in,
                              void* d_out, int out_size, void* d_ws, size_t ws_size,
                              hipStream_t stream) {
  const float* x = (const float*)d_in[0];
  float* out = (float*)d_out;
  int n = in_sizes[0];
  (void)n_in; (void)out_size; (void)ws_size;

  uint32_t bk0, bk1, sk0, sk1;
  tf2x32(0u, 42u, 0u, 0u, bk0, bk1);
  tf2x32(0u, 42u, 0u, 1u, sk0, sk1);

  int nBlkG = (n + ELEMS_G - 1) / ELEMS_G;     // 4096
  bool exact = ((n % ELEMS_G) == 0);

  size_t off = 0;
  auto alloc = [&](size_t bytes) -> void* {
    void* p = (uint8_t*)d_ws + off;
    off += (bytes + 255) & ~(size_t)255;
    return p;
  };
  uint32_t* coarseCursor = (uint32_t*)alloc((size_t)64 * 4);
  uint32_t* fineCursor   = (uint32_t*)alloc((size_t)(NFINE + 1) * 4);
  size_t zeroBytes = off;                      // all cursors zeroed
  uint32_t* rsums = (uint32_t*)alloc((size_t)(nBlkG + 1) * 4);
  uint64_t* mask  = (uint64_t*)alloc((size_t)((n + 63) / 64 + 4) * 8);     // 4 MB
  uint2* fine   = (uint2*)alloc((size_t)NFINE * STRIDE * 8);               // 34.9 MB
  uint2* coarse = (uint2*)alloc((size_t)NCOARSE * CSTRIDE * 8);            // 31.2 MB
  float* donors = (float*)coarse;  // alias: coarse dead after k_regB

  hipMemsetAsync(d_ws, 0, zeroBytes, stream);

  if (exact)
    k_gen<false><<<nBlkG, 256, 0, stream>>>(x, mask, rsums, coarseCursor, coarse,
                                            bk0, bk1, sk0, sk1, n);
  else
    k_gen<true><<<nBlkG, 256, 0, stream>>>(x, mask, rsums, coarseCursor, coarse,
                                           bk0, bk1, sk0, sk1, n);
  k_regB<<<(int)(NCOARSE * WPC), 256, 0, stream>>>(coarse, coarseCursor, fineCursor, fine);
  k_scan2<<<2, 256, 0, stream>>>(rsums, nBlkG, fineCursor, (int)NFINE);
  k_binsort<<<(int)NFINE, 256, 0, stream>>>(fine, fineCursor, donors);
  if (exact)
    k_final<false><<<nBlkG, 256, 0, stream>>>(x, mask, rsums, donors, out, n);
  else
    k_final<true><<<nBlkG, 256, 0, stream>>>(x, mask, rsums, donors, out, n);
}